// Round 9
// baseline (935.504 us; speedup 1.0000x reference)
//
#include <hip/hip_runtime.h>
#include <hip/hip_bf16.h>
#include <stdint.h>

static constexpr int BATCH = 256;

#define CDIV(a,b) (((a)+(b)-1)/(b))

// ---------------- weight packing ----------------
__global__ void k_pack_conv_w(const float* __restrict__ w, uint32_t* __restrict__ out, int Co, int CW){
  int idx = blockIdx.x*256 + threadIdx.x;
  int total = Co*CW*9;
  if (idx >= total) return;
  int tap = idx % 9; int t = idx / 9; int cw = t % CW; int co = t / CW;
  int Ci = CW*32;
  const float* src = w + ((size_t)co*Ci + (size_t)cw*32)*9 + tap;
  uint32_t bits = 0;
  #pragma unroll
  for (int b=0;b<32;b++) bits |= (src[(size_t)b*9] >= 0.f ? 1u:0u) << b;
  out[idx] = bits;
}

__global__ void k_pack_fc1_w(const float* __restrict__ w, uint32_t* __restrict__ out){
  int idx = blockIdx.x*256 + threadIdx.x;
  if (idx >= 1024*256) return;
  int wd = idx & 255, o = idx >> 8;
  int cw = wd >> 4, p = wd & 15;
  const float* src = w + (size_t)o*8192;
  uint32_t bits=0;
  #pragma unroll
  for (int b=0;b<32;b++) bits |= (src[(cw*32+b)*16 + p] >= 0.f ? 1u:0u) << b;
  out[idx]=bits;
}

__global__ void k_pack_fc2_w(const float* __restrict__ w, uint32_t* __restrict__ out){
  int idx = blockIdx.x*256+threadIdx.x; if (idx >= 10*32) return;
  int wd = idx & 31, o = idx >> 5;
  uint32_t bits=0;
  #pragma unroll
  for (int b=0;b<32;b++) bits |= (w[o*1024 + wd*32 + b] >= 0.f ? 1u:0u)<<b;
  out[idx]=bits;
}

// =====================================================================
// conv1 (f64-exact, as round 8)
// =====================================================================
__global__ __launch_bounds__(256) void k_conv1_stats3(const float* __restrict__ x,
        const float* __restrict__ w1, double* __restrict__ partials){
  __shared__ double xs[3][10][34];
  __shared__ float wf[128][27];
  int n = blockIdx.x >> 2, rg = blockIdx.x & 3;
  int y0 = rg*8;
  const float* xp = x + (size_t)n*3*1024;
  for (int i=threadIdx.x; i<3*10*34; i+=256){
    int ci = i/340, r = i%340, ly = r/34, lx = r%34;
    int gy = y0 - 1 + ly, gx = lx - 1;
    double v = 0.0;
    if (gy>=0 && gy<32 && gx>=0 && gx<32) v = (double)xp[ci*1024 + gy*32 + gx];
    (&xs[0][0][0])[i] = v;
  }
  for (int i=threadIdx.x; i<128*27; i+=256)
    (&wf[0][0])[i] = w1[i];
  __syncthreads();
  int wave = threadIdx.x>>6, lane = threadIdx.x&63;
  int c0 = (wave&1)*64, rsub = wave>>1;
  int co = c0 + lane;
  double w[27];
  #pragma unroll
  for (int k=0;k<27;k++) w[k] = (wf[co][k] >= 0.f) ? 1.0 : -1.0;
  double s=0.0, s2=0.0;
  for (int rr = rsub*4; rr < rsub*4+4; ++rr){
    for (int xx=0; xx<32; ++xx){
      double a0=0.0, a1=0.0, a2=0.0;
      #pragma unroll
      for (int ci=0;ci<3;ci++){
        const double* r0 = &xs[ci][rr+0][xx];
        const double* r1 = &xs[ci][rr+1][xx];
        const double* r2 = &xs[ci][rr+2][xx];
        a0 += r0[0]*w[ci*9+0] + r0[1]*w[ci*9+1] + r0[2]*w[ci*9+2];
        a1 += r1[0]*w[ci*9+3] + r1[1]*w[ci*9+4] + r1[2]*w[ci*9+5];
        a2 += r2[0]*w[ci*9+6] + r2[1]*w[ci*9+7] + r2[2]*w[ci*9+8];
      }
      double acc = (a0 + a1) + a2;
      s += acc; s2 += acc*acc;
    }
  }
  size_t pi = (size_t)co*2048 + (size_t)n*8 + rg*2 + rsub;
  partials[pi*2+0]=s; partials[pi*2+1]=s2;
}

__global__ __launch_bounds__(256) void k_finalize_partials_p(const double* __restrict__ partials,
        const float* __restrict__ g, const float* __restrict__ b,
        double* __restrict__ A, double* __restrict__ Bv, int nPart, double invCount){
  int c = blockIdx.x;
  double s=0.0, s2=0.0;
  for (int i=threadIdx.x; i<nPart; i+=256){
    s  += partials[((size_t)c*nPart+i)*2+0];
    s2 += partials[((size_t)c*nPart+i)*2+1];
  }
  for (int off=32; off; off>>=1){ s+=__shfl_down(s,off,64); s2+=__shfl_down(s2,off,64); }
  __shared__ double sh[8];
  int wid=threadIdx.x>>6, lane=threadIdx.x&63;
  if(lane==0){sh[wid]=s;sh[4+wid]=s2;}
  __syncthreads();
  if(threadIdx.x==0){
    double S=0,S2=0;
    #pragma unroll
    for(int i=0;i<4;i++){S+=sh[i];S2+=sh[4+i];}
    double m=S*invCount, v=S2*invCount-m*m;
    double a=(double)g[c]/sqrt(v+1e-5);
    A[c]=a; Bv[c]=(double)b[c]-m*a;
  }
}

__global__ __launch_bounds__(256) void k_conv1_binarize4(const float* __restrict__ x,
        const float* __restrict__ w1, const double* __restrict__ A, const double* __restrict__ Bv,
        uint32_t* __restrict__ bits){
  __shared__ double xs[3][10][34];
  __shared__ float wf[128][27];
  __shared__ uint32_t wordbuf[4][256];
  int n = blockIdx.x >> 2, rg = blockIdx.x & 3;
  int y0 = rg*8;
  const float* xp = x + (size_t)n*3*1024;
  for (int i=threadIdx.x; i<3*10*34; i+=256){
    int ci = i/340, r = i%340, ly = r/34, lx = r%34;
    int gy = y0 - 1 + ly, gx = lx - 1;
    double v = 0.0;
    if (gy>=0 && gy<32 && gx>=0 && gx<32) v = (double)xp[ci*1024 + gy*32 + gx];
    (&xs[0][0][0])[i] = v;
  }
  for (int i=threadIdx.x; i<128*27; i+=256)
    (&wf[0][0])[i] = w1[i];
  __syncthreads();
  int wave = threadIdx.x>>6, lane = threadIdx.x&63;
  int c0 = (wave&1)*64, rsub = wave>>1;
  int co = c0 + lane;
  double w[27];
  #pragma unroll
  for (int k=0;k<27;k++) w[k] = (wf[co][k] >= 0.f) ? 1.0 : -1.0;
  double av = A[co], bv = Bv[co];
  for (int rr = rsub*4; rr < rsub*4+4; ++rr){
    for (int xx=0; xx<32; ++xx){
      double a0=0.0, a1=0.0, a2=0.0;
      #pragma unroll
      for (int ci=0;ci<3;ci++){
        const double* r0 = &xs[ci][rr+0][xx];
        const double* r1 = &xs[ci][rr+1][xx];
        const double* r2 = &xs[ci][rr+2][xx];
        a0 += r0[0]*w[ci*9+0] + r0[1]*w[ci*9+1] + r0[2]*w[ci*9+2];
        a1 += r1[0]*w[ci*9+3] + r1[1]*w[ci*9+4] + r1[2]*w[ci*9+5];
        a2 += r2[0]*w[ci*9+6] + r2[1]*w[ci*9+7] + r2[2]*w[ci*9+8];
      }
      double acc = (a0 + a1) + a2;
      int pred = (acc*av + bv >= 0.0) ? 1 : 0;
      unsigned long long m = __ballot(pred);
      if (lane == 0){
        wordbuf[(c0>>5)+0][rr*32+xx] = (uint32_t)m;
        wordbuf[(c0>>5)+1][rr*32+xx] = (uint32_t)(m>>32);
      }
    }
  }
  __syncthreads();
  for (int i=threadIdx.x; i<1024; i+=256){
    int cw = i>>8, p = i&255;
    bits[(size_t)n*4096 + cw*1024 + rg*256 + p] = wordbuf[cw][p];
  }
}

// =====================================================================
// LDS-tiled XNOR conv, zero-padded LDS border (no per-lane predication).
// inlds[CW][H+2][PITCH], pad words = 0; colpc/nv epilogue corrects exactly.
// =====================================================================
template<int CW,int H,int W,int CO,int COB,int NX>
__global__ __launch_bounds__(256) void k_xconv_pool(const uint32_t* __restrict__ in,
        const uint32_t* __restrict__ wb, int16_t* __restrict__ out){
  constexpr int HP = H+2;
  constexpr int PITCH = W+3;          // odd
  constexpr int WP = CW*9+1;
  constexpr int NG = CO/COB;
  constexpr int XS = W/NX;
  constexpr int UNITS = (H/2)*XS;
  static_assert(COB*UNITS==256, "thread mapping");
  __shared__ uint32_t inlds[CW*HP*PITCH];
  __shared__ uint32_t wlds[COB*WP];
  __shared__ int colpc[COB][10];
  int n = blockIdx.x / NG, cg = blockIdx.x % NG;
  int co0 = cg*COB;
  const uint32_t* ip = in + (size_t)n*CW*H*W;
  for (int i=threadIdx.x; i<CW*HP*PITCH; i+=256){
    int cw = i/(HP*PITCH); int r = i%(HP*PITCH); int y=r/PITCH, x=r%PITCH;
    uint32_t v = 0u;
    if (y>=1 && y<=H && x>=1 && x<=W) v = ip[cw*H*W + (y-1)*W + (x-1)];
    inlds[i] = v;
  }
  for (int i=threadIdx.x; i<COB*CW*9; i+=256){
    int co = i/(CW*9); int r = i%(CW*9);
    wlds[co*WP + r] = wb[(size_t)(co0+co)*CW*9 + r];
  }
  __syncthreads();
  for (int i=threadIdx.x; i<COB*9; i+=256){
    int co=i/9, tap=i%9; int s=0;
    #pragma unroll
    for (int cw=0;cw<CW;cw++) s += __popc(wlds[co*WP + cw*9 + tap]);
    colpc[co][tap]=s;
  }
  __syncthreads();
  int t = threadIdx.x;
  int col = t / UNITS;
  int rem = t % UNITS;
  int yy = rem / XS;
  int xs = (rem % XS)*NX;
  int co = co0 + col;
  int acc0[NX], acc1[NX];
  #pragma unroll
  for (int i2=0;i2<NX;i2++){acc0[i2]=0;acc1[i2]=0;}
  for (int cw=0; cw<CW; cw++){
    uint32_t wr[9];
    #pragma unroll
    for (int k=0;k<9;k++) wr[k]=wlds[col*WP+cw*9+k];
    const uint32_t* ib = &inlds[cw*HP*PITCH + (2*yy)*PITCH + xs];
    uint32_t rr[4][NX+2];
    #pragma unroll
    for (int rrow=0; rrow<4; rrow++)
      #pragma unroll
      for (int j=0;j<NX+2;j++)
        rr[rrow][j] = ib[rrow*PITCH + j];
    #pragma unroll
    for (int q=0;q<NX;q++){
      int a0 = __popc(rr[0][q]^wr[0])+__popc(rr[0][q+1]^wr[1])+__popc(rr[0][q+2]^wr[2])
             + __popc(rr[1][q]^wr[3])+__popc(rr[1][q+1]^wr[4])+__popc(rr[1][q+2]^wr[5])
             + __popc(rr[2][q]^wr[6])+__popc(rr[2][q+1]^wr[7])+__popc(rr[2][q+2]^wr[8]);
      int a1 = __popc(rr[1][q]^wr[0])+__popc(rr[1][q+1]^wr[1])+__popc(rr[1][q+2]^wr[2])
             + __popc(rr[2][q]^wr[3])+__popc(rr[2][q+1]^wr[4])+__popc(rr[2][q+2]^wr[5])
             + __popc(rr[3][q]^wr[6])+__popc(rr[3][q+1]^wr[7])+__popc(rr[3][q+2]^wr[8]);
      acc0[q]+=a0; acc1[q]+=a1;
    }
  }
  const int* cp = colpc[col];
  int16_t res[NX/2];
  #pragma unroll
  for (int tp=0; tp<NX/2; tp++){
    int best=-32768;
    #pragma unroll
    for (int rrow=0;rrow<2;rrow++){
      int kyi = (rrow==0 && yy==0) ? 0 : ((rrow==1 && yy==H/2-1) ? 2 : -1);
      #pragma unroll
      for (int dx=0;dx<2;dx++){
        int q = 2*tp+dx;
        int x = xs+q;
        int kxi = (x==0)?0:((x==W-1)?2:-1);
        int acc = rrow? acc1[q]:acc0[q];
        int corr=0, nv=9;
        if (kyi>=0){ corr += cp[kyi*3+0]+cp[kyi*3+1]+cp[kyi*3+2]; }
        if (kxi>=0){ corr += cp[0+kxi]+cp[3+kxi]+cp[6+kxi]; }
        if (kyi>=0 && kxi>=0){ corr -= cp[kyi*3+kxi]; nv=4; }
        else if (kyi>=0 || kxi>=0) nv=6;
        int dot = 32*CW*nv - 2*(acc - corr);
        best = dot>best?dot:best;
      }
    }
    res[tp]=(int16_t)best;
  }
  int16_t* op = out + (((size_t)n*CO + co)*(H/2) + yy)*(W/2) + xs/2;
  #pragma unroll
  for (int tp=0;tp<NX/2;tp++) op[tp]=res[tp];
}

template<int CW,int H,int W,int CO,int COB,int NX>
__global__ __launch_bounds__(256) void k_xconv(const uint32_t* __restrict__ in,
        const uint32_t* __restrict__ wb, int16_t* __restrict__ out){
  constexpr int HP = H+2;
  constexpr int PITCH = W+3;          // odd
  constexpr int WP = CW*9+1;
  constexpr int NG = CO/COB;
  constexpr int XS = W/NX;
  constexpr int UNITS = H*XS;
  static_assert((COB/2)*UNITS==256, "thread mapping");
  __shared__ uint32_t inlds[CW*HP*PITCH];
  __shared__ uint32_t wlds[COB*WP];
  __shared__ int colpc[COB][10];
  int n = blockIdx.x / NG, cg = blockIdx.x % NG;
  int co0 = cg*COB;
  const uint32_t* ip = in + (size_t)n*CW*H*W;
  for (int i=threadIdx.x; i<CW*HP*PITCH; i+=256){
    int cw = i/(HP*PITCH); int r = i%(HP*PITCH); int y=r/PITCH, x=r%PITCH;
    uint32_t v = 0u;
    if (y>=1 && y<=H && x>=1 && x<=W) v = ip[cw*H*W + (y-1)*W + (x-1)];
    inlds[i] = v;
  }
  for (int i=threadIdx.x; i<COB*CW*9; i+=256){
    int co = i/(CW*9); int r = i%(CW*9);
    wlds[co*WP + r] = wb[(size_t)(co0+co)*CW*9 + r];
  }
  __syncthreads();
  for (int i=threadIdx.x; i<COB*9; i+=256){
    int co=i/9, tap=i%9; int s=0;
    #pragma unroll
    for (int cw=0;cw<CW;cw++) s += __popc(wlds[co*WP + cw*9 + tap]);
    colpc[co][tap]=s;
  }
  __syncthreads();
  int t = threadIdx.x;
  int cog = t / UNITS;
  int rem = t % UNITS;
  int y = rem / XS;
  int xs = (rem % XS)*NX;
  int c0 = cog*2;
  int acc[2][NX];
  #pragma unroll
  for (int c=0;c<2;c++)
    #pragma unroll
    for (int i2=0;i2<NX;i2++) acc[c][i2]=0;
  for (int cw=0; cw<CW; cw++){
    uint32_t wr[2][9];
    #pragma unroll
    for (int c=0;c<2;c++)
      #pragma unroll
      for (int k=0;k<9;k++) wr[c][k]=wlds[(c0+c)*WP+cw*9+k];
    const uint32_t* ib = &inlds[cw*HP*PITCH + y*PITCH + xs];
    uint32_t rr[3][NX+2];
    #pragma unroll
    for (int rrow=0; rrow<3; rrow++)
      #pragma unroll
      for (int j=0;j<NX+2;j++)
        rr[rrow][j] = ib[rrow*PITCH + j];
    #pragma unroll
    for (int q=0;q<NX;q++){
      #pragma unroll
      for (int c=0;c<2;c++){
        int a = __popc(rr[0][q]^wr[c][0])+__popc(rr[0][q+1]^wr[c][1])+__popc(rr[0][q+2]^wr[c][2])
              + __popc(rr[1][q]^wr[c][3])+__popc(rr[1][q+1]^wr[c][4])+__popc(rr[1][q+2]^wr[c][5])
              + __popc(rr[2][q]^wr[c][6])+__popc(rr[2][q+1]^wr[c][7])+__popc(rr[2][q+2]^wr[c][8]);
        acc[c][q]+=a;
      }
    }
  }
  int kyi = (y==0)?0:((y==H-1)?2:-1);
  #pragma unroll
  for (int c=0;c<2;c++){
    const int* cp = colpc[c0+c];
    int16_t rbuf[NX];
    #pragma unroll
    for (int q=0;q<NX;q++){
      int x = xs+q;
      int kxi = (x==0)?0:((x==W-1)?2:-1);
      int corr=0, nv=9;
      if (kyi>=0){ corr += cp[kyi*3+0]+cp[kyi*3+1]+cp[kyi*3+2]; }
      if (kxi>=0){ corr += cp[0+kxi]+cp[3+kxi]+cp[6+kxi]; }
      if (kyi>=0 && kxi>=0){ corr -= cp[kyi*3+kxi]; nv=4; }
      else if (kyi>=0 || kxi>=0) nv=6;
      rbuf[q] = (int16_t)(32*CW*nv - 2*(acc[c][q] - corr));
    }
    int16_t* op = out + (((size_t)n*CO + (co0+c0+c))*H + y)*W + xs;
    #pragma unroll
    for (int q=0;q<NX;q++) op[q]=rbuf[q];
  }
}

// ---------------- per-channel BN stats, exact int64, 2-stage ----------------
template<int NP>
__global__ void k_chstats_part(const int16_t* __restrict__ in, long long* __restrict__ part,
                               int C, int HW){
  int c = blockIdx.x / NP, p = blockIdx.x % NP;
  const int NPB = BATCH/NP;
  long long s=0, s2=0;
  int total = NPB*HW;
  for (int i=threadIdx.x; i<total; i+=256){
    int n = p*NPB + i/HW; int hw = i%HW;
    int v = in[((size_t)n*C+c)*HW+hw];
    s += v; s2 += (long long)(v*v);
  }
  __shared__ long long sh[8];
  for (int off=32; off; off>>=1){ s+=__shfl_down(s,off,64); s2+=__shfl_down(s2,off,64); }
  int wid=threadIdx.x>>6, lane=threadIdx.x&63;
  if(lane==0){sh[wid]=s;sh[4+wid]=s2;}
  __syncthreads();
  if(threadIdx.x==0){
    long long S=0,S2=0;
    #pragma unroll
    for(int i=0;i<4;i++){S+=sh[i];S2+=sh[4+i];}
    part[((size_t)c*NP+p)*2+0]=S;
    part[((size_t)c*NP+p)*2+1]=S2;
  }
}

__global__ void k_chstats_fin(const long long* __restrict__ part, const float* __restrict__ g,
                              const float* __restrict__ b, double* __restrict__ A, double* __restrict__ Bv,
                              int C, int NP, double invCount){
  int c = blockIdx.x*64+threadIdx.x; if (c>=C) return;
  long long S=0,S2=0;
  for (int i=0;i<NP;i++){ S+=part[((size_t)c*NP+i)*2]; S2+=part[((size_t)c*NP+i)*2+1]; }
  double m = (double)S*invCount;
  double v = (double)S2*invCount - m*m;
  double a = (double)g[c]/sqrt(v+1e-5);
  A[c]=a; Bv[c]=(double)b[c]-m*a;
}

// ---------------- binarize BN(conv) and pack ----------------
__global__ void k_binarize_pack(const int16_t* __restrict__ in, const double* __restrict__ A,
                                const double* __restrict__ Bv, uint32_t* __restrict__ bits,
                                int C, int HW){
  int CW = C>>5;
  size_t total = (size_t)BATCH*CW*HW;
  size_t idx = (size_t)blockIdx.x*256+threadIdx.x;
  if (idx>=total) return;
  int hw = (int)(idx % HW); size_t t = idx/HW;
  int cw = (int)(t % CW); int n = (int)(t / CW);
  uint32_t wordv=0;
  for (int b=0;b<32;b++){
    int c = cw*32+b;
    double v = (double)in[((size_t)n*C + c)*HW + hw];
    if (v*A[c]+Bv[c] >= 0.0) wordv |= 1u<<b;
  }
  bits[idx]=wordv;
}

// ---------------- FC1 ----------------
__global__ void k_fc1(const uint32_t* __restrict__ actbits, const uint32_t* __restrict__ wb,
                      int16_t* __restrict__ out){
  int og = blockIdx.x & 3; int n = blockIdx.x >> 2;
  int o = og*256 + threadIdx.x;
  __shared__ uint32_t sact[256];
  sact[threadIdx.x] = actbits[(size_t)n*256 + threadIdx.x];
  __syncthreads();
  const uint32_t* wp = wb + (size_t)o*256;
  int acc=0;
  #pragma unroll 8
  for (int k=0;k<256;k++) acc += __popc(sact[k]^wp[k]);
  out[(size_t)n*1024 + o] = (int16_t)(8192 - 2*acc);
}

__global__ void k_fc_stats(const int16_t* __restrict__ in, const float* __restrict__ g,
                           const float* __restrict__ b, double* __restrict__ A, double* __restrict__ Bv){
  int f = blockIdx.x;
  double v = (double)in[(size_t)threadIdx.x*1024 + f];
  double s=v, s2=v*v;
  __shared__ double sh[8];
  for (int off=32; off; off>>=1){ s+=__shfl_down(s,off,64); s2+=__shfl_down(s2,off,64); }
  int wid=threadIdx.x>>6, lane=threadIdx.x&63;
  if(lane==0){sh[wid]=s;sh[4+wid]=s2;}
  __syncthreads();
  if(threadIdx.x==0){
    double S=0,S2=0;
    #pragma unroll
    for(int i=0;i<4;i++){S+=sh[i];S2+=sh[4+i];}
    double m=S/256.0, var=S2/256.0-m*m;
    double a=(double)g[f]/sqrt(var+1e-5);
    A[f]=a; Bv[f]=(double)b[f]-m*a;
  }
}

__global__ void k_binpack_fc(const int16_t* __restrict__ in, const double* __restrict__ A,
                             const double* __restrict__ Bv, uint32_t* __restrict__ bits){
  int idx = blockIdx.x*256+threadIdx.x;
  if (idx >= 256*32) return;
  int w = idx & 31, n = idx >> 5;
  uint32_t word=0;
  for (int b=0;b<32;b++){
    int f = w*32+b;
    double v=(double)in[(size_t)n*1024+f];
    if (v*A[f]+Bv[f] >= 0.0) word|=1u<<b;
  }
  bits[idx]=word;
}

// ---------------- FC2 + final BN -> float out ----------------
__global__ void k_fc2_out(const uint32_t* __restrict__ actbits, const uint32_t* __restrict__ wb,
                          const float* __restrict__ bias2, const float* __restrict__ g,
                          const float* __restrict__ b, float* __restrict__ out){
  int o = blockIdx.x;     // 0..9
  int n = threadIdx.x;    // 0..255
  const uint32_t* ap = actbits + (size_t)n*32;
  const uint32_t* wp = wb + (size_t)o*32;
  int acc=0;
  #pragma unroll
  for (int k=0;k<32;k++) acc += __popc(ap[k]^wp[k]);
  double h = (double)(1024 - 2*acc) + (double)bias2[o];
  double s=h, s2=h*h;
  __shared__ double sh[8];
  for(int off=32;off;off>>=1){s+=__shfl_down(s,off,64);s2+=__shfl_down(s2,off,64);}
  int wid=threadIdx.x>>6,lane=threadIdx.x&63;
  if(lane==0){sh[wid]=s;sh[4+wid]=s2;}
  __syncthreads();
  __shared__ double sm, sinv;
  if(threadIdx.x==0){
    double S=0,S2=0;
    #pragma unroll
    for(int i=0;i<4;i++){S+=sh[i];S2+=sh[4+i];}
    double m=S/256.0, v=S2/256.0-m*m;
    sm=m; sinv=1.0/sqrt(v+1e-5);
  }
  __syncthreads();
  double r = (h - sm)*sinv*(double)g[o] + (double)b[o];
  out[(size_t)n*10 + o] = (float)r;
}

extern "C" void kernel_launch(void* const* d_in, const int* in_sizes, int n_in,
                              void* d_out, int out_size, void* d_ws, size_t ws_size,
                              hipStream_t stream) {
  const float* x   = (const float*)d_in[0];
  const float* w1  = (const float*)d_in[1];
  const float* g1  = (const float*)d_in[2];
  const float* b1  = (const float*)d_in[3];
  const float* w2  = (const float*)d_in[4];
  const float* g2  = (const float*)d_in[5];
  const float* b2  = (const float*)d_in[6];
  const float* w3  = (const float*)d_in[7];
  const float* g3  = (const float*)d_in[8];
  const float* b3  = (const float*)d_in[9];
  const float* w4  = (const float*)d_in[10];
  const float* g4  = (const float*)d_in[11];
  const float* b4  = (const float*)d_in[12];
  const float* w5  = (const float*)d_in[13];
  const float* g5  = (const float*)d_in[14];
  const float* b5  = (const float*)d_in[15];
  const float* w6  = (const float*)d_in[16];
  const float* g6  = (const float*)d_in[17];
  const float* b6  = (const float*)d_in[18];
  const float* wf1 = (const float*)d_in[19];
  const float* gf1 = (const float*)d_in[20];
  const float* bf1 = (const float*)d_in[21];
  const float* wf2 = (const float*)d_in[22];
  const float* bias2=(const float*)d_in[23];
  const float* gf2 = (const float*)d_in[24];
  const float* bf2 = (const float*)d_in[25];
  float* out = (float*)d_out;

  char* ws = (char*)d_ws;
  size_t off = 0;
  auto alloc = [&](size_t bytes)->char*{ char* p = ws + off; off = (off + bytes + 255) & ~(size_t)255; return p; };

  uint32_t* wb2  = (uint32_t*)alloc(4608ull*4);
  uint32_t* wb3  = (uint32_t*)alloc(9216ull*4);
  uint32_t* wb4  = (uint32_t*)alloc(18432ull*4);
  uint32_t* wb5  = (uint32_t*)alloc(36864ull*4);
  uint32_t* wb6  = (uint32_t*)alloc(73728ull*4);
  uint32_t* wf1b = (uint32_t*)alloc(262144ull*4);
  uint32_t* wf2b = (uint32_t*)alloc(320ull*4);
  double*   part = (double*)  alloc(128ull*2048*2*8);
  long long* pll = (long long*)alloc(512ull*8*2*8);
  double*   Abuf = (double*)  alloc(1024ull*8);
  double*   Bbuf = (double*)  alloc(1024ull*8);
  uint32_t* bitsA= (uint32_t*)alloc(1048576ull*4);
  uint32_t* bitsB= (uint32_t*)alloc(262144ull*4);
  int16_t*  conv = (int16_t*) alloc(16777216ull*2);

  // pack weights
  k_pack_conv_w<<<CDIV(4608,256),256,0,stream>>>(w2, wb2, 128, 4);
  k_pack_conv_w<<<CDIV(9216,256),256,0,stream>>>(w3, wb3, 256, 4);
  k_pack_conv_w<<<CDIV(18432,256),256,0,stream>>>(w4, wb4, 256, 8);
  k_pack_conv_w<<<CDIV(36864,256),256,0,stream>>>(w5, wb5, 512, 8);
  k_pack_conv_w<<<CDIV(73728,256),256,0,stream>>>(w6, wb6, 512, 16);
  k_pack_fc1_w<<<CDIV(262144,256),256,0,stream>>>(wf1, wf1b);
  k_pack_fc2_w<<<CDIV(320,256),256,0,stream>>>(wf2, wf2b);

  // ---- layer 1 ----
  k_conv1_stats3<<<1024,256,0,stream>>>(x, w1, part);
  k_finalize_partials_p<<<128,256,0,stream>>>(part, g1, b1, Abuf, Bbuf, 2048, 1.0/(256.0*1024.0));
  k_conv1_binarize4<<<1024,256,0,stream>>>(x, w1, Abuf, Bbuf, bitsA);

  // ---- layer 2: conv+pool -> [256,128,16,16] ----
  k_xconv_pool<4,32,32,128,4,8><<<256*32,256,0,stream>>>(bitsA, wb2, conv);
  k_chstats_part<8><<<128*8,256,0,stream>>>(conv, pll, 128, 256);
  k_chstats_fin<<<CDIV(128,64),64,0,stream>>>(pll, g2, b2, Abuf, Bbuf, 128, 8, 1.0/(256.0*256.0));
  k_binarize_pack<<<CDIV(256ull*4*256,256),256,0,stream>>>(conv, Abuf, Bbuf, bitsB, 128, 256);

  // ---- layer 3: conv -> [256,256,16,16] ----
  k_xconv<4,16,16,256,16,8><<<256*16,256,0,stream>>>(bitsB, wb3, conv);
  k_chstats_part<8><<<256*8,256,0,stream>>>(conv, pll, 256, 256);
  k_chstats_fin<<<CDIV(256,64),64,0,stream>>>(pll, g3, b3, Abuf, Bbuf, 256, 8, 1.0/(256.0*256.0));
  k_binarize_pack<<<CDIV(256ull*8*256,256),256,0,stream>>>(conv, Abuf, Bbuf, bitsA, 256, 256);

  // ---- layer 4: conv+pool -> [256,256,8,8] ----
  k_xconv_pool<8,16,16,256,16,8><<<256*16,256,0,stream>>>(bitsA, wb4, conv);
  k_chstats_part<8><<<256*8,256,0,stream>>>(conv, pll, 256, 64);
  k_chstats_fin<<<CDIV(256,64),64,0,stream>>>(pll, g4, b4, Abuf, Bbuf, 256, 8, 1.0/(256.0*64.0));
  k_binarize_pack<<<CDIV(256ull*8*64,256),256,0,stream>>>(conv, Abuf, Bbuf, bitsB, 256, 64);

  // ---- layer 5: conv -> [256,512,8,8] ----
  k_xconv<8,8,8,512,64,8><<<256*8,256,0,stream>>>(bitsB, wb5, conv);
  k_chstats_part<8><<<512*8,256,0,stream>>>(conv, pll, 512, 64);
  k_chstats_fin<<<CDIV(512,64),64,0,stream>>>(pll, g5, b5, Abuf, Bbuf, 512, 8, 1.0/(256.0*64.0));
  k_binarize_pack<<<CDIV(256ull*16*64,256),256,0,stream>>>(conv, Abuf, Bbuf, bitsA, 512, 64);

  // ---- layer 6: conv+pool -> [256,512,4,4] ----
  k_xconv_pool<16,8,8,512,64,8><<<256*8,256,0,stream>>>(bitsA, wb6, conv);
  k_chstats_part<8><<<512*8,256,0,stream>>>(conv, pll, 512, 16);
  k_chstats_fin<<<CDIV(512,64),64,0,stream>>>(pll, g6, b6, Abuf, Bbuf, 512, 8, 1.0/(256.0*16.0));
  k_binarize_pack<<<CDIV(256ull*16*16,256),256,0,stream>>>(conv, Abuf, Bbuf, bitsB, 512, 16);

  // ---- FC1 ----
  k_fc1<<<256*4,256,0,stream>>>(bitsB, wf1b, conv);
  k_fc_stats<<<1024,256,0,stream>>>(conv, gf1, bf1, Abuf, Bbuf);
  k_binpack_fc<<<CDIV(256*32,256),256,0,stream>>>(conv, Abuf, Bbuf, bitsA);

  // ---- FC2 + final BN ----
  k_fc2_out<<<10,256,0,stream>>>(bitsA, wf2b, bias2, gf2, bf2, out);

  (void)in_sizes; (void)n_in; (void)out_size; (void)ws_size;
}

// Round 10
// 798.047 us; speedup vs baseline: 1.1722x; 1.1722x over previous
//
#include <hip/hip_runtime.h>
#include <hip/hip_bf16.h>
#include <stdint.h>

static constexpr int BATCH = 256;

#define CDIV(a,b) (((a)+(b)-1)/(b))

// ---------------- weight packing ----------------
__global__ void k_pack_conv_w(const float* __restrict__ w, uint32_t* __restrict__ out, int Co, int CW){
  int idx = blockIdx.x*256 + threadIdx.x;
  int total = Co*CW*9;
  if (idx >= total) return;
  int tap = idx % 9; int t = idx / 9; int cw = t % CW; int co = t / CW;
  int Ci = CW*32;
  const float* src = w + ((size_t)co*Ci + (size_t)cw*32)*9 + tap;
  uint32_t bits = 0;
  #pragma unroll
  for (int b=0;b<32;b++) bits |= (src[(size_t)b*9] >= 0.f ? 1u:0u) << b;
  out[idx] = bits;
}

__global__ void k_pack_fc1_w(const float* __restrict__ w, uint32_t* __restrict__ out){
  int idx = blockIdx.x*256 + threadIdx.x;
  if (idx >= 1024*256) return;
  int wd = idx & 255, o = idx >> 8;
  int cw = wd >> 4, p = wd & 15;
  const float* src = w + (size_t)o*8192;
  uint32_t bits=0;
  #pragma unroll
  for (int b=0;b<32;b++) bits |= (src[(cw*32+b)*16 + p] >= 0.f ? 1u:0u) << b;
  out[idx]=bits;
}

__global__ void k_pack_fc2_w(const float* __restrict__ w, uint32_t* __restrict__ out){
  int idx = blockIdx.x*256+threadIdx.x; if (idx >= 10*32) return;
  int wd = idx & 31, o = idx >> 5;
  uint32_t bits=0;
  #pragma unroll
  for (int b=0;b<32;b++) bits |= (w[o*1024 + wd*32 + b] >= 0.f ? 1u:0u)<<b;
  out[idx]=bits;
}

// =====================================================================
// conv1 (f64-exact, as round 8)
// =====================================================================
__global__ __launch_bounds__(256) void k_conv1_stats3(const float* __restrict__ x,
        const float* __restrict__ w1, double* __restrict__ partials){
  __shared__ double xs[3][10][34];
  __shared__ float wf[128][27];
  int n = blockIdx.x >> 2, rg = blockIdx.x & 3;
  int y0 = rg*8;
  const float* xp = x + (size_t)n*3*1024;
  for (int i=threadIdx.x; i<3*10*34; i+=256){
    int ci = i/340, r = i%340, ly = r/34, lx = r%34;
    int gy = y0 - 1 + ly, gx = lx - 1;
    double v = 0.0;
    if (gy>=0 && gy<32 && gx>=0 && gx<32) v = (double)xp[ci*1024 + gy*32 + gx];
    (&xs[0][0][0])[i] = v;
  }
  for (int i=threadIdx.x; i<128*27; i+=256)
    (&wf[0][0])[i] = w1[i];
  __syncthreads();
  int wave = threadIdx.x>>6, lane = threadIdx.x&63;
  int c0 = (wave&1)*64, rsub = wave>>1;
  int co = c0 + lane;
  double w[27];
  #pragma unroll
  for (int k=0;k<27;k++) w[k] = (wf[co][k] >= 0.f) ? 1.0 : -1.0;
  double s=0.0, s2=0.0;
  for (int rr = rsub*4; rr < rsub*4+4; ++rr){
    for (int xx=0; xx<32; ++xx){
      double a0=0.0, a1=0.0, a2=0.0;
      #pragma unroll
      for (int ci=0;ci<3;ci++){
        const double* r0 = &xs[ci][rr+0][xx];
        const double* r1 = &xs[ci][rr+1][xx];
        const double* r2 = &xs[ci][rr+2][xx];
        a0 += r0[0]*w[ci*9+0] + r0[1]*w[ci*9+1] + r0[2]*w[ci*9+2];
        a1 += r1[0]*w[ci*9+3] + r1[1]*w[ci*9+4] + r1[2]*w[ci*9+5];
        a2 += r2[0]*w[ci*9+6] + r2[1]*w[ci*9+7] + r2[2]*w[ci*9+8];
      }
      double acc = (a0 + a1) + a2;
      s += acc; s2 += acc*acc;
    }
  }
  size_t pi = (size_t)co*2048 + (size_t)n*8 + rg*2 + rsub;
  partials[pi*2+0]=s; partials[pi*2+1]=s2;
}

__global__ __launch_bounds__(256) void k_finalize_partials_p(const double* __restrict__ partials,
        const float* __restrict__ g, const float* __restrict__ b,
        double* __restrict__ A, double* __restrict__ Bv, int nPart, double invCount){
  int c = blockIdx.x;
  double s=0.0, s2=0.0;
  for (int i=threadIdx.x; i<nPart; i+=256){
    s  += partials[((size_t)c*nPart+i)*2+0];
    s2 += partials[((size_t)c*nPart+i)*2+1];
  }
  for (int off=32; off; off>>=1){ s+=__shfl_down(s,off,64); s2+=__shfl_down(s2,off,64); }
  __shared__ double sh[8];
  int wid=threadIdx.x>>6, lane=threadIdx.x&63;
  if(lane==0){sh[wid]=s;sh[4+wid]=s2;}
  __syncthreads();
  if(threadIdx.x==0){
    double S=0,S2=0;
    #pragma unroll
    for(int i=0;i<4;i++){S+=sh[i];S2+=sh[4+i];}
    double m=S*invCount, v=S2*invCount-m*m;
    double a=(double)g[c]/sqrt(v+1e-5);
    A[c]=a; Bv[c]=(double)b[c]-m*a;
  }
}

__global__ __launch_bounds__(256) void k_conv1_binarize4(const float* __restrict__ x,
        const float* __restrict__ w1, const double* __restrict__ A, const double* __restrict__ Bv,
        uint32_t* __restrict__ bits){
  __shared__ double xs[3][10][34];
  __shared__ float wf[128][27];
  __shared__ uint32_t wordbuf[4][256];
  int n = blockIdx.x >> 2, rg = blockIdx.x & 3;
  int y0 = rg*8;
  const float* xp = x + (size_t)n*3*1024;
  for (int i=threadIdx.x; i<3*10*34; i+=256){
    int ci = i/340, r = i%340, ly = r/34, lx = r%34;
    int gy = y0 - 1 + ly, gx = lx - 1;
    double v = 0.0;
    if (gy>=0 && gy<32 && gx>=0 && gx<32) v = (double)xp[ci*1024 + gy*32 + gx];
    (&xs[0][0][0])[i] = v;
  }
  for (int i=threadIdx.x; i<128*27; i+=256)
    (&wf[0][0])[i] = w1[i];
  __syncthreads();
  int wave = threadIdx.x>>6, lane = threadIdx.x&63;
  int c0 = (wave&1)*64, rsub = wave>>1;
  int co = c0 + lane;
  double w[27];
  #pragma unroll
  for (int k=0;k<27;k++) w[k] = (wf[co][k] >= 0.f) ? 1.0 : -1.0;
  double av = A[co], bv = Bv[co];
  for (int rr = rsub*4; rr < rsub*4+4; ++rr){
    for (int xx=0; xx<32; ++xx){
      double a0=0.0, a1=0.0, a2=0.0;
      #pragma unroll
      for (int ci=0;ci<3;ci++){
        const double* r0 = &xs[ci][rr+0][xx];
        const double* r1 = &xs[ci][rr+1][xx];
        const double* r2 = &xs[ci][rr+2][xx];
        a0 += r0[0]*w[ci*9+0] + r0[1]*w[ci*9+1] + r0[2]*w[ci*9+2];
        a1 += r1[0]*w[ci*9+3] + r1[1]*w[ci*9+4] + r1[2]*w[ci*9+5];
        a2 += r2[0]*w[ci*9+6] + r2[1]*w[ci*9+7] + r2[2]*w[ci*9+8];
      }
      double acc = (a0 + a1) + a2;
      int pred = (acc*av + bv >= 0.0) ? 1 : 0;
      unsigned long long m = __ballot(pred);
      if (lane == 0){
        wordbuf[(c0>>5)+0][rr*32+xx] = (uint32_t)m;
        wordbuf[(c0>>5)+1][rr*32+xx] = (uint32_t)(m>>32);
      }
    }
  }
  __syncthreads();
  for (int i=threadIdx.x; i<1024; i+=256){
    int cw = i>>8, p = i&255;
    bits[(size_t)n*4096 + cw*1024 + rg*256 + p] = wordbuf[cw][p];
  }
}

// =====================================================================
// LDS-tiled XNOR conv: zero-padded LDS border + ROW-WISE inner loop
// (one 10-word row live at a time -> low VGPR, no border predication).
// =====================================================================
template<int CW,int H,int W,int CO,int COB,int NX>
__global__ __launch_bounds__(256) void k_xconv_pool(const uint32_t* __restrict__ in,
        const uint32_t* __restrict__ wb, int16_t* __restrict__ out){
  constexpr int HP = H+2;
  constexpr int PITCH = W+3;          // odd
  constexpr int WP = CW*9+1;
  constexpr int NG = CO/COB;
  constexpr int XS = W/NX;
  constexpr int UNITS = (H/2)*XS;
  static_assert(COB*UNITS==256, "thread mapping");
  __shared__ uint32_t inlds[CW*HP*PITCH];
  __shared__ uint32_t wlds[COB*WP];
  __shared__ int colpc[COB][10];
  int n = blockIdx.x / NG, cg = blockIdx.x % NG;
  int co0 = cg*COB;
  const uint32_t* ip = in + (size_t)n*CW*H*W;
  for (int i=threadIdx.x; i<CW*HP*PITCH; i+=256){
    int cw = i/(HP*PITCH); int r = i%(HP*PITCH); int y=r/PITCH, x=r%PITCH;
    uint32_t v = 0u;
    if (y>=1 && y<=H && x>=1 && x<=W) v = ip[cw*H*W + (y-1)*W + (x-1)];
    inlds[i] = v;
  }
  for (int i=threadIdx.x; i<COB*CW*9; i+=256){
    int co = i/(CW*9); int r = i%(CW*9);
    wlds[co*WP + r] = wb[(size_t)(co0+co)*CW*9 + r];
  }
  __syncthreads();
  for (int i=threadIdx.x; i<COB*9; i+=256){
    int co=i/9, tap=i%9; int s=0;
    #pragma unroll
    for (int cw=0;cw<CW;cw++) s += __popc(wlds[co*WP + cw*9 + tap]);
    colpc[co][tap]=s;
  }
  __syncthreads();
  int t = threadIdx.x;
  int col = t / UNITS;
  int rem = t % UNITS;
  int yy = rem / XS;
  int xs = (rem % XS)*NX;
  int co = co0 + col;
  int acc0[NX], acc1[NX];
  #pragma unroll
  for (int i2=0;i2<NX;i2++){acc0[i2]=0;acc1[i2]=0;}
  for (int cw=0; cw<CW; cw++){
    uint32_t wr[9];
    #pragma unroll
    for (int k=0;k<9;k++) wr[k]=wlds[col*WP+cw*9+k];
    const uint32_t* ib = &inlds[cw*HP*PITCH + (2*yy)*PITCH + xs];
    { // row 0 -> acc0 (tap row 0)
      uint32_t row[NX+2];
      #pragma unroll
      for (int j=0;j<NX+2;j++) row[j] = ib[j];
      #pragma unroll
      for (int q=0;q<NX;q++)
        acc0[q] += __popc(row[q]^wr[0])+__popc(row[q+1]^wr[1])+__popc(row[q+2]^wr[2]);
    }
    #pragma unroll
    for (int rrow=1; rrow<=2; rrow++){ // rows 1,2 -> acc0(tap rrow) + acc1(tap rrow-1)
      uint32_t row[NX+2];
      #pragma unroll
      for (int j=0;j<NX+2;j++) row[j] = ib[rrow*PITCH + j];
      #pragma unroll
      for (int q=0;q<NX;q++){
        acc0[q] += __popc(row[q]^wr[3*rrow+0])+__popc(row[q+1]^wr[3*rrow+1])+__popc(row[q+2]^wr[3*rrow+2]);
        acc1[q] += __popc(row[q]^wr[3*rrow-3])+__popc(row[q+1]^wr[3*rrow-2])+__popc(row[q+2]^wr[3*rrow-1]);
      }
    }
    { // row 3 -> acc1 (tap row 2)
      uint32_t row[NX+2];
      #pragma unroll
      for (int j=0;j<NX+2;j++) row[j] = ib[3*PITCH + j];
      #pragma unroll
      for (int q=0;q<NX;q++)
        acc1[q] += __popc(row[q]^wr[6])+__popc(row[q+1]^wr[7])+__popc(row[q+2]^wr[8]);
    }
  }
  const int* cp = colpc[col];
  int16_t res[NX/2];
  #pragma unroll
  for (int tp=0; tp<NX/2; tp++){
    int best=-32768;
    #pragma unroll
    for (int rrow=0;rrow<2;rrow++){
      int kyi = (rrow==0 && yy==0) ? 0 : ((rrow==1 && yy==H/2-1) ? 2 : -1);
      #pragma unroll
      for (int dx=0;dx<2;dx++){
        int q = 2*tp+dx;
        int x = xs+q;
        int kxi = (x==0)?0:((x==W-1)?2:-1);
        int acc = rrow? acc1[q]:acc0[q];
        int corr=0, nv=9;
        if (kyi>=0){ corr += cp[kyi*3+0]+cp[kyi*3+1]+cp[kyi*3+2]; }
        if (kxi>=0){ corr += cp[0+kxi]+cp[3+kxi]+cp[6+kxi]; }
        if (kyi>=0 && kxi>=0){ corr -= cp[kyi*3+kxi]; nv=4; }
        else if (kyi>=0 || kxi>=0) nv=6;
        int dot = 32*CW*nv - 2*(acc - corr);
        best = dot>best?dot:best;
      }
    }
    res[tp]=(int16_t)best;
  }
  int16_t* op = out + (((size_t)n*CO + co)*(H/2) + yy)*(W/2) + xs/2;
  #pragma unroll
  for (int tp=0;tp<NX/2;tp++) op[tp]=res[tp];
}

template<int CW,int H,int W,int CO,int COB,int NX>
__global__ __launch_bounds__(256) void k_xconv(const uint32_t* __restrict__ in,
        const uint32_t* __restrict__ wb, int16_t* __restrict__ out){
  constexpr int HP = H+2;
  constexpr int PITCH = W+3;          // odd
  constexpr int WP = CW*9+1;
  constexpr int NG = CO/COB;
  constexpr int XS = W/NX;
  constexpr int UNITS = H*XS;
  static_assert((COB/2)*UNITS==256, "thread mapping");
  __shared__ uint32_t inlds[CW*HP*PITCH];
  __shared__ uint32_t wlds[COB*WP];
  __shared__ int colpc[COB][10];
  int n = blockIdx.x / NG, cg = blockIdx.x % NG;
  int co0 = cg*COB;
  const uint32_t* ip = in + (size_t)n*CW*H*W;
  for (int i=threadIdx.x; i<CW*HP*PITCH; i+=256){
    int cw = i/(HP*PITCH); int r = i%(HP*PITCH); int y=r/PITCH, x=r%PITCH;
    uint32_t v = 0u;
    if (y>=1 && y<=H && x>=1 && x<=W) v = ip[cw*H*W + (y-1)*W + (x-1)];
    inlds[i] = v;
  }
  for (int i=threadIdx.x; i<COB*CW*9; i+=256){
    int co = i/(CW*9); int r = i%(CW*9);
    wlds[co*WP + r] = wb[(size_t)(co0+co)*CW*9 + r];
  }
  __syncthreads();
  for (int i=threadIdx.x; i<COB*9; i+=256){
    int co=i/9, tap=i%9; int s=0;
    #pragma unroll
    for (int cw=0;cw<CW;cw++) s += __popc(wlds[co*WP + cw*9 + tap]);
    colpc[co][tap]=s;
  }
  __syncthreads();
  int t = threadIdx.x;
  int cog = t / UNITS;
  int rem = t % UNITS;
  int y = rem / XS;
  int xs = (rem % XS)*NX;
  int c0 = cog*2;
  int acc[2][NX];
  #pragma unroll
  for (int c=0;c<2;c++)
    #pragma unroll
    for (int i2=0;i2<NX;i2++) acc[c][i2]=0;
  for (int cw=0; cw<CW; cw++){
    uint32_t wr[2][9];
    #pragma unroll
    for (int c=0;c<2;c++)
      #pragma unroll
      for (int k=0;k<9;k++) wr[c][k]=wlds[(c0+c)*WP+cw*9+k];
    const uint32_t* ib = &inlds[cw*HP*PITCH + y*PITCH + xs];
    #pragma unroll
    for (int rrow=0; rrow<3; rrow++){
      uint32_t row[NX+2];
      #pragma unroll
      for (int j=0;j<NX+2;j++) row[j] = ib[rrow*PITCH + j];
      #pragma unroll
      for (int q=0;q<NX;q++){
        acc[0][q] += __popc(row[q]^wr[0][3*rrow+0])+__popc(row[q+1]^wr[0][3*rrow+1])+__popc(row[q+2]^wr[0][3*rrow+2]);
        acc[1][q] += __popc(row[q]^wr[1][3*rrow+0])+__popc(row[q+1]^wr[1][3*rrow+1])+__popc(row[q+2]^wr[1][3*rrow+2]);
      }
    }
  }
  int kyi = (y==0)?0:((y==H-1)?2:-1);
  #pragma unroll
  for (int c=0;c<2;c++){
    const int* cp = colpc[c0+c];
    int16_t rbuf[NX];
    #pragma unroll
    for (int q=0;q<NX;q++){
      int x = xs+q;
      int kxi = (x==0)?0:((x==W-1)?2:-1);
      int corr=0, nv=9;
      if (kyi>=0){ corr += cp[kyi*3+0]+cp[kyi*3+1]+cp[kyi*3+2]; }
      if (kxi>=0){ corr += cp[0+kxi]+cp[3+kxi]+cp[6+kxi]; }
      if (kyi>=0 && kxi>=0){ corr -= cp[kyi*3+kxi]; nv=4; }
      else if (kyi>=0 || kxi>=0) nv=6;
      rbuf[q] = (int16_t)(32*CW*nv - 2*(acc[c][q] - corr));
    }
    int16_t* op = out + (((size_t)n*CO + (co0+c0+c))*H + y)*W + xs;
    #pragma unroll
    for (int q=0;q<NX;q++) op[q]=rbuf[q];
  }
}

// ---------------- per-channel BN stats, exact int64, 2-stage ----------------
template<int NP>
__global__ void k_chstats_part(const int16_t* __restrict__ in, long long* __restrict__ part,
                               int C, int HW){
  int c = blockIdx.x / NP, p = blockIdx.x % NP;
  const int NPB = BATCH/NP;
  long long s=0, s2=0;
  int total = NPB*HW;
  for (int i=threadIdx.x; i<total; i+=256){
    int n = p*NPB + i/HW; int hw = i%HW;
    int v = in[((size_t)n*C+c)*HW+hw];
    s += v; s2 += (long long)(v*v);
  }
  __shared__ long long sh[8];
  for (int off=32; off; off>>=1){ s+=__shfl_down(s,off,64); s2+=__shfl_down(s2,off,64); }
  int wid=threadIdx.x>>6, lane=threadIdx.x&63;
  if(lane==0){sh[wid]=s;sh[4+wid]=s2;}
  __syncthreads();
  if(threadIdx.x==0){
    long long S=0,S2=0;
    #pragma unroll
    for(int i=0;i<4;i++){S+=sh[i];S2+=sh[4+i];}
    part[((size_t)c*NP+p)*2+0]=S;
    part[((size_t)c*NP+p)*2+1]=S2;
  }
}

__global__ void k_chstats_fin(const long long* __restrict__ part, const float* __restrict__ g,
                              const float* __restrict__ b, double* __restrict__ A, double* __restrict__ Bv,
                              int C, int NP, double invCount){
  int c = blockIdx.x*64+threadIdx.x; if (c>=C) return;
  long long S=0,S2=0;
  for (int i=0;i<NP;i++){ S+=part[((size_t)c*NP+i)*2]; S2+=part[((size_t)c*NP+i)*2+1]; }
  double m = (double)S*invCount;
  double v = (double)S2*invCount - m*m;
  double a = (double)g[c]/sqrt(v+1e-5);
  A[c]=a; Bv[c]=(double)b[c]-m*a;
}

// ---------------- binarize BN(conv) and pack ----------------
__global__ void k_binarize_pack(const int16_t* __restrict__ in, const double* __restrict__ A,
                                const double* __restrict__ Bv, uint32_t* __restrict__ bits,
                                int C, int HW){
  int CW = C>>5;
  size_t total = (size_t)BATCH*CW*HW;
  size_t idx = (size_t)blockIdx.x*256+threadIdx.x;
  if (idx>=total) return;
  int hw = (int)(idx % HW); size_t t = idx/HW;
  int cw = (int)(t % CW); int n = (int)(t / CW);
  uint32_t wordv=0;
  for (int b=0;b<32;b++){
    int c = cw*32+b;
    double v = (double)in[((size_t)n*C + c)*HW + hw];
    if (v*A[c]+Bv[c] >= 0.0) wordv |= 1u<<b;
  }
  bits[idx]=wordv;
}

// ---------------- FC1 ----------------
__global__ void k_fc1(const uint32_t* __restrict__ actbits, const uint32_t* __restrict__ wb,
                      int16_t* __restrict__ out){
  int og = blockIdx.x & 3; int n = blockIdx.x >> 2;
  int o = og*256 + threadIdx.x;
  __shared__ uint32_t sact[256];
  sact[threadIdx.x] = actbits[(size_t)n*256 + threadIdx.x];
  __syncthreads();
  const uint32_t* wp = wb + (size_t)o*256;
  int acc=0;
  #pragma unroll 8
  for (int k=0;k<256;k++) acc += __popc(sact[k]^wp[k]);
  out[(size_t)n*1024 + o] = (int16_t)(8192 - 2*acc);
}

__global__ void k_fc_stats(const int16_t* __restrict__ in, const float* __restrict__ g,
                           const float* __restrict__ b, double* __restrict__ A, double* __restrict__ Bv){
  int f = blockIdx.x;
  double v = (double)in[(size_t)threadIdx.x*1024 + f];
  double s=v, s2=v*v;
  __shared__ double sh[8];
  for (int off=32; off; off>>=1){ s+=__shfl_down(s,off,64); s2+=__shfl_down(s2,off,64); }
  int wid=threadIdx.x>>6, lane=threadIdx.x&63;
  if(lane==0){sh[wid]=s;sh[4+wid]=s2;}
  __syncthreads();
  if(threadIdx.x==0){
    double S=0,S2=0;
    #pragma unroll
    for(int i=0;i<4;i++){S+=sh[i];S2+=sh[4+i];}
    double m=S/256.0, var=S2/256.0-m*m;
    double a=(double)g[f]/sqrt(var+1e-5);
    A[f]=a; Bv[f]=(double)b[f]-m*a;
  }
}

__global__ void k_binpack_fc(const int16_t* __restrict__ in, const double* __restrict__ A,
                             const double* __restrict__ Bv, uint32_t* __restrict__ bits){
  int idx = blockIdx.x*256+threadIdx.x;
  if (idx >= 256*32) return;
  int w = idx & 31, n = idx >> 5;
  uint32_t word=0;
  for (int b=0;b<32;b++){
    int f = w*32+b;
    double v=(double)in[(size_t)n*1024+f];
    if (v*A[f]+Bv[f] >= 0.0) word|=1u<<b;
  }
  bits[idx]=word;
}

// ---------------- FC2 + final BN -> float out ----------------
__global__ void k_fc2_out(const uint32_t* __restrict__ actbits, const uint32_t* __restrict__ wb,
                          const float* __restrict__ bias2, const float* __restrict__ g,
                          const float* __restrict__ b, float* __restrict__ out){
  int o = blockIdx.x;     // 0..9
  int n = threadIdx.x;    // 0..255
  const uint32_t* ap = actbits + (size_t)n*32;
  const uint32_t* wp = wb + (size_t)o*32;
  int acc=0;
  #pragma unroll
  for (int k=0;k<32;k++) acc += __popc(ap[k]^wp[k]);
  double h = (double)(1024 - 2*acc) + (double)bias2[o];
  double s=h, s2=h*h;
  __shared__ double sh[8];
  for(int off=32;off;off>>=1){s+=__shfl_down(s,off,64);s2+=__shfl_down(s2,off,64);}
  int wid=threadIdx.x>>6,lane=threadIdx.x&63;
  if(lane==0){sh[wid]=s;sh[4+wid]=s2;}
  __syncthreads();
  __shared__ double sm, sinv;
  if(threadIdx.x==0){
    double S=0,S2=0;
    #pragma unroll
    for(int i=0;i<4;i++){S+=sh[i];S2+=sh[4+i];}
    double m=S/256.0, v=S2/256.0-m*m;
    sm=m; sinv=1.0/sqrt(v+1e-5);
  }
  __syncthreads();
  double r = (h - sm)*sinv*(double)g[o] + (double)b[o];
  out[(size_t)n*10 + o] = (float)r;
}

extern "C" void kernel_launch(void* const* d_in, const int* in_sizes, int n_in,
                              void* d_out, int out_size, void* d_ws, size_t ws_size,
                              hipStream_t stream) {
  const float* x   = (const float*)d_in[0];
  const float* w1  = (const float*)d_in[1];
  const float* g1  = (const float*)d_in[2];
  const float* b1  = (const float*)d_in[3];
  const float* w2  = (const float*)d_in[4];
  const float* g2  = (const float*)d_in[5];
  const float* b2  = (const float*)d_in[6];
  const float* w3  = (const float*)d_in[7];
  const float* g3  = (const float*)d_in[8];
  const float* b3  = (const float*)d_in[9];
  const float* w4  = (const float*)d_in[10];
  const float* g4  = (const float*)d_in[11];
  const float* b4  = (const float*)d_in[12];
  const float* w5  = (const float*)d_in[13];
  const float* g5  = (const float*)d_in[14];
  const float* b5  = (const float*)d_in[15];
  const float* w6  = (const float*)d_in[16];
  const float* g6  = (const float*)d_in[17];
  const float* b6  = (const float*)d_in[18];
  const float* wf1 = (const float*)d_in[19];
  const float* gf1 = (const float*)d_in[20];
  const float* bf1 = (const float*)d_in[21];
  const float* wf2 = (const float*)d_in[22];
  const float* bias2=(const float*)d_in[23];
  const float* gf2 = (const float*)d_in[24];
  const float* bf2 = (const float*)d_in[25];
  float* out = (float*)d_out;

  char* ws = (char*)d_ws;
  size_t off = 0;
  auto alloc = [&](size_t bytes)->char*{ char* p = ws + off; off = (off + bytes + 255) & ~(size_t)255; return p; };

  uint32_t* wb2  = (uint32_t*)alloc(4608ull*4);
  uint32_t* wb3  = (uint32_t*)alloc(9216ull*4);
  uint32_t* wb4  = (uint32_t*)alloc(18432ull*4);
  uint32_t* wb5  = (uint32_t*)alloc(36864ull*4);
  uint32_t* wb6  = (uint32_t*)alloc(73728ull*4);
  uint32_t* wf1b = (uint32_t*)alloc(262144ull*4);
  uint32_t* wf2b = (uint32_t*)alloc(320ull*4);
  double*   part = (double*)  alloc(128ull*2048*2*8);
  long long* pll = (long long*)alloc(512ull*8*2*8);
  double*   Abuf = (double*)  alloc(1024ull*8);
  double*   Bbuf = (double*)  alloc(1024ull*8);
  uint32_t* bitsA= (uint32_t*)alloc(1048576ull*4);
  uint32_t* bitsB= (uint32_t*)alloc(262144ull*4);
  int16_t*  conv = (int16_t*) alloc(16777216ull*2);

  // pack weights
  k_pack_conv_w<<<CDIV(4608,256),256,0,stream>>>(w2, wb2, 128, 4);
  k_pack_conv_w<<<CDIV(9216,256),256,0,stream>>>(w3, wb3, 256, 4);
  k_pack_conv_w<<<CDIV(18432,256),256,0,stream>>>(w4, wb4, 256, 8);
  k_pack_conv_w<<<CDIV(36864,256),256,0,stream>>>(w5, wb5, 512, 8);
  k_pack_conv_w<<<CDIV(73728,256),256,0,stream>>>(w6, wb6, 512, 16);
  k_pack_fc1_w<<<CDIV(262144,256),256,0,stream>>>(wf1, wf1b);
  k_pack_fc2_w<<<CDIV(320,256),256,0,stream>>>(wf2, wf2b);

  // ---- layer 1 ----
  k_conv1_stats3<<<1024,256,0,stream>>>(x, w1, part);
  k_finalize_partials_p<<<128,256,0,stream>>>(part, g1, b1, Abuf, Bbuf, 2048, 1.0/(256.0*1024.0));
  k_conv1_binarize4<<<1024,256,0,stream>>>(x, w1, Abuf, Bbuf, bitsA);

  // ---- layer 2: conv+pool -> [256,128,16,16] ----
  k_xconv_pool<4,32,32,128,4,8><<<256*32,256,0,stream>>>(bitsA, wb2, conv);
  k_chstats_part<8><<<128*8,256,0,stream>>>(conv, pll, 128, 256);
  k_chstats_fin<<<CDIV(128,64),64,0,stream>>>(pll, g2, b2, Abuf, Bbuf, 128, 8, 1.0/(256.0*256.0));
  k_binarize_pack<<<CDIV(256ull*4*256,256),256,0,stream>>>(conv, Abuf, Bbuf, bitsB, 128, 256);

  // ---- layer 3: conv -> [256,256,16,16] ----
  k_xconv<4,16,16,256,16,8><<<256*16,256,0,stream>>>(bitsB, wb3, conv);
  k_chstats_part<8><<<256*8,256,0,stream>>>(conv, pll, 256, 256);
  k_chstats_fin<<<CDIV(256,64),64,0,stream>>>(pll, g3, b3, Abuf, Bbuf, 256, 8, 1.0/(256.0*256.0));
  k_binarize_pack<<<CDIV(256ull*8*256,256),256,0,stream>>>(conv, Abuf, Bbuf, bitsA, 256, 256);

  // ---- layer 4: conv+pool -> [256,256,8,8] ----
  k_xconv_pool<8,16,16,256,16,8><<<256*16,256,0,stream>>>(bitsA, wb4, conv);
  k_chstats_part<8><<<256*8,256,0,stream>>>(conv, pll, 256, 64);
  k_chstats_fin<<<CDIV(256,64),64,0,stream>>>(pll, g4, b4, Abuf, Bbuf, 256, 8, 1.0/(256.0*64.0));
  k_binarize_pack<<<CDIV(256ull*8*64,256),256,0,stream>>>(conv, Abuf, Bbuf, bitsB, 256, 64);

  // ---- layer 5: conv -> [256,512,8,8] ----
  k_xconv<8,8,8,512,64,8><<<256*8,256,0,stream>>>(bitsB, wb5, conv);
  k_chstats_part<8><<<512*8,256,0,stream>>>(conv, pll, 512, 64);
  k_chstats_fin<<<CDIV(512,64),64,0,stream>>>(pll, g5, b5, Abuf, Bbuf, 512, 8, 1.0/(256.0*64.0));
  k_binarize_pack<<<CDIV(256ull*16*64,256),256,0,stream>>>(conv, Abuf, Bbuf, bitsA, 512, 64);

  // ---- layer 6: conv+pool -> [256,512,4,4] ----
  k_xconv_pool<16,8,8,512,64,8><<<256*8,256,0,stream>>>(bitsA, wb6, conv);
  k_chstats_part<8><<<512*8,256,0,stream>>>(conv, pll, 512, 16);
  k_chstats_fin<<<CDIV(512,64),64,0,stream>>>(pll, g6, b6, Abuf, Bbuf, 512, 8, 1.0/(256.0*16.0));
  k_binarize_pack<<<CDIV(256ull*16*16,256),256,0,stream>>>(conv, Abuf, Bbuf, bitsB, 512, 16);

  // ---- FC1 ----
  k_fc1<<<256*4,256,0,stream>>>(bitsB, wf1b, conv);
  k_fc_stats<<<1024,256,0,stream>>>(conv, gf1, bf1, Abuf, Bbuf);
  k_binpack_fc<<<CDIV(256*32,256),256,0,stream>>>(conv, Abuf, Bbuf, bitsA);

  // ---- FC2 + final BN ----
  k_fc2_out<<<10,256,0,stream>>>(bitsA, wf2b, bias2, gf2, bf2, out);

  (void)in_sizes; (void)n_in; (void)out_size; (void)ws_size;
}

// Round 11
// 750.451 us; speedup vs baseline: 1.2466x; 1.0634x over previous
//
#include <hip/hip_runtime.h>
#include <hip/hip_bf16.h>
#include <stdint.h>

static constexpr int BATCH = 256;

#define CDIV(a,b) (((a)+(b)-1)/(b))

// ---------------- weight packing ----------------
__global__ void k_pack_conv_w(const float* __restrict__ w, uint32_t* __restrict__ out, int Co, int CW){
  int idx = blockIdx.x*256 + threadIdx.x;
  int total = Co*CW*9;
  if (idx >= total) return;
  int tap = idx % 9; int t = idx / 9; int cw = t % CW; int co = t / CW;
  int Ci = CW*32;
  const float* src = w + ((size_t)co*Ci + (size_t)cw*32)*9 + tap;
  uint32_t bits = 0;
  #pragma unroll
  for (int b=0;b<32;b++) bits |= (src[(size_t)b*9] >= 0.f ? 1u:0u) << b;
  out[idx] = bits;
}

__global__ void k_pack_fc1_w(const float* __restrict__ w, uint32_t* __restrict__ out){
  int idx = blockIdx.x*256 + threadIdx.x;
  if (idx >= 1024*256) return;
  int wd = idx & 255, o = idx >> 8;
  int cw = wd >> 4, p = wd & 15;
  const float* src = w + (size_t)o*8192;
  uint32_t bits=0;
  #pragma unroll
  for (int b=0;b<32;b++) bits |= (src[(cw*32+b)*16 + p] >= 0.f ? 1u:0u) << b;
  out[idx]=bits;
}

__global__ void k_pack_fc2_w(const float* __restrict__ w, uint32_t* __restrict__ out){
  int idx = blockIdx.x*256+threadIdx.x; if (idx >= 10*32) return;
  int wd = idx & 31, o = idx >> 5;
  uint32_t bits=0;
  #pragma unroll
  for (int b=0;b<32;b++) bits |= (w[o*1024 + wd*32 + b] >= 0.f ? 1u:0u)<<b;
  out[idx]=bits;
}

// =====================================================================
// conv1 (f64-exact, as round 8)
// =====================================================================
__global__ __launch_bounds__(256) void k_conv1_stats3(const float* __restrict__ x,
        const float* __restrict__ w1, double* __restrict__ partials){
  __shared__ double xs[3][10][34];
  __shared__ float wf[128][27];
  int n = blockIdx.x >> 2, rg = blockIdx.x & 3;
  int y0 = rg*8;
  const float* xp = x + (size_t)n*3*1024;
  for (int i=threadIdx.x; i<3*10*34; i+=256){
    int ci = i/340, r = i%340, ly = r/34, lx = r%34;
    int gy = y0 - 1 + ly, gx = lx - 1;
    double v = 0.0;
    if (gy>=0 && gy<32 && gx>=0 && gx<32) v = (double)xp[ci*1024 + gy*32 + gx];
    (&xs[0][0][0])[i] = v;
  }
  for (int i=threadIdx.x; i<128*27; i+=256)
    (&wf[0][0])[i] = w1[i];
  __syncthreads();
  int wave = threadIdx.x>>6, lane = threadIdx.x&63;
  int c0 = (wave&1)*64, rsub = wave>>1;
  int co = c0 + lane;
  double w[27];
  #pragma unroll
  for (int k=0;k<27;k++) w[k] = (wf[co][k] >= 0.f) ? 1.0 : -1.0;
  double s=0.0, s2=0.0;
  for (int rr = rsub*4; rr < rsub*4+4; ++rr){
    for (int xx=0; xx<32; ++xx){
      double a0=0.0, a1=0.0, a2=0.0;
      #pragma unroll
      for (int ci=0;ci<3;ci++){
        const double* r0 = &xs[ci][rr+0][xx];
        const double* r1 = &xs[ci][rr+1][xx];
        const double* r2 = &xs[ci][rr+2][xx];
        a0 += r0[0]*w[ci*9+0] + r0[1]*w[ci*9+1] + r0[2]*w[ci*9+2];
        a1 += r1[0]*w[ci*9+3] + r1[1]*w[ci*9+4] + r1[2]*w[ci*9+5];
        a2 += r2[0]*w[ci*9+6] + r2[1]*w[ci*9+7] + r2[2]*w[ci*9+8];
      }
      double acc = (a0 + a1) + a2;
      s += acc; s2 += acc*acc;
    }
  }
  size_t pi = (size_t)co*2048 + (size_t)n*8 + rg*2 + rsub;
  partials[pi*2+0]=s; partials[pi*2+1]=s2;
}

__global__ __launch_bounds__(256) void k_finalize_partials_p(const double* __restrict__ partials,
        const float* __restrict__ g, const float* __restrict__ b,
        double* __restrict__ A, double* __restrict__ Bv, int nPart, double invCount){
  int c = blockIdx.x;
  double s=0.0, s2=0.0;
  for (int i=threadIdx.x; i<nPart; i+=256){
    s  += partials[((size_t)c*nPart+i)*2+0];
    s2 += partials[((size_t)c*nPart+i)*2+1];
  }
  for (int off=32; off; off>>=1){ s+=__shfl_down(s,off,64); s2+=__shfl_down(s2,off,64); }
  __shared__ double sh[8];
  int wid=threadIdx.x>>6, lane=threadIdx.x&63;
  if(lane==0){sh[wid]=s;sh[4+wid]=s2;}
  __syncthreads();
  if(threadIdx.x==0){
    double S=0,S2=0;
    #pragma unroll
    for(int i=0;i<4;i++){S+=sh[i];S2+=sh[4+i];}
    double m=S*invCount, v=S2*invCount-m*m;
    double a=(double)g[c]/sqrt(v+1e-5);
    A[c]=a; Bv[c]=(double)b[c]-m*a;
  }
}

__global__ __launch_bounds__(256) void k_conv1_binarize4(const float* __restrict__ x,
        const float* __restrict__ w1, const double* __restrict__ A, const double* __restrict__ Bv,
        uint32_t* __restrict__ bits){
  __shared__ double xs[3][10][34];
  __shared__ float wf[128][27];
  __shared__ uint32_t wordbuf[4][256];
  int n = blockIdx.x >> 2, rg = blockIdx.x & 3;
  int y0 = rg*8;
  const float* xp = x + (size_t)n*3*1024;
  for (int i=threadIdx.x; i<3*10*34; i+=256){
    int ci = i/340, r = i%340, ly = r/34, lx = r%34;
    int gy = y0 - 1 + ly, gx = lx - 1;
    double v = 0.0;
    if (gy>=0 && gy<32 && gx>=0 && gx<32) v = (double)xp[ci*1024 + gy*32 + gx];
    (&xs[0][0][0])[i] = v;
  }
  for (int i=threadIdx.x; i<128*27; i+=256)
    (&wf[0][0])[i] = w1[i];
  __syncthreads();
  int wave = threadIdx.x>>6, lane = threadIdx.x&63;
  int c0 = (wave&1)*64, rsub = wave>>1;
  int co = c0 + lane;
  double w[27];
  #pragma unroll
  for (int k=0;k<27;k++) w[k] = (wf[co][k] >= 0.f) ? 1.0 : -1.0;
  double av = A[co], bv = Bv[co];
  for (int rr = rsub*4; rr < rsub*4+4; ++rr){
    for (int xx=0; xx<32; ++xx){
      double a0=0.0, a1=0.0, a2=0.0;
      #pragma unroll
      for (int ci=0;ci<3;ci++){
        const double* r0 = &xs[ci][rr+0][xx];
        const double* r1 = &xs[ci][rr+1][xx];
        const double* r2 = &xs[ci][rr+2][xx];
        a0 += r0[0]*w[ci*9+0] + r0[1]*w[ci*9+1] + r0[2]*w[ci*9+2];
        a1 += r1[0]*w[ci*9+3] + r1[1]*w[ci*9+4] + r1[2]*w[ci*9+5];
        a2 += r2[0]*w[ci*9+6] + r2[1]*w[ci*9+7] + r2[2]*w[ci*9+8];
      }
      double acc = (a0 + a1) + a2;
      int pred = (acc*av + bv >= 0.0) ? 1 : 0;
      unsigned long long m = __ballot(pred);
      if (lane == 0){
        wordbuf[(c0>>5)+0][rr*32+xx] = (uint32_t)m;
        wordbuf[(c0>>5)+1][rr*32+xx] = (uint32_t)(m>>32);
      }
    }
  }
  __syncthreads();
  for (int i=threadIdx.x; i<1024; i+=256){
    int cw = i>>8, p = i&255;
    bits[(size_t)n*4096 + cw*1024 + rg*256 + p] = wordbuf[cw][p];
  }
}

// =====================================================================
// LDS-tiled XNOR conv: zero-padded LDS border, PITCH%4==0 -> b128 row
// loads (conflict-balanced), row-wise inner loop, fused exact block stats.
// part layout: [co][n] x (sum, sumsq) int64.
// =====================================================================
__device__ __forceinline__ void loadrow10(const uint32_t* p, uint32_t* row){
  uint4 v0 = *reinterpret_cast<const uint4*>(p);
  uint4 v1 = *reinterpret_cast<const uint4*>(p+4);
  uint2 v2 = *reinterpret_cast<const uint2*>(p+8);
  row[0]=v0.x;row[1]=v0.y;row[2]=v0.z;row[3]=v0.w;
  row[4]=v1.x;row[5]=v1.y;row[6]=v1.z;row[7]=v1.w;
  row[8]=v2.x;row[9]=v2.y;
}

template<int CW,int H,int W,int CO,int COB,int NX>
__global__ __launch_bounds__(256) void k_xconv_pool(const uint32_t* __restrict__ in,
        const uint32_t* __restrict__ wb, int16_t* __restrict__ out, long long* __restrict__ part){
  constexpr int HP = H+2;
  constexpr int PITCH = W+4;          // multiple of 4 -> 16B-aligned rows
  constexpr int WP = CW*9+1;
  constexpr int NG = CO/COB;
  constexpr int XS = W/NX;
  constexpr int UNITS = (H/2)*XS;
  static_assert(COB*UNITS==256, "thread mapping");
  static_assert(NX==8, "row loads fixed at 10 words");
  __shared__ __align__(16) uint32_t inlds[CW*HP*PITCH];
  __shared__ uint32_t wlds[COB*WP];
  __shared__ int colpc[COB][10];
  int n = blockIdx.x / NG, cg = blockIdx.x % NG;
  int co0 = cg*COB;
  const uint32_t* ip = in + (size_t)n*CW*H*W;
  for (int i=threadIdx.x; i<CW*HP*PITCH; i+=256){
    int cw = i/(HP*PITCH); int r = i%(HP*PITCH); int y=r/PITCH, x=r%PITCH;
    uint32_t v = 0u;
    if (y>=1 && y<=H && x>=1 && x<=W) v = ip[cw*H*W + (y-1)*W + (x-1)];
    inlds[i] = v;
  }
  for (int i=threadIdx.x; i<COB*CW*9; i+=256){
    int co = i/(CW*9); int r = i%(CW*9);
    wlds[co*WP + r] = wb[(size_t)(co0+co)*CW*9 + r];
  }
  __syncthreads();
  for (int i=threadIdx.x; i<COB*9; i+=256){
    int co=i/9, tap=i%9; int s=0;
    #pragma unroll
    for (int cw=0;cw<CW;cw++) s += __popc(wlds[co*WP + cw*9 + tap]);
    colpc[co][tap]=s;
  }
  __syncthreads();
  int t = threadIdx.x;
  int col = t / UNITS;
  int rem = t % UNITS;
  int yy = rem / XS;
  int xs = (rem % XS)*NX;
  int co = co0 + col;
  int acc0[NX], acc1[NX];
  #pragma unroll
  for (int i2=0;i2<NX;i2++){acc0[i2]=0;acc1[i2]=0;}
  for (int cw=0; cw<CW; cw++){
    uint32_t wr[9];
    #pragma unroll
    for (int k=0;k<9;k++) wr[k]=wlds[col*WP+cw*9+k];
    const uint32_t* ib = &inlds[cw*HP*PITCH + (2*yy)*PITCH + xs];
    { // row 0 -> acc0 (tap row 0)
      uint32_t row[10];
      loadrow10(ib, row);
      #pragma unroll
      for (int q=0;q<NX;q++)
        acc0[q] += __popc(row[q]^wr[0])+__popc(row[q+1]^wr[1])+__popc(row[q+2]^wr[2]);
    }
    #pragma unroll
    for (int rrow=1; rrow<=2; rrow++){ // rows 1,2 -> acc0(tap rrow) + acc1(tap rrow-1)
      uint32_t row[10];
      loadrow10(ib + rrow*PITCH, row);
      #pragma unroll
      for (int q=0;q<NX;q++){
        acc0[q] += __popc(row[q]^wr[3*rrow+0])+__popc(row[q+1]^wr[3*rrow+1])+__popc(row[q+2]^wr[3*rrow+2]);
        acc1[q] += __popc(row[q]^wr[3*rrow-3])+__popc(row[q+1]^wr[3*rrow-2])+__popc(row[q+2]^wr[3*rrow-1]);
      }
    }
    { // row 3 -> acc1 (tap row 2)
      uint32_t row[10];
      loadrow10(ib + 3*PITCH, row);
      #pragma unroll
      for (int q=0;q<NX;q++)
        acc1[q] += __popc(row[q]^wr[6])+__popc(row[q+1]^wr[7])+__popc(row[q+2]^wr[8]);
    }
  }
  const int* cp = colpc[col];
  int16_t res[NX/2];
  #pragma unroll
  for (int tp=0; tp<NX/2; tp++){
    int best=-32768;
    #pragma unroll
    for (int rrow=0;rrow<2;rrow++){
      int kyi = (rrow==0 && yy==0) ? 0 : ((rrow==1 && yy==H/2-1) ? 2 : -1);
      #pragma unroll
      for (int dx=0;dx<2;dx++){
        int q = 2*tp+dx;
        int x = xs+q;
        int kxi = (x==0)?0:((x==W-1)?2:-1);
        int acc = rrow? acc1[q]:acc0[q];
        int corr=0, nv=9;
        if (kyi>=0){ corr += cp[kyi*3+0]+cp[kyi*3+1]+cp[kyi*3+2]; }
        if (kxi>=0){ corr += cp[0+kxi]+cp[3+kxi]+cp[6+kxi]; }
        if (kyi>=0 && kxi>=0){ corr -= cp[kyi*3+kxi]; nv=4; }
        else if (kyi>=0 || kxi>=0) nv=6;
        int dot = 32*CW*nv - 2*(acc - corr);
        best = dot>best?dot:best;
      }
    }
    res[tp]=(int16_t)best;
  }
  int16_t* op = out + (((size_t)n*CO + co)*(H/2) + yy)*(W/2) + xs/2;
  #pragma unroll
  for (int tp=0;tp<NX/2;tp++) op[tp]=res[tp];
  // fused exact stats: group of UNITS consecutive threads covers all of (co,n)
  int ssum=0; long long ssq=0;
  #pragma unroll
  for (int tp=0;tp<NX/2;tp++){ int v=res[tp]; ssum+=v; ssq += (long long)(v*v); }
  long long s = (long long)ssum;
  #pragma unroll
  for (int off=UNITS>>1; off; off>>=1){ s += __shfl_down(s,off,UNITS); ssq += __shfl_down(ssq,off,UNITS); }
  if (rem==0){
    size_t pi = (size_t)co*BATCH + n;
    part[pi*2+0]=s; part[pi*2+1]=ssq;
  }
}

template<int CW,int H,int W,int CO,int COB,int NX>
__global__ __launch_bounds__(256) void k_xconv(const uint32_t* __restrict__ in,
        const uint32_t* __restrict__ wb, int16_t* __restrict__ out, long long* __restrict__ part){
  constexpr int HP = H+2;
  constexpr int PITCH = W+4;          // multiple of 4
  constexpr int WP = CW*9+1;
  constexpr int NG = CO/COB;
  constexpr int XS = W/NX;
  constexpr int UNITS = H*XS;
  static_assert((COB/2)*UNITS==256, "thread mapping");
  static_assert(NX==8, "row loads fixed at 10 words");
  __shared__ __align__(16) uint32_t inlds[CW*HP*PITCH];
  __shared__ uint32_t wlds[COB*WP];
  __shared__ int colpc[COB][10];
  int n = blockIdx.x / NG, cg = blockIdx.x % NG;
  int co0 = cg*COB;
  const uint32_t* ip = in + (size_t)n*CW*H*W;
  for (int i=threadIdx.x; i<CW*HP*PITCH; i+=256){
    int cw = i/(HP*PITCH); int r = i%(HP*PITCH); int y=r/PITCH, x=r%PITCH;
    uint32_t v = 0u;
    if (y>=1 && y<=H && x>=1 && x<=W) v = ip[cw*H*W + (y-1)*W + (x-1)];
    inlds[i] = v;
  }
  for (int i=threadIdx.x; i<COB*CW*9; i+=256){
    int co = i/(CW*9); int r = i%(CW*9);
    wlds[co*WP + r] = wb[(size_t)(co0+co)*CW*9 + r];
  }
  __syncthreads();
  for (int i=threadIdx.x; i<COB*9; i+=256){
    int co=i/9, tap=i%9; int s=0;
    #pragma unroll
    for (int cw=0;cw<CW;cw++) s += __popc(wlds[co*WP + cw*9 + tap]);
    colpc[co][tap]=s;
  }
  __syncthreads();
  int t = threadIdx.x;
  int cog = t / UNITS;
  int rem = t % UNITS;
  int y = rem / XS;
  int xs = (rem % XS)*NX;
  int c0 = cog*2;
  int acc[2][NX];
  #pragma unroll
  for (int c=0;c<2;c++)
    #pragma unroll
    for (int i2=0;i2<NX;i2++) acc[c][i2]=0;
  for (int cw=0; cw<CW; cw++){
    uint32_t wr[2][9];
    #pragma unroll
    for (int c=0;c<2;c++)
      #pragma unroll
      for (int k=0;k<9;k++) wr[c][k]=wlds[(c0+c)*WP+cw*9+k];
    const uint32_t* ib = &inlds[cw*HP*PITCH + y*PITCH + xs];
    #pragma unroll
    for (int rrow=0; rrow<3; rrow++){
      uint32_t row[10];
      loadrow10(ib + rrow*PITCH, row);
      #pragma unroll
      for (int q=0;q<NX;q++){
        acc[0][q] += __popc(row[q]^wr[0][3*rrow+0])+__popc(row[q+1]^wr[0][3*rrow+1])+__popc(row[q+2]^wr[0][3*rrow+2]);
        acc[1][q] += __popc(row[q]^wr[1][3*rrow+0])+__popc(row[q+1]^wr[1][3*rrow+1])+__popc(row[q+2]^wr[1][3*rrow+2]);
      }
    }
  }
  int kyi = (y==0)?0:((y==H-1)?2:-1);
  int ssum[2]={0,0}; long long ssq[2]={0,0};
  #pragma unroll
  for (int c=0;c<2;c++){
    const int* cp = colpc[c0+c];
    int16_t rbuf[NX];
    #pragma unroll
    for (int q=0;q<NX;q++){
      int x = xs+q;
      int kxi = (x==0)?0:((x==W-1)?2:-1);
      int corr=0, nv=9;
      if (kyi>=0){ corr += cp[kyi*3+0]+cp[kyi*3+1]+cp[kyi*3+2]; }
      if (kxi>=0){ corr += cp[0+kxi]+cp[3+kxi]+cp[6+kxi]; }
      if (kyi>=0 && kxi>=0){ corr -= cp[kyi*3+kxi]; nv=4; }
      else if (kyi>=0 || kxi>=0) nv=6;
      int dot = 32*CW*nv - 2*(acc[c][q] - corr);
      rbuf[q] = (int16_t)dot;
      ssum[c]+=dot; ssq[c]+=(long long)(dot*dot);
    }
    int16_t* op = out + (((size_t)n*CO + (co0+c0+c))*H + y)*W + xs;
    #pragma unroll
    for (int q=0;q<NX;q++) op[q]=rbuf[q];
  }
  #pragma unroll
  for (int c=0;c<2;c++){
    long long s=(long long)ssum[c], q2=ssq[c];
    #pragma unroll
    for (int off=UNITS>>1; off; off>>=1){ s += __shfl_down(s,off,UNITS); q2 += __shfl_down(q2,off,UNITS); }
    if (rem==0){
      size_t pi = (size_t)(co0+c0+c)*BATCH + n;
      part[pi*2+0]=s; part[pi*2+1]=q2;
    }
  }
}

// ---------------- parallel per-channel finalize from [c][256] int64 ----------------
__global__ __launch_bounds__(256) void k_chstats_fin_p(const long long* __restrict__ part,
        const float* __restrict__ g, const float* __restrict__ b,
        double* __restrict__ A, double* __restrict__ Bv, double invCount){
  int c = blockIdx.x;
  long long s  = part[((size_t)c*BATCH+threadIdx.x)*2+0];
  long long s2 = part[((size_t)c*BATCH+threadIdx.x)*2+1];
  for (int off=32; off; off>>=1){ s+=__shfl_down(s,off,64); s2+=__shfl_down(s2,off,64); }
  __shared__ long long sh[8];
  int wid=threadIdx.x>>6, lane=threadIdx.x&63;
  if(lane==0){sh[wid]=s;sh[4+wid]=s2;}
  __syncthreads();
  if(threadIdx.x==0){
    long long S=0,S2=0;
    #pragma unroll
    for(int i=0;i<4;i++){S+=sh[i];S2+=sh[4+i];}
    double m=(double)S*invCount, v=(double)S2*invCount-m*m;
    double a=(double)g[c]/sqrt(v+1e-5);
    A[c]=a; Bv[c]=(double)b[c]-m*a;
  }
}

// ---------------- binarize BN(conv) and pack ----------------
__global__ void k_binarize_pack(const int16_t* __restrict__ in, const double* __restrict__ A,
                                const double* __restrict__ Bv, uint32_t* __restrict__ bits,
                                int C, int HW){
  int CW = C>>5;
  size_t total = (size_t)BATCH*CW*HW;
  size_t idx = (size_t)blockIdx.x*256+threadIdx.x;
  if (idx>=total) return;
  int hw = (int)(idx % HW); size_t t = idx/HW;
  int cw = (int)(t % CW); int n = (int)(t / CW);
  uint32_t wordv=0;
  for (int b=0;b<32;b++){
    int c = cw*32+b;
    double v = (double)in[((size_t)n*C + c)*HW + hw];
    if (v*A[c]+Bv[c] >= 0.0) wordv |= 1u<<b;
  }
  bits[idx]=wordv;
}

// ---------------- FC1 ----------------
__global__ void k_fc1(const uint32_t* __restrict__ actbits, const uint32_t* __restrict__ wb,
                      int16_t* __restrict__ out){
  int og = blockIdx.x & 3; int n = blockIdx.x >> 2;
  int o = og*256 + threadIdx.x;
  __shared__ uint32_t sact[256];
  sact[threadIdx.x] = actbits[(size_t)n*256 + threadIdx.x];
  __syncthreads();
  const uint32_t* wp = wb + (size_t)o*256;
  int acc=0;
  #pragma unroll 8
  for (int k=0;k<256;k++) acc += __popc(sact[k]^wp[k]);
  out[(size_t)n*1024 + o] = (int16_t)(8192 - 2*acc);
}

__global__ void k_fc_stats(const int16_t* __restrict__ in, const float* __restrict__ g,
                           const float* __restrict__ b, double* __restrict__ A, double* __restrict__ Bv){
  int f = blockIdx.x;
  double v = (double)in[(size_t)threadIdx.x*1024 + f];
  double s=v, s2=v*v;
  __shared__ double sh[8];
  for (int off=32; off; off>>=1){ s+=__shfl_down(s,off,64); s2+=__shfl_down(s2,off,64); }
  int wid=threadIdx.x>>6, lane=threadIdx.x&63;
  if(lane==0){sh[wid]=s;sh[4+wid]=s2;}
  __syncthreads();
  if(threadIdx.x==0){
    double S=0,S2=0;
    #pragma unroll
    for(int i=0;i<4;i++){S+=sh[i];S2+=sh[4+i];}
    double m=S/256.0, var=S2/256.0-m*m;
    double a=(double)g[f]/sqrt(var+1e-5);
    A[f]=a; Bv[f]=(double)b[f]-m*a;
  }
}

__global__ void k_binpack_fc(const int16_t* __restrict__ in, const double* __restrict__ A,
                             const double* __restrict__ Bv, uint32_t* __restrict__ bits){
  int idx = blockIdx.x*256+threadIdx.x;
  if (idx >= 256*32) return;
  int w = idx & 31, n = idx >> 5;
  uint32_t word=0;
  for (int b=0;b<32;b++){
    int f = w*32+b;
    double v=(double)in[(size_t)n*1024+f];
    if (v*A[f]+Bv[f] >= 0.0) word|=1u<<b;
  }
  bits[idx]=word;
}

// ---------------- FC2 + final BN -> float out ----------------
__global__ void k_fc2_out(const uint32_t* __restrict__ actbits, const uint32_t* __restrict__ wb,
                          const float* __restrict__ bias2, const float* __restrict__ g,
                          const float* __restrict__ b, float* __restrict__ out){
  int o = blockIdx.x;     // 0..9
  int n = threadIdx.x;    // 0..255
  const uint32_t* ap = actbits + (size_t)n*32;
  const uint32_t* wp = wb + (size_t)o*32;
  int acc=0;
  #pragma unroll
  for (int k=0;k<32;k++) acc += __popc(ap[k]^wp[k]);
  double h = (double)(1024 - 2*acc) + (double)bias2[o];
  double s=h, s2=h*h;
  __shared__ double sh[8];
  for(int off=32;off;off>>=1){s+=__shfl_down(s,off,64);s2+=__shfl_down(s2,off,64);}
  int wid=threadIdx.x>>6,lane=threadIdx.x&63;
  if(lane==0){sh[wid]=s;sh[4+wid]=s2;}
  __syncthreads();
  __shared__ double sm, sinv;
  if(threadIdx.x==0){
    double S=0,S2=0;
    #pragma unroll
    for(int i=0;i<4;i++){S+=sh[i];S2+=sh[4+i];}
    double m=S/256.0, v=S2/256.0-m*m;
    sm=m; sinv=1.0/sqrt(v+1e-5);
  }
  __syncthreads();
  double r = (h - sm)*sinv*(double)g[o] + (double)b[o];
  out[(size_t)n*10 + o] = (float)r;
}

extern "C" void kernel_launch(void* const* d_in, const int* in_sizes, int n_in,
                              void* d_out, int out_size, void* d_ws, size_t ws_size,
                              hipStream_t stream) {
  const float* x   = (const float*)d_in[0];
  const float* w1  = (const float*)d_in[1];
  const float* g1  = (const float*)d_in[2];
  const float* b1  = (const float*)d_in[3];
  const float* w2  = (const float*)d_in[4];
  const float* g2  = (const float*)d_in[5];
  const float* b2  = (const float*)d_in[6];
  const float* w3  = (const float*)d_in[7];
  const float* g3  = (const float*)d_in[8];
  const float* b3  = (const float*)d_in[9];
  const float* w4  = (const float*)d_in[10];
  const float* g4  = (const float*)d_in[11];
  const float* b4  = (const float*)d_in[12];
  const float* w5  = (const float*)d_in[13];
  const float* g5  = (const float*)d_in[14];
  const float* b5  = (const float*)d_in[15];
  const float* w6  = (const float*)d_in[16];
  const float* g6  = (const float*)d_in[17];
  const float* b6  = (const float*)d_in[18];
  const float* wf1 = (const float*)d_in[19];
  const float* gf1 = (const float*)d_in[20];
  const float* bf1 = (const float*)d_in[21];
  const float* wf2 = (const float*)d_in[22];
  const float* bias2=(const float*)d_in[23];
  const float* gf2 = (const float*)d_in[24];
  const float* bf2 = (const float*)d_in[25];
  float* out = (float*)d_out;

  char* ws = (char*)d_ws;
  size_t off = 0;
  auto alloc = [&](size_t bytes)->char*{ char* p = ws + off; off = (off + bytes + 255) & ~(size_t)255; return p; };

  uint32_t* wb2  = (uint32_t*)alloc(4608ull*4);
  uint32_t* wb3  = (uint32_t*)alloc(9216ull*4);
  uint32_t* wb4  = (uint32_t*)alloc(18432ull*4);
  uint32_t* wb5  = (uint32_t*)alloc(36864ull*4);
  uint32_t* wb6  = (uint32_t*)alloc(73728ull*4);
  uint32_t* wf1b = (uint32_t*)alloc(262144ull*4);
  uint32_t* wf2b = (uint32_t*)alloc(320ull*4);
  double*   part = (double*)  alloc(128ull*2048*2*8);
  long long* pll = (long long*)alloc(512ull*256*2*8);
  double*   Abuf = (double*)  alloc(1024ull*8);
  double*   Bbuf = (double*)  alloc(1024ull*8);
  uint32_t* bitsA= (uint32_t*)alloc(1048576ull*4);
  uint32_t* bitsB= (uint32_t*)alloc(262144ull*4);
  int16_t*  conv = (int16_t*) alloc(16777216ull*2);

  // pack weights
  k_pack_conv_w<<<CDIV(4608,256),256,0,stream>>>(w2, wb2, 128, 4);
  k_pack_conv_w<<<CDIV(9216,256),256,0,stream>>>(w3, wb3, 256, 4);
  k_pack_conv_w<<<CDIV(18432,256),256,0,stream>>>(w4, wb4, 256, 8);
  k_pack_conv_w<<<CDIV(36864,256),256,0,stream>>>(w5, wb5, 512, 8);
  k_pack_conv_w<<<CDIV(73728,256),256,0,stream>>>(w6, wb6, 512, 16);
  k_pack_fc1_w<<<CDIV(262144,256),256,0,stream>>>(wf1, wf1b);
  k_pack_fc2_w<<<CDIV(320,256),256,0,stream>>>(wf2, wf2b);

  // ---- layer 1 ----
  k_conv1_stats3<<<1024,256,0,stream>>>(x, w1, part);
  k_finalize_partials_p<<<128,256,0,stream>>>(part, g1, b1, Abuf, Bbuf, 2048, 1.0/(256.0*1024.0));
  k_conv1_binarize4<<<1024,256,0,stream>>>(x, w1, Abuf, Bbuf, bitsA);

  // ---- layer 2: conv+pool -> [256,128,16,16] ----
  k_xconv_pool<4,32,32,128,4,8><<<256*32,256,0,stream>>>(bitsA, wb2, conv, pll);
  k_chstats_fin_p<<<128,256,0,stream>>>(pll, g2, b2, Abuf, Bbuf, 1.0/(256.0*256.0));
  k_binarize_pack<<<CDIV(256ull*4*256,256),256,0,stream>>>(conv, Abuf, Bbuf, bitsB, 128, 256);

  // ---- layer 3: conv -> [256,256,16,16] ----
  k_xconv<4,16,16,256,16,8><<<256*16,256,0,stream>>>(bitsB, wb3, conv, pll);
  k_chstats_fin_p<<<256,256,0,stream>>>(pll, g3, b3, Abuf, Bbuf, 1.0/(256.0*256.0));
  k_binarize_pack<<<CDIV(256ull*8*256,256),256,0,stream>>>(conv, Abuf, Bbuf, bitsA, 256, 256);

  // ---- layer 4: conv+pool -> [256,256,8,8] ----
  k_xconv_pool<8,16,16,256,16,8><<<256*16,256,0,stream>>>(bitsA, wb4, conv, pll);
  k_chstats_fin_p<<<256,256,0,stream>>>(pll, g4, b4, Abuf, Bbuf, 1.0/(256.0*64.0));
  k_binarize_pack<<<CDIV(256ull*8*64,256),256,0,stream>>>(conv, Abuf, Bbuf, bitsB, 256, 64);

  // ---- layer 5: conv -> [256,512,8,8] ----
  k_xconv<8,8,8,512,64,8><<<256*8,256,0,stream>>>(bitsB, wb5, conv, pll);
  k_chstats_fin_p<<<512,256,0,stream>>>(pll, g5, b5, Abuf, Bbuf, 1.0/(256.0*64.0));
  k_binarize_pack<<<CDIV(256ull*16*64,256),256,0,stream>>>(conv, Abuf, Bbuf, bitsA, 512, 64);

  // ---- layer 6: conv+pool -> [256,512,4,4] ----
  k_xconv_pool<16,8,8,512,64,8><<<256*8,256,0,stream>>>(bitsA, wb6, conv, pll);
  k_chstats_fin_p<<<512,256,0,stream>>>(pll, g6, b6, Abuf, Bbuf, 1.0/(256.0*16.0));
  k_binarize_pack<<<CDIV(256ull*16*16,256),256,0,stream>>>(conv, Abuf, Bbuf, bitsB, 512, 16);

  // ---- FC1 ----
  k_fc1<<<256*4,256,0,stream>>>(bitsB, wf1b, conv);
  k_fc_stats<<<1024,256,0,stream>>>(conv, gf1, bf1, Abuf, Bbuf);
  k_binpack_fc<<<CDIV(256*32,256),256,0,stream>>>(conv, Abuf, Bbuf, bitsA);

  // ---- FC2 + final BN ----
  k_fc2_out<<<10,256,0,stream>>>(bitsA, wf2b, bias2, gf2, bf2, out);

  (void)in_sizes; (void)n_in; (void)out_size; (void)ws_size;
}

// Round 12
// 748.108 us; speedup vs baseline: 1.2505x; 1.0031x over previous
//
#include <hip/hip_runtime.h>
#include <hip/hip_bf16.h>
#include <stdint.h>

static constexpr int BATCH = 256;

#define CDIV(a,b) (((a)+(b)-1)/(b))

// ---------------- weight packing ----------------
__global__ void k_pack_conv_w(const float* __restrict__ w, uint32_t* __restrict__ out, int Co, int CW){
  int idx = blockIdx.x*256 + threadIdx.x;
  int total = Co*CW*9;
  if (idx >= total) return;
  int tap = idx % 9; int t = idx / 9; int cw = t % CW; int co = t / CW;
  int Ci = CW*32;
  const float* src = w + ((size_t)co*Ci + (size_t)cw*32)*9 + tap;
  uint32_t bits = 0;
  #pragma unroll
  for (int b=0;b<32;b++) bits |= (src[(size_t)b*9] >= 0.f ? 1u:0u) << b;
  out[idx] = bits;
}

__global__ void k_pack_fc1_w(const float* __restrict__ w, uint32_t* __restrict__ out){
  int idx = blockIdx.x*256 + threadIdx.x;
  if (idx >= 1024*256) return;
  int wd = idx & 255, o = idx >> 8;
  int cw = wd >> 4, p = wd & 15;
  const float* src = w + (size_t)o*8192;
  uint32_t bits=0;
  #pragma unroll
  for (int b=0;b<32;b++) bits |= (src[(cw*32+b)*16 + p] >= 0.f ? 1u:0u) << b;
  out[idx]=bits;
}

__global__ void k_pack_fc2_w(const float* __restrict__ w, uint32_t* __restrict__ out){
  int idx = blockIdx.x*256+threadIdx.x; if (idx >= 10*32) return;
  int wd = idx & 31, o = idx >> 5;
  uint32_t bits=0;
  #pragma unroll
  for (int b=0;b<32;b++) bits |= (w[o*1024 + wd*32 + b] >= 0.f ? 1u:0u)<<b;
  out[idx]=bits;
}

// =====================================================================
// conv1 (f64-exact, as round 8)
// =====================================================================
__global__ __launch_bounds__(256) void k_conv1_stats3(const float* __restrict__ x,
        const float* __restrict__ w1, double* __restrict__ partials){
  __shared__ double xs[3][10][34];
  __shared__ float wf[128][27];
  int n = blockIdx.x >> 2, rg = blockIdx.x & 3;
  int y0 = rg*8;
  const float* xp = x + (size_t)n*3*1024;
  for (int i=threadIdx.x; i<3*10*34; i+=256){
    int ci = i/340, r = i%340, ly = r/34, lx = r%34;
    int gy = y0 - 1 + ly, gx = lx - 1;
    double v = 0.0;
    if (gy>=0 && gy<32 && gx>=0 && gx<32) v = (double)xp[ci*1024 + gy*32 + gx];
    (&xs[0][0][0])[i] = v;
  }
  for (int i=threadIdx.x; i<128*27; i+=256)
    (&wf[0][0])[i] = w1[i];
  __syncthreads();
  int wave = threadIdx.x>>6, lane = threadIdx.x&63;
  int c0 = (wave&1)*64, rsub = wave>>1;
  int co = c0 + lane;
  double w[27];
  #pragma unroll
  for (int k=0;k<27;k++) w[k] = (wf[co][k] >= 0.f) ? 1.0 : -1.0;
  double s=0.0, s2=0.0;
  for (int rr = rsub*4; rr < rsub*4+4; ++rr){
    for (int xx=0; xx<32; ++xx){
      double a0=0.0, a1=0.0, a2=0.0;
      #pragma unroll
      for (int ci=0;ci<3;ci++){
        const double* r0 = &xs[ci][rr+0][xx];
        const double* r1 = &xs[ci][rr+1][xx];
        const double* r2 = &xs[ci][rr+2][xx];
        a0 += r0[0]*w[ci*9+0] + r0[1]*w[ci*9+1] + r0[2]*w[ci*9+2];
        a1 += r1[0]*w[ci*9+3] + r1[1]*w[ci*9+4] + r1[2]*w[ci*9+5];
        a2 += r2[0]*w[ci*9+6] + r2[1]*w[ci*9+7] + r2[2]*w[ci*9+8];
      }
      double acc = (a0 + a1) + a2;
      s += acc; s2 += acc*acc;
    }
  }
  size_t pi = (size_t)co*2048 + (size_t)n*8 + rg*2 + rsub;
  partials[pi*2+0]=s; partials[pi*2+1]=s2;
}

__global__ __launch_bounds__(256) void k_finalize_partials_p(const double* __restrict__ partials,
        const float* __restrict__ g, const float* __restrict__ b,
        double* __restrict__ A, double* __restrict__ Bv, int nPart, double invCount){
  int c = blockIdx.x;
  double s=0.0, s2=0.0;
  for (int i=threadIdx.x; i<nPart; i+=256){
    s  += partials[((size_t)c*nPart+i)*2+0];
    s2 += partials[((size_t)c*nPart+i)*2+1];
  }
  for (int off=32; off; off>>=1){ s+=__shfl_down(s,off,64); s2+=__shfl_down(s2,off,64); }
  __shared__ double sh[8];
  int wid=threadIdx.x>>6, lane=threadIdx.x&63;
  if(lane==0){sh[wid]=s;sh[4+wid]=s2;}
  __syncthreads();
  if(threadIdx.x==0){
    double S=0,S2=0;
    #pragma unroll
    for(int i=0;i<4;i++){S+=sh[i];S2+=sh[4+i];}
    double m=S*invCount, v=S2*invCount-m*m;
    double a=(double)g[c]/sqrt(v+1e-5);
    A[c]=a; Bv[c]=(double)b[c]-m*a;
  }
}

__global__ __launch_bounds__(256) void k_conv1_binarize4(const float* __restrict__ x,
        const float* __restrict__ w1, const double* __restrict__ A, const double* __restrict__ Bv,
        uint32_t* __restrict__ bits){
  __shared__ double xs[3][10][34];
  __shared__ float wf[128][27];
  __shared__ uint32_t wordbuf[4][256];
  int n = blockIdx.x >> 2, rg = blockIdx.x & 3;
  int y0 = rg*8;
  const float* xp = x + (size_t)n*3*1024;
  for (int i=threadIdx.x; i<3*10*34; i+=256){
    int ci = i/340, r = i%340, ly = r/34, lx = r%34;
    int gy = y0 - 1 + ly, gx = lx - 1;
    double v = 0.0;
    if (gy>=0 && gy<32 && gx>=0 && gx<32) v = (double)xp[ci*1024 + gy*32 + gx];
    (&xs[0][0][0])[i] = v;
  }
  for (int i=threadIdx.x; i<128*27; i+=256)
    (&wf[0][0])[i] = w1[i];
  __syncthreads();
  int wave = threadIdx.x>>6, lane = threadIdx.x&63;
  int c0 = (wave&1)*64, rsub = wave>>1;
  int co = c0 + lane;
  double w[27];
  #pragma unroll
  for (int k=0;k<27;k++) w[k] = (wf[co][k] >= 0.f) ? 1.0 : -1.0;
  double av = A[co], bv = Bv[co];
  for (int rr = rsub*4; rr < rsub*4+4; ++rr){
    for (int xx=0; xx<32; ++xx){
      double a0=0.0, a1=0.0, a2=0.0;
      #pragma unroll
      for (int ci=0;ci<3;ci++){
        const double* r0 = &xs[ci][rr+0][xx];
        const double* r1 = &xs[ci][rr+1][xx];
        const double* r2 = &xs[ci][rr+2][xx];
        a0 += r0[0]*w[ci*9+0] + r0[1]*w[ci*9+1] + r0[2]*w[ci*9+2];
        a1 += r1[0]*w[ci*9+3] + r1[1]*w[ci*9+4] + r1[2]*w[ci*9+5];
        a2 += r2[0]*w[ci*9+6] + r2[1]*w[ci*9+7] + r2[2]*w[ci*9+8];
      }
      double acc = (a0 + a1) + a2;
      int pred = (acc*av + bv >= 0.0) ? 1 : 0;
      unsigned long long m = __ballot(pred);
      if (lane == 0){
        wordbuf[(c0>>5)+0][rr*32+xx] = (uint32_t)m;
        wordbuf[(c0>>5)+1][rr*32+xx] = (uint32_t)(m>>32);
      }
    }
  }
  __syncthreads();
  for (int i=threadIdx.x; i<1024; i+=256){
    int cw = i>>8, p = i&255;
    bits[(size_t)n*4096 + cw*1024 + rg*256 + p] = wordbuf[cw][p];
  }
}

// =====================================================================
// LDS-tiled XNOR conv: zero-padded LDS border, ODD PITCH (natural bank
// rotation, scalar row loads), row-wise inner loop (low VGPR), fused
// exact int64 block stats. part layout: [co][n] x (sum, sumsq).
// =====================================================================
template<int CW,int H,int W,int CO,int COB,int NX>
__global__ __launch_bounds__(256) void k_xconv_pool(const uint32_t* __restrict__ in,
        const uint32_t* __restrict__ wb, int16_t* __restrict__ out, long long* __restrict__ part){
  constexpr int HP = H+2;
  constexpr int PITCH = W+3;          // odd
  constexpr int WP = CW*9+1;
  constexpr int NG = CO/COB;
  constexpr int XS = W/NX;
  constexpr int UNITS = (H/2)*XS;
  static_assert(COB*UNITS==256, "thread mapping");
  __shared__ uint32_t inlds[CW*HP*PITCH];
  __shared__ uint32_t wlds[COB*WP];
  __shared__ int colpc[COB][10];
  int n = blockIdx.x / NG, cg = blockIdx.x % NG;
  int co0 = cg*COB;
  const uint32_t* ip = in + (size_t)n*CW*H*W;
  for (int i=threadIdx.x; i<CW*HP*PITCH; i+=256){
    int cw = i/(HP*PITCH); int r = i%(HP*PITCH); int y=r/PITCH, x=r%PITCH;
    uint32_t v = 0u;
    if (y>=1 && y<=H && x>=1 && x<=W) v = ip[cw*H*W + (y-1)*W + (x-1)];
    inlds[i] = v;
  }
  for (int i=threadIdx.x; i<COB*CW*9; i+=256){
    int co = i/(CW*9); int r = i%(CW*9);
    wlds[co*WP + r] = wb[(size_t)(co0+co)*CW*9 + r];
  }
  __syncthreads();
  for (int i=threadIdx.x; i<COB*9; i+=256){
    int co=i/9, tap=i%9; int s=0;
    #pragma unroll
    for (int cw=0;cw<CW;cw++) s += __popc(wlds[co*WP + cw*9 + tap]);
    colpc[co][tap]=s;
  }
  __syncthreads();
  int t = threadIdx.x;
  int col = t / UNITS;
  int rem = t % UNITS;
  int yy = rem / XS;
  int xs = (rem % XS)*NX;
  int co = co0 + col;
  int acc0[NX], acc1[NX];
  #pragma unroll
  for (int i2=0;i2<NX;i2++){acc0[i2]=0;acc1[i2]=0;}
  for (int cw=0; cw<CW; cw++){
    uint32_t wr[9];
    #pragma unroll
    for (int k=0;k<9;k++) wr[k]=wlds[col*WP+cw*9+k];
    const uint32_t* ib = &inlds[cw*HP*PITCH + (2*yy)*PITCH + xs];
    { // row 0 -> acc0 (tap row 0)
      uint32_t row[NX+2];
      #pragma unroll
      for (int j=0;j<NX+2;j++) row[j] = ib[j];
      #pragma unroll
      for (int q=0;q<NX;q++)
        acc0[q] += __popc(row[q]^wr[0])+__popc(row[q+1]^wr[1])+__popc(row[q+2]^wr[2]);
    }
    #pragma unroll
    for (int rrow=1; rrow<=2; rrow++){ // rows 1,2 -> acc0(tap rrow) + acc1(tap rrow-1)
      uint32_t row[NX+2];
      #pragma unroll
      for (int j=0;j<NX+2;j++) row[j] = ib[rrow*PITCH + j];
      #pragma unroll
      for (int q=0;q<NX;q++){
        acc0[q] += __popc(row[q]^wr[3*rrow+0])+__popc(row[q+1]^wr[3*rrow+1])+__popc(row[q+2]^wr[3*rrow+2]);
        acc1[q] += __popc(row[q]^wr[3*rrow-3])+__popc(row[q+1]^wr[3*rrow-2])+__popc(row[q+2]^wr[3*rrow-1]);
      }
    }
    { // row 3 -> acc1 (tap row 2)
      uint32_t row[NX+2];
      #pragma unroll
      for (int j=0;j<NX+2;j++) row[j] = ib[3*PITCH + j];
      #pragma unroll
      for (int q=0;q<NX;q++)
        acc1[q] += __popc(row[q]^wr[6])+__popc(row[q+1]^wr[7])+__popc(row[q+2]^wr[8]);
    }
  }
  const int* cp = colpc[col];
  int16_t res[NX/2];
  #pragma unroll
  for (int tp=0; tp<NX/2; tp++){
    int best=-32768;
    #pragma unroll
    for (int rrow=0;rrow<2;rrow++){
      int kyi = (rrow==0 && yy==0) ? 0 : ((rrow==1 && yy==H/2-1) ? 2 : -1);
      #pragma unroll
      for (int dx=0;dx<2;dx++){
        int q = 2*tp+dx;
        int x = xs+q;
        int kxi = (x==0)?0:((x==W-1)?2:-1);
        int acc = rrow? acc1[q]:acc0[q];
        int corr=0, nv=9;
        if (kyi>=0){ corr += cp[kyi*3+0]+cp[kyi*3+1]+cp[kyi*3+2]; }
        if (kxi>=0){ corr += cp[0+kxi]+cp[3+kxi]+cp[6+kxi]; }
        if (kyi>=0 && kxi>=0){ corr -= cp[kyi*3+kxi]; nv=4; }
        else if (kyi>=0 || kxi>=0) nv=6;
        int dot = 32*CW*nv - 2*(acc - corr);
        best = dot>best?dot:best;
      }
    }
    res[tp]=(int16_t)best;
  }
  int16_t* op = out + (((size_t)n*CO + co)*(H/2) + yy)*(W/2) + xs/2;
  #pragma unroll
  for (int tp=0;tp<NX/2;tp++) op[tp]=res[tp];
  // fused exact stats: UNITS consecutive threads cover all of (co,n)
  int ssum=0; long long ssq=0;
  #pragma unroll
  for (int tp=0;tp<NX/2;tp++){ int v=res[tp]; ssum+=v; ssq += (long long)(v*v); }
  long long s = (long long)ssum;
  #pragma unroll
  for (int off=UNITS>>1; off; off>>=1){ s += __shfl_down(s,off,UNITS); ssq += __shfl_down(ssq,off,UNITS); }
  if (rem==0){
    size_t pi = (size_t)co*BATCH + n;
    part[pi*2+0]=s; part[pi*2+1]=ssq;
  }
}

template<int CW,int H,int W,int CO,int COB,int NX>
__global__ __launch_bounds__(256) void k_xconv(const uint32_t* __restrict__ in,
        const uint32_t* __restrict__ wb, int16_t* __restrict__ out, long long* __restrict__ part){
  constexpr int HP = H+2;
  constexpr int PITCH = W+3;          // odd
  constexpr int WP = CW*9+1;
  constexpr int NG = CO/COB;
  constexpr int XS = W/NX;
  constexpr int UNITS = H*XS;
  static_assert((COB/2)*UNITS==256, "thread mapping");
  __shared__ uint32_t inlds[CW*HP*PITCH];
  __shared__ uint32_t wlds[COB*WP];
  __shared__ int colpc[COB][10];
  int n = blockIdx.x / NG, cg = blockIdx.x % NG;
  int co0 = cg*COB;
  const uint32_t* ip = in + (size_t)n*CW*H*W;
  for (int i=threadIdx.x; i<CW*HP*PITCH; i+=256){
    int cw = i/(HP*PITCH); int r = i%(HP*PITCH); int y=r/PITCH, x=r%PITCH;
    uint32_t v = 0u;
    if (y>=1 && y<=H && x>=1 && x<=W) v = ip[cw*H*W + (y-1)*W + (x-1)];
    inlds[i] = v;
  }
  for (int i=threadIdx.x; i<COB*CW*9; i+=256){
    int co = i/(CW*9); int r = i%(CW*9);
    wlds[co*WP + r] = wb[(size_t)(co0+co)*CW*9 + r];
  }
  __syncthreads();
  for (int i=threadIdx.x; i<COB*9; i+=256){
    int co=i/9, tap=i%9; int s=0;
    #pragma unroll
    for (int cw=0;cw<CW;cw++) s += __popc(wlds[co*WP + cw*9 + tap]);
    colpc[co][tap]=s;
  }
  __syncthreads();
  int t = threadIdx.x;
  int cog = t / UNITS;
  int rem = t % UNITS;
  int y = rem / XS;
  int xs = (rem % XS)*NX;
  int c0 = cog*2;
  int acc[2][NX];
  #pragma unroll
  for (int c=0;c<2;c++)
    #pragma unroll
    for (int i2=0;i2<NX;i2++) acc[c][i2]=0;
  for (int cw=0; cw<CW; cw++){
    uint32_t wr[2][9];
    #pragma unroll
    for (int c=0;c<2;c++)
      #pragma unroll
      for (int k=0;k<9;k++) wr[c][k]=wlds[(c0+c)*WP+cw*9+k];
    const uint32_t* ib = &inlds[cw*HP*PITCH + y*PITCH + xs];
    #pragma unroll
    for (int rrow=0; rrow<3; rrow++){
      uint32_t row[NX+2];
      #pragma unroll
      for (int j=0;j<NX+2;j++) row[j] = ib[rrow*PITCH + j];
      #pragma unroll
      for (int q=0;q<NX;q++){
        acc[0][q] += __popc(row[q]^wr[0][3*rrow+0])+__popc(row[q+1]^wr[0][3*rrow+1])+__popc(row[q+2]^wr[0][3*rrow+2]);
        acc[1][q] += __popc(row[q]^wr[1][3*rrow+0])+__popc(row[q+1]^wr[1][3*rrow+1])+__popc(row[q+2]^wr[1][3*rrow+2]);
      }
    }
  }
  int kyi = (y==0)?0:((y==H-1)?2:-1);
  int ssum[2]={0,0}; long long ssq[2]={0,0};
  #pragma unroll
  for (int c=0;c<2;c++){
    const int* cp = colpc[c0+c];
    int16_t rbuf[NX];
    #pragma unroll
    for (int q=0;q<NX;q++){
      int x = xs+q;
      int kxi = (x==0)?0:((x==W-1)?2:-1);
      int corr=0, nv=9;
      if (kyi>=0){ corr += cp[kyi*3+0]+cp[kyi*3+1]+cp[kyi*3+2]; }
      if (kxi>=0){ corr += cp[0+kxi]+cp[3+kxi]+cp[6+kxi]; }
      if (kyi>=0 && kxi>=0){ corr -= cp[kyi*3+kxi]; nv=4; }
      else if (kyi>=0 || kxi>=0) nv=6;
      int dot = 32*CW*nv - 2*(acc[c][q] - corr);
      rbuf[q] = (int16_t)dot;
      ssum[c]+=dot; ssq[c]+=(long long)(dot*dot);
    }
    int16_t* op = out + (((size_t)n*CO + (co0+c0+c))*H + y)*W + xs;
    #pragma unroll
    for (int q=0;q<NX;q++) op[q]=rbuf[q];
  }
  #pragma unroll
  for (int c=0;c<2;c++){
    long long s=(long long)ssum[c], q2=ssq[c];
    #pragma unroll
    for (int off=UNITS>>1; off; off>>=1){ s += __shfl_down(s,off,UNITS); q2 += __shfl_down(q2,off,UNITS); }
    if (rem==0){
      size_t pi = (size_t)(co0+c0+c)*BATCH + n;
      part[pi*2+0]=s; part[pi*2+1]=q2;
    }
  }
}

// ---------------- parallel per-channel finalize from [c][256] int64 ----------------
__global__ __launch_bounds__(256) void k_chstats_fin_p(const long long* __restrict__ part,
        const float* __restrict__ g, const float* __restrict__ b,
        double* __restrict__ A, double* __restrict__ Bv, double invCount){
  int c = blockIdx.x;
  long long s  = part[((size_t)c*BATCH+threadIdx.x)*2+0];
  long long s2 = part[((size_t)c*BATCH+threadIdx.x)*2+1];
  for (int off=32; off; off>>=1){ s+=__shfl_down(s,off,64); s2+=__shfl_down(s2,off,64); }
  __shared__ long long sh[8];
  int wid=threadIdx.x>>6, lane=threadIdx.x&63;
  if(lane==0){sh[wid]=s;sh[4+wid]=s2;}
  __syncthreads();
  if(threadIdx.x==0){
    long long S=0,S2=0;
    #pragma unroll
    for(int i=0;i<4;i++){S+=sh[i];S2+=sh[4+i];}
    double m=(double)S*invCount, v=(double)S2*invCount-m*m;
    double a=(double)g[c]/sqrt(v+1e-5);
    A[c]=a; Bv[c]=(double)b[c]-m*a;
  }
}

// ---------------- binarize BN(conv) and pack ----------------
__global__ void k_binarize_pack(const int16_t* __restrict__ in, const double* __restrict__ A,
                                const double* __restrict__ Bv, uint32_t* __restrict__ bits,
                                int C, int HW){
  int CW = C>>5;
  size_t total = (size_t)BATCH*CW*HW;
  size_t idx = (size_t)blockIdx.x*256+threadIdx.x;
  if (idx>=total) return;
  int hw = (int)(idx % HW); size_t t = idx/HW;
  int cw = (int)(t % CW); int n = (int)(t / CW);
  uint32_t wordv=0;
  for (int b=0;b<32;b++){
    int c = cw*32+b;
    double v = (double)in[((size_t)n*C + c)*HW + hw];
    if (v*A[c]+Bv[c] >= 0.0) wordv |= 1u<<b;
  }
  bits[idx]=wordv;
}

// ---------------- FC1 ----------------
__global__ void k_fc1(const uint32_t* __restrict__ actbits, const uint32_t* __restrict__ wb,
                      int16_t* __restrict__ out){
  int og = blockIdx.x & 3; int n = blockIdx.x >> 2;
  int o = og*256 + threadIdx.x;
  __shared__ uint32_t sact[256];
  sact[threadIdx.x] = actbits[(size_t)n*256 + threadIdx.x];
  __syncthreads();
  const uint32_t* wp = wb + (size_t)o*256;
  int acc=0;
  #pragma unroll 8
  for (int k=0;k<256;k++) acc += __popc(sact[k]^wp[k]);
  out[(size_t)n*1024 + o] = (int16_t)(8192 - 2*acc);
}

__global__ void k_fc_stats(const int16_t* __restrict__ in, const float* __restrict__ g,
                           const float* __restrict__ b, double* __restrict__ A, double* __restrict__ Bv){
  int f = blockIdx.x;
  double v = (double)in[(size_t)threadIdx.x*1024 + f];
  double s=v, s2=v*v;
  __shared__ double sh[8];
  for (int off=32; off; off>>=1){ s+=__shfl_down(s,off,64); s2+=__shfl_down(s2,off,64); }
  int wid=threadIdx.x>>6, lane=threadIdx.x&63;
  if(lane==0){sh[wid]=s;sh[4+wid]=s2;}
  __syncthreads();
  if(threadIdx.x==0){
    double S=0,S2=0;
    #pragma unroll
    for(int i=0;i<4;i++){S+=sh[i];S2+=sh[4+i];}
    double m=S/256.0, var=S2/256.0-m*m;
    double a=(double)g[f]/sqrt(var+1e-5);
    A[f]=a; Bv[f]=(double)b[f]-m*a;
  }
}

__global__ void k_binpack_fc(const int16_t* __restrict__ in, const double* __restrict__ A,
                             const double* __restrict__ Bv, uint32_t* __restrict__ bits){
  int idx = blockIdx.x*256+threadIdx.x;
  if (idx >= 256*32) return;
  int w = idx & 31, n = idx >> 5;
  uint32_t word=0;
  for (int b=0;b<32;b++){
    int f = w*32+b;
    double v=(double)in[(size_t)n*1024+f];
    if (v*A[f]+Bv[f] >= 0.0) word|=1u<<b;
  }
  bits[idx]=word;
}

// ---------------- FC2 + final BN -> float out ----------------
__global__ void k_fc2_out(const uint32_t* __restrict__ actbits, const uint32_t* __restrict__ wb,
                          const float* __restrict__ bias2, const float* __restrict__ g,
                          const float* __restrict__ b, float* __restrict__ out){
  int o = blockIdx.x;     // 0..9
  int n = threadIdx.x;    // 0..255
  const uint32_t* ap = actbits + (size_t)n*32;
  const uint32_t* wp = wb + (size_t)o*32;
  int acc=0;
  #pragma unroll
  for (int k=0;k<32;k++) acc += __popc(ap[k]^wp[k]);
  double h = (double)(1024 - 2*acc) + (double)bias2[o];
  double s=h, s2=h*h;
  __shared__ double sh[8];
  for(int off=32;off;off>>=1){s+=__shfl_down(s,off,64);s2+=__shfl_down(s2,off,64);}
  int wid=threadIdx.x>>6,lane=threadIdx.x&63;
  if(lane==0){sh[wid]=s;sh[4+wid]=s2;}
  __syncthreads();
  __shared__ double sm, sinv;
  if(threadIdx.x==0){
    double S=0,S2=0;
    #pragma unroll
    for(int i=0;i<4;i++){S+=sh[i];S2+=sh[4+i];}
    double m=S/256.0, v=S2/256.0-m*m;
    sm=m; sinv=1.0/sqrt(v+1e-5);
  }
  __syncthreads();
  double r = (h - sm)*sinv*(double)g[o] + (double)b[o];
  out[(size_t)n*10 + o] = (float)r;
}

extern "C" void kernel_launch(void* const* d_in, const int* in_sizes, int n_in,
                              void* d_out, int out_size, void* d_ws, size_t ws_size,
                              hipStream_t stream) {
  const float* x   = (const float*)d_in[0];
  const float* w1  = (const float*)d_in[1];
  const float* g1  = (const float*)d_in[2];
  const float* b1  = (const float*)d_in[3];
  const float* w2  = (const float*)d_in[4];
  const float* g2  = (const float*)d_in[5];
  const float* b2  = (const float*)d_in[6];
  const float* w3  = (const float*)d_in[7];
  const float* g3  = (const float*)d_in[8];
  const float* b3  = (const float*)d_in[9];
  const float* w4  = (const float*)d_in[10];
  const float* g4  = (const float*)d_in[11];
  const float* b4  = (const float*)d_in[12];
  const float* w5  = (const float*)d_in[13];
  const float* g5  = (const float*)d_in[14];
  const float* b5  = (const float*)d_in[15];
  const float* w6  = (const float*)d_in[16];
  const float* g6  = (const float*)d_in[17];
  const float* b6  = (const float*)d_in[18];
  const float* wf1 = (const float*)d_in[19];
  const float* gf1 = (const float*)d_in[20];
  const float* bf1 = (const float*)d_in[21];
  const float* wf2 = (const float*)d_in[22];
  const float* bias2=(const float*)d_in[23];
  const float* gf2 = (const float*)d_in[24];
  const float* bf2 = (const float*)d_in[25];
  float* out = (float*)d_out;

  char* ws = (char*)d_ws;
  size_t off = 0;
  auto alloc = [&](size_t bytes)->char*{ char* p = ws + off; off = (off + bytes + 255) & ~(size_t)255; return p; };

  uint32_t* wb2  = (uint32_t*)alloc(4608ull*4);
  uint32_t* wb3  = (uint32_t*)alloc(9216ull*4);
  uint32_t* wb4  = (uint32_t*)alloc(18432ull*4);
  uint32_t* wb5  = (uint32_t*)alloc(36864ull*4);
  uint32_t* wb6  = (uint32_t*)alloc(73728ull*4);
  uint32_t* wf1b = (uint32_t*)alloc(262144ull*4);
  uint32_t* wf2b = (uint32_t*)alloc(320ull*4);
  double*   part = (double*)  alloc(128ull*2048*2*8);
  long long* pll = (long long*)alloc(512ull*256*2*8);
  double*   Abuf = (double*)  alloc(1024ull*8);
  double*   Bbuf = (double*)  alloc(1024ull*8);
  uint32_t* bitsA= (uint32_t*)alloc(1048576ull*4);
  uint32_t* bitsB= (uint32_t*)alloc(262144ull*4);
  int16_t*  conv = (int16_t*) alloc(16777216ull*2);

  // pack weights
  k_pack_conv_w<<<CDIV(4608,256),256,0,stream>>>(w2, wb2, 128, 4);
  k_pack_conv_w<<<CDIV(9216,256),256,0,stream>>>(w3, wb3, 256, 4);
  k_pack_conv_w<<<CDIV(18432,256),256,0,stream>>>(w4, wb4, 256, 8);
  k_pack_conv_w<<<CDIV(36864,256),256,0,stream>>>(w5, wb5, 512, 8);
  k_pack_conv_w<<<CDIV(73728,256),256,0,stream>>>(w6, wb6, 512, 16);
  k_pack_fc1_w<<<CDIV(262144,256),256,0,stream>>>(wf1, wf1b);
  k_pack_fc2_w<<<CDIV(320,256),256,0,stream>>>(wf2, wf2b);

  // ---- layer 1 ----
  k_conv1_stats3<<<1024,256,0,stream>>>(x, w1, part);
  k_finalize_partials_p<<<128,256,0,stream>>>(part, g1, b1, Abuf, Bbuf, 2048, 1.0/(256.0*1024.0));
  k_conv1_binarize4<<<1024,256,0,stream>>>(x, w1, Abuf, Bbuf, bitsA);

  // ---- layer 2: conv+pool -> [256,128,16,16] ----
  k_xconv_pool<4,32,32,128,4,8><<<256*32,256,0,stream>>>(bitsA, wb2, conv, pll);
  k_chstats_fin_p<<<128,256,0,stream>>>(pll, g2, b2, Abuf, Bbuf, 1.0/(256.0*256.0));
  k_binarize_pack<<<CDIV(256ull*4*256,256),256,0,stream>>>(conv, Abuf, Bbuf, bitsB, 128, 256);

  // ---- layer 3: conv -> [256,256,16,16] ----
  k_xconv<4,16,16,256,16,8><<<256*16,256,0,stream>>>(bitsB, wb3, conv, pll);
  k_chstats_fin_p<<<256,256,0,stream>>>(pll, g3, b3, Abuf, Bbuf, 1.0/(256.0*256.0));
  k_binarize_pack<<<CDIV(256ull*8*256,256),256,0,stream>>>(conv, Abuf, Bbuf, bitsA, 256, 256);

  // ---- layer 4: conv+pool -> [256,256,8,8] ----
  k_xconv_pool<8,16,16,256,16,8><<<256*16,256,0,stream>>>(bitsA, wb4, conv, pll);
  k_chstats_fin_p<<<256,256,0,stream>>>(pll, g4, b4, Abuf, Bbuf, 1.0/(256.0*64.0));
  k_binarize_pack<<<CDIV(256ull*8*64,256),256,0,stream>>>(conv, Abuf, Bbuf, bitsB, 256, 64);

  // ---- layer 5: conv -> [256,512,8,8] ----
  k_xconv<8,8,8,512,64,8><<<256*8,256,0,stream>>>(bitsB, wb5, conv, pll);
  k_chstats_fin_p<<<512,256,0,stream>>>(pll, g5, b5, Abuf, Bbuf, 1.0/(256.0*64.0));
  k_binarize_pack<<<CDIV(256ull*16*64,256),256,0,stream>>>(conv, Abuf, Bbuf, bitsA, 512, 64);

  // ---- layer 6: conv+pool -> [256,512,4,4] ----
  k_xconv_pool<16,8,8,512,64,8><<<256*8,256,0,stream>>>(bitsA, wb6, conv, pll);
  k_chstats_fin_p<<<512,256,0,stream>>>(pll, g6, b6, Abuf, Bbuf, 1.0/(256.0*16.0));
  k_binarize_pack<<<CDIV(256ull*16*16,256),256,0,stream>>>(conv, Abuf, Bbuf, bitsB, 512, 16);

  // ---- FC1 ----
  k_fc1<<<256*4,256,0,stream>>>(bitsB, wf1b, conv);
  k_fc_stats<<<1024,256,0,stream>>>(conv, gf1, bf1, Abuf, Bbuf);
  k_binpack_fc<<<CDIV(256*32,256),256,0,stream>>>(conv, Abuf, Bbuf, bitsA);

  // ---- FC2 + final BN ----
  k_fc2_out<<<10,256,0,stream>>>(bitsA, wf2b, bias2, gf2, bf2, out);

  (void)in_sizes; (void)n_in; (void)out_size; (void)ws_size;
}

// Round 13
// 713.717 us; speedup vs baseline: 1.3107x; 1.0482x over previous
//
#include <hip/hip_runtime.h>
#include <hip/hip_bf16.h>
#include <stdint.h>

static constexpr int BATCH = 256;

#define CDIV(a,b) (((a)+(b)-1)/(b))

// ---------------- weight packing ----------------
__global__ void k_pack_conv_w(const float* __restrict__ w, uint32_t* __restrict__ out, int Co, int CW){
  int idx = blockIdx.x*256 + threadIdx.x;
  int total = Co*CW*9;
  if (idx >= total) return;
  int tap = idx % 9; int t = idx / 9; int cw = t % CW; int co = t / CW;
  int Ci = CW*32;
  const float* src = w + ((size_t)co*Ci + (size_t)cw*32)*9 + tap;
  uint32_t bits = 0;
  #pragma unroll
  for (int b=0;b<32;b++) bits |= (src[(size_t)b*9] >= 0.f ? 1u:0u) << b;
  out[idx] = bits;
}

__global__ void k_pack_fc1_w(const float* __restrict__ w, uint32_t* __restrict__ out){
  int idx = blockIdx.x*256 + threadIdx.x;
  if (idx >= 1024*256) return;
  int wd = idx & 255, o = idx >> 8;
  int cw = wd >> 4, p = wd & 15;
  const float* src = w + (size_t)o*8192;
  uint32_t bits=0;
  #pragma unroll
  for (int b=0;b<32;b++) bits |= (src[(cw*32+b)*16 + p] >= 0.f ? 1u:0u) << b;
  out[idx]=bits;
}

__global__ void k_pack_fc2_w(const float* __restrict__ w, uint32_t* __restrict__ out){
  int idx = blockIdx.x*256+threadIdx.x; if (idx >= 10*32) return;
  int wd = idx & 31, o = idx >> 5;
  uint32_t bits=0;
  #pragma unroll
  for (int b=0;b<32;b++) bits |= (w[o*1024 + wd*32 + b] >= 0.f ? 1u:0u)<<b;
  out[idx]=bits;
}

// =====================================================================
// conv1 (f64-exact, as round 8)
// =====================================================================
__global__ __launch_bounds__(256) void k_conv1_stats3(const float* __restrict__ x,
        const float* __restrict__ w1, double* __restrict__ partials){
  __shared__ double xs[3][10][34];
  __shared__ float wf[128][27];
  int n = blockIdx.x >> 2, rg = blockIdx.x & 3;
  int y0 = rg*8;
  const float* xp = x + (size_t)n*3*1024;
  for (int i=threadIdx.x; i<3*10*34; i+=256){
    int ci = i/340, r = i%340, ly = r/34, lx = r%34;
    int gy = y0 - 1 + ly, gx = lx - 1;
    double v = 0.0;
    if (gy>=0 && gy<32 && gx>=0 && gx<32) v = (double)xp[ci*1024 + gy*32 + gx];
    (&xs[0][0][0])[i] = v;
  }
  for (int i=threadIdx.x; i<128*27; i+=256)
    (&wf[0][0])[i] = w1[i];
  __syncthreads();
  int wave = threadIdx.x>>6, lane = threadIdx.x&63;
  int c0 = (wave&1)*64, rsub = wave>>1;
  int co = c0 + lane;
  double w[27];
  #pragma unroll
  for (int k=0;k<27;k++) w[k] = (wf[co][k] >= 0.f) ? 1.0 : -1.0;
  double s=0.0, s2=0.0;
  for (int rr = rsub*4; rr < rsub*4+4; ++rr){
    for (int xx=0; xx<32; ++xx){
      double a0=0.0, a1=0.0, a2=0.0;
      #pragma unroll
      for (int ci=0;ci<3;ci++){
        const double* r0 = &xs[ci][rr+0][xx];
        const double* r1 = &xs[ci][rr+1][xx];
        const double* r2 = &xs[ci][rr+2][xx];
        a0 += r0[0]*w[ci*9+0] + r0[1]*w[ci*9+1] + r0[2]*w[ci*9+2];
        a1 += r1[0]*w[ci*9+3] + r1[1]*w[ci*9+4] + r1[2]*w[ci*9+5];
        a2 += r2[0]*w[ci*9+6] + r2[1]*w[ci*9+7] + r2[2]*w[ci*9+8];
      }
      double acc = (a0 + a1) + a2;
      s += acc; s2 += acc*acc;
    }
  }
  size_t pi = (size_t)co*2048 + (size_t)n*8 + rg*2 + rsub;
  partials[pi*2+0]=s; partials[pi*2+1]=s2;
}

__global__ __launch_bounds__(256) void k_finalize_partials_p(const double* __restrict__ partials,
        const float* __restrict__ g, const float* __restrict__ b,
        double* __restrict__ A, double* __restrict__ Bv, int nPart, double invCount){
  int c = blockIdx.x;
  double s=0.0, s2=0.0;
  for (int i=threadIdx.x; i<nPart; i+=256){
    s  += partials[((size_t)c*nPart+i)*2+0];
    s2 += partials[((size_t)c*nPart+i)*2+1];
  }
  for (int off=32; off; off>>=1){ s+=__shfl_down(s,off,64); s2+=__shfl_down(s2,off,64); }
  __shared__ double sh[8];
  int wid=threadIdx.x>>6, lane=threadIdx.x&63;
  if(lane==0){sh[wid]=s;sh[4+wid]=s2;}
  __syncthreads();
  if(threadIdx.x==0){
    double S=0,S2=0;
    #pragma unroll
    for(int i=0;i<4;i++){S+=sh[i];S2+=sh[4+i];}
    double m=S*invCount, v=S2*invCount-m*m;
    double a=(double)g[c]/sqrt(v+1e-5);
    A[c]=a; Bv[c]=(double)b[c]-m*a;
  }
}

__global__ __launch_bounds__(256) void k_conv1_binarize4(const float* __restrict__ x,
        const float* __restrict__ w1, const double* __restrict__ A, const double* __restrict__ Bv,
        uint32_t* __restrict__ bits){
  __shared__ double xs[3][10][34];
  __shared__ float wf[128][27];
  __shared__ uint32_t wordbuf[4][256];
  int n = blockIdx.x >> 2, rg = blockIdx.x & 3;
  int y0 = rg*8;
  const float* xp = x + (size_t)n*3*1024;
  for (int i=threadIdx.x; i<3*10*34; i+=256){
    int ci = i/340, r = i%340, ly = r/34, lx = r%34;
    int gy = y0 - 1 + ly, gx = lx - 1;
    double v = 0.0;
    if (gy>=0 && gy<32 && gx>=0 && gx<32) v = (double)xp[ci*1024 + gy*32 + gx];
    (&xs[0][0][0])[i] = v;
  }
  for (int i=threadIdx.x; i<128*27; i+=256)
    (&wf[0][0])[i] = w1[i];
  __syncthreads();
  int wave = threadIdx.x>>6, lane = threadIdx.x&63;
  int c0 = (wave&1)*64, rsub = wave>>1;
  int co = c0 + lane;
  double w[27];
  #pragma unroll
  for (int k=0;k<27;k++) w[k] = (wf[co][k] >= 0.f) ? 1.0 : -1.0;
  double av = A[co], bv = Bv[co];
  for (int rr = rsub*4; rr < rsub*4+4; ++rr){
    for (int xx=0; xx<32; ++xx){
      double a0=0.0, a1=0.0, a2=0.0;
      #pragma unroll
      for (int ci=0;ci<3;ci++){
        const double* r0 = &xs[ci][rr+0][xx];
        const double* r1 = &xs[ci][rr+1][xx];
        const double* r2 = &xs[ci][rr+2][xx];
        a0 += r0[0]*w[ci*9+0] + r0[1]*w[ci*9+1] + r0[2]*w[ci*9+2];
        a1 += r1[0]*w[ci*9+3] + r1[1]*w[ci*9+4] + r1[2]*w[ci*9+5];
        a2 += r2[0]*w[ci*9+6] + r2[1]*w[ci*9+7] + r2[2]*w[ci*9+8];
      }
      double acc = (a0 + a1) + a2;
      int pred = (acc*av + bv >= 0.0) ? 1 : 0;
      unsigned long long m = __ballot(pred);
      if (lane == 0){
        wordbuf[(c0>>5)+0][rr*32+xx] = (uint32_t)m;
        wordbuf[(c0>>5)+1][rr*32+xx] = (uint32_t)(m>>32);
      }
    }
  }
  __syncthreads();
  for (int i=threadIdx.x; i<1024; i+=256){
    int cw = i>>8, p = i&255;
    bits[(size_t)n*4096 + cw*1024 + rg*256 + p] = wordbuf[cw][p];
  }
}

// =====================================================================
// XNOR conv family: zero+fill staging (pow2 shifts only), odd PITCH,
// row-wise inner loop, fused exact int64 stats.
// =====================================================================
template<int CW,int H,int W,int HP,int PITCH>
__device__ __forceinline__ void stage_bits(const uint32_t* __restrict__ ip, uint32_t* __restrict__ inlds){
  constexpr int LOGW  = (W==32)?5:(W==16)?4:3;
  constexpr int LOGHW = ((H*W)==1024)?10:((H*W)==256)?8:6;
  for (int i=threadIdx.x; i<CW*HP*PITCH; i+=256) inlds[i]=0u;
  // (weights staged by caller between here and sync)
}

template<int CW,int H,int W,int HP,int PITCH>
__device__ __forceinline__ void fill_bits(const uint32_t* __restrict__ ip, uint32_t* __restrict__ inlds){
  constexpr int LOGW  = (W==32)?5:(W==16)?4:3;
  constexpr int LOGHW = ((H*W)==1024)?10:((H*W)==256)?8:6;
  for (int i=threadIdx.x; i<CW*H*W; i+=256){
    int cw = i >> LOGHW;
    int rem = i & (H*W-1);
    int y = rem >> LOGW;
    int x = rem & (W-1);
    inlds[cw*HP*PITCH + (y+1)*PITCH + (x+1)] = ip[i];
  }
}

// ---- fused conv + pool, TWO output channels per thread (L2, L4)
template<int CW,int H,int W,int CO,int COB,int NX>
__global__ __launch_bounds__(256) void k_xconv_pool2(const uint32_t* __restrict__ in,
        const uint32_t* __restrict__ wb, int16_t* __restrict__ out, long long* __restrict__ part){
  constexpr int HP = H+2;
  constexpr int PITCH = W+3;          // odd
  constexpr int WP = CW*9+1;
  constexpr int NG = CO/COB;
  constexpr int XS = W/NX;
  constexpr int UNITS = (H/2)*XS;
  static_assert((COB/2)*UNITS==256, "thread mapping");
  __shared__ uint32_t inlds[CW*HP*PITCH];
  __shared__ uint32_t wlds[COB*WP];
  __shared__ int colpc[COB][10];
  int n = blockIdx.x / NG, cg = blockIdx.x % NG;
  int co0 = cg*COB;
  const uint32_t* ip = in + (size_t)n*CW*H*W;
  stage_bits<CW,H,W,HP,PITCH>(ip, inlds);
  for (int i=threadIdx.x; i<COB*CW*9; i+=256){
    int co = i/(CW*9); int r = i%(CW*9);
    wlds[co*WP + r] = wb[(size_t)(co0+co)*CW*9 + r];
  }
  __syncthreads();
  fill_bits<CW,H,W,HP,PITCH>(ip, inlds);
  for (int i=threadIdx.x; i<COB*9; i+=256){
    int co=i/9, tap=i%9; int s=0;
    #pragma unroll
    for (int cw=0;cw<CW;cw++) s += __popc(wlds[co*WP + cw*9 + tap]);
    colpc[co][tap]=s;
  }
  __syncthreads();
  int t = threadIdx.x;
  int cog = t / UNITS;
  int rem = t % UNITS;
  int yy = rem / XS;
  int xs = (rem % XS)*NX;
  int c0 = cog*2;
  int acc0[2][NX], acc1[2][NX];
  #pragma unroll
  for (int c=0;c<2;c++)
    #pragma unroll
    for (int i2=0;i2<NX;i2++){acc0[c][i2]=0;acc1[c][i2]=0;}
  for (int cw=0; cw<CW; cw++){
    uint32_t wr[2][9];
    #pragma unroll
    for (int c=0;c<2;c++)
      #pragma unroll
      for (int k=0;k<9;k++) wr[c][k]=wlds[(c0+c)*WP+cw*9+k];
    const uint32_t* ib = &inlds[cw*HP*PITCH + (2*yy)*PITCH + xs];
    { // row 0 -> acc0 (tap row 0)
      uint32_t row[NX+2];
      #pragma unroll
      for (int j=0;j<NX+2;j++) row[j] = ib[j];
      #pragma unroll
      for (int q=0;q<NX;q++)
        #pragma unroll
        for (int c=0;c<2;c++)
          acc0[c][q] += __popc(row[q]^wr[c][0])+__popc(row[q+1]^wr[c][1])+__popc(row[q+2]^wr[c][2]);
    }
    #pragma unroll
    for (int rrow=1; rrow<=2; rrow++){ // rows 1,2 -> acc0(tap rrow) + acc1(tap rrow-1)
      uint32_t row[NX+2];
      #pragma unroll
      for (int j=0;j<NX+2;j++) row[j] = ib[rrow*PITCH + j];
      #pragma unroll
      for (int q=0;q<NX;q++)
        #pragma unroll
        for (int c=0;c<2;c++){
          acc0[c][q] += __popc(row[q]^wr[c][3*rrow+0])+__popc(row[q+1]^wr[c][3*rrow+1])+__popc(row[q+2]^wr[c][3*rrow+2]);
          acc1[c][q] += __popc(row[q]^wr[c][3*rrow-3])+__popc(row[q+1]^wr[c][3*rrow-2])+__popc(row[q+2]^wr[c][3*rrow-1]);
        }
    }
    { // row 3 -> acc1 (tap row 2)
      uint32_t row[NX+2];
      #pragma unroll
      for (int j=0;j<NX+2;j++) row[j] = ib[3*PITCH + j];
      #pragma unroll
      for (int q=0;q<NX;q++)
        #pragma unroll
        for (int c=0;c<2;c++)
          acc1[c][q] += __popc(row[q]^wr[c][6])+__popc(row[q+1]^wr[c][7])+__popc(row[q+2]^wr[c][8]);
    }
  }
  #pragma unroll
  for (int c=0;c<2;c++){
    const int* cp = colpc[c0+c];
    int16_t res[NX/2];
    #pragma unroll
    for (int tp=0; tp<NX/2; tp++){
      int best=-32768;
      #pragma unroll
      for (int rrow=0;rrow<2;rrow++){
        int kyi = (rrow==0 && yy==0) ? 0 : ((rrow==1 && yy==H/2-1) ? 2 : -1);
        #pragma unroll
        for (int dx=0;dx<2;dx++){
          int q = 2*tp+dx;
          int x = xs+q;
          int kxi = (x==0)?0:((x==W-1)?2:-1);
          int acc = rrow? acc1[c][q]:acc0[c][q];
          int corr=0, nv=9;
          if (kyi>=0){ corr += cp[kyi*3+0]+cp[kyi*3+1]+cp[kyi*3+2]; }
          if (kxi>=0){ corr += cp[0+kxi]+cp[3+kxi]+cp[6+kxi]; }
          if (kyi>=0 && kxi>=0){ corr -= cp[kyi*3+kxi]; nv=4; }
          else if (kyi>=0 || kxi>=0) nv=6;
          int dot = 32*CW*nv - 2*(acc - corr);
          best = dot>best?dot:best;
        }
      }
      res[tp]=(int16_t)best;
    }
    int16_t* op = out + (((size_t)n*CO + (co0+c0+c))*(H/2) + yy)*(W/2) + xs/2;
    #pragma unroll
    for (int tp=0;tp<NX/2;tp++) op[tp]=res[tp];
    int ssum=0; long long ssq=0;
    #pragma unroll
    for (int tp=0;tp<NX/2;tp++){ int v=res[tp]; ssum+=v; ssq += (long long)(v*v); }
    long long s = (long long)ssum;
    #pragma unroll
    for (int off=UNITS>>1; off; off>>=1){ s += __shfl_down(s,off,UNITS); ssq += __shfl_down(ssq,off,UNITS); }
    if (rem==0){
      size_t pi = (size_t)(co0+c0+c)*BATCH + n;
      part[pi*2+0]=s; part[pi*2+1]=ssq;
    }
  }
}

// ---- fused conv + pool, one channel per thread (L6: COB limited by LDS)
template<int CW,int H,int W,int CO,int COB,int NX>
__global__ __launch_bounds__(256) void k_xconv_pool(const uint32_t* __restrict__ in,
        const uint32_t* __restrict__ wb, int16_t* __restrict__ out, long long* __restrict__ part){
  constexpr int HP = H+2;
  constexpr int PITCH = W+3;          // odd
  constexpr int WP = CW*9+1;
  constexpr int NG = CO/COB;
  constexpr int XS = W/NX;
  constexpr int UNITS = (H/2)*XS;
  static_assert(COB*UNITS==256, "thread mapping");
  __shared__ uint32_t inlds[CW*HP*PITCH];
  __shared__ uint32_t wlds[COB*WP];
  __shared__ int colpc[COB][10];
  int n = blockIdx.x / NG, cg = blockIdx.x % NG;
  int co0 = cg*COB;
  const uint32_t* ip = in + (size_t)n*CW*H*W;
  stage_bits<CW,H,W,HP,PITCH>(ip, inlds);
  for (int i=threadIdx.x; i<COB*CW*9; i+=256){
    int co = i/(CW*9); int r = i%(CW*9);
    wlds[co*WP + r] = wb[(size_t)(co0+co)*CW*9 + r];
  }
  __syncthreads();
  fill_bits<CW,H,W,HP,PITCH>(ip, inlds);
  for (int i=threadIdx.x; i<COB*9; i+=256){
    int co=i/9, tap=i%9; int s=0;
    #pragma unroll
    for (int cw=0;cw<CW;cw++) s += __popc(wlds[co*WP + cw*9 + tap]);
    colpc[co][tap]=s;
  }
  __syncthreads();
  int t = threadIdx.x;
  int col = t / UNITS;
  int rem = t % UNITS;
  int yy = rem / XS;
  int xs = (rem % XS)*NX;
  int co = co0 + col;
  int acc0[NX], acc1[NX];
  #pragma unroll
  for (int i2=0;i2<NX;i2++){acc0[i2]=0;acc1[i2]=0;}
  for (int cw=0; cw<CW; cw++){
    uint32_t wr[9];
    #pragma unroll
    for (int k=0;k<9;k++) wr[k]=wlds[col*WP+cw*9+k];
    const uint32_t* ib = &inlds[cw*HP*PITCH + (2*yy)*PITCH + xs];
    {
      uint32_t row[NX+2];
      #pragma unroll
      for (int j=0;j<NX+2;j++) row[j] = ib[j];
      #pragma unroll
      for (int q=0;q<NX;q++)
        acc0[q] += __popc(row[q]^wr[0])+__popc(row[q+1]^wr[1])+__popc(row[q+2]^wr[2]);
    }
    #pragma unroll
    for (int rrow=1; rrow<=2; rrow++){
      uint32_t row[NX+2];
      #pragma unroll
      for (int j=0;j<NX+2;j++) row[j] = ib[rrow*PITCH + j];
      #pragma unroll
      for (int q=0;q<NX;q++){
        acc0[q] += __popc(row[q]^wr[3*rrow+0])+__popc(row[q+1]^wr[3*rrow+1])+__popc(row[q+2]^wr[3*rrow+2]);
        acc1[q] += __popc(row[q]^wr[3*rrow-3])+__popc(row[q+1]^wr[3*rrow-2])+__popc(row[q+2]^wr[3*rrow-1]);
      }
    }
    {
      uint32_t row[NX+2];
      #pragma unroll
      for (int j=0;j<NX+2;j++) row[j] = ib[3*PITCH + j];
      #pragma unroll
      for (int q=0;q<NX;q++)
        acc1[q] += __popc(row[q]^wr[6])+__popc(row[q+1]^wr[7])+__popc(row[q+2]^wr[8]);
    }
  }
  const int* cp = colpc[col];
  int16_t res[NX/2];
  #pragma unroll
  for (int tp=0; tp<NX/2; tp++){
    int best=-32768;
    #pragma unroll
    for (int rrow=0;rrow<2;rrow++){
      int kyi = (rrow==0 && yy==0) ? 0 : ((rrow==1 && yy==H/2-1) ? 2 : -1);
      #pragma unroll
      for (int dx=0;dx<2;dx++){
        int q = 2*tp+dx;
        int x = xs+q;
        int kxi = (x==0)?0:((x==W-1)?2:-1);
        int acc = rrow? acc1[q]:acc0[q];
        int corr=0, nv=9;
        if (kyi>=0){ corr += cp[kyi*3+0]+cp[kyi*3+1]+cp[kyi*3+2]; }
        if (kxi>=0){ corr += cp[0+kxi]+cp[3+kxi]+cp[6+kxi]; }
        if (kyi>=0 && kxi>=0){ corr -= cp[kyi*3+kxi]; nv=4; }
        else if (kyi>=0 || kxi>=0) nv=6;
        int dot = 32*CW*nv - 2*(acc - corr);
        best = dot>best?dot:best;
      }
    }
    res[tp]=(int16_t)best;
  }
  int16_t* op = out + (((size_t)n*CO + co)*(H/2) + yy)*(W/2) + xs/2;
  #pragma unroll
  for (int tp=0;tp<NX/2;tp++) op[tp]=res[tp];
  int ssum=0; long long ssq=0;
  #pragma unroll
  for (int tp=0;tp<NX/2;tp++){ int v=res[tp]; ssum+=v; ssq += (long long)(v*v); }
  long long s = (long long)ssum;
  #pragma unroll
  for (int off=UNITS>>1; off; off>>=1){ s += __shfl_down(s,off,UNITS); ssq += __shfl_down(ssq,off,UNITS); }
  if (rem==0){
    size_t pi = (size_t)co*BATCH + n;
    part[pi*2+0]=s; part[pi*2+1]=ssq;
  }
}

// ---- plain conv, two channels per thread (L3, L5)
template<int CW,int H,int W,int CO,int COB,int NX>
__global__ __launch_bounds__(256) void k_xconv(const uint32_t* __restrict__ in,
        const uint32_t* __restrict__ wb, int16_t* __restrict__ out, long long* __restrict__ part){
  constexpr int HP = H+2;
  constexpr int PITCH = W+3;          // odd
  constexpr int WP = CW*9+1;
  constexpr int NG = CO/COB;
  constexpr int XS = W/NX;
  constexpr int UNITS = H*XS;
  static_assert((COB/2)*UNITS==256, "thread mapping");
  __shared__ uint32_t inlds[CW*HP*PITCH];
  __shared__ uint32_t wlds[COB*WP];
  __shared__ int colpc[COB][10];
  int n = blockIdx.x / NG, cg = blockIdx.x % NG;
  int co0 = cg*COB;
  const uint32_t* ip = in + (size_t)n*CW*H*W;
  stage_bits<CW,H,W,HP,PITCH>(ip, inlds);
  for (int i=threadIdx.x; i<COB*CW*9; i+=256){
    int co = i/(CW*9); int r = i%(CW*9);
    wlds[co*WP + r] = wb[(size_t)(co0+co)*CW*9 + r];
  }
  __syncthreads();
  fill_bits<CW,H,W,HP,PITCH>(ip, inlds);
  for (int i=threadIdx.x; i<COB*9; i+=256){
    int co=i/9, tap=i%9; int s=0;
    #pragma unroll
    for (int cw=0;cw<CW;cw++) s += __popc(wlds[co*WP + cw*9 + tap]);
    colpc[co][tap]=s;
  }
  __syncthreads();
  int t = threadIdx.x;
  int cog = t / UNITS;
  int rem = t % UNITS;
  int y = rem / XS;
  int xs = (rem % XS)*NX;
  int c0 = cog*2;
  int acc[2][NX];
  #pragma unroll
  for (int c=0;c<2;c++)
    #pragma unroll
    for (int i2=0;i2<NX;i2++) acc[c][i2]=0;
  for (int cw=0; cw<CW; cw++){
    uint32_t wr[2][9];
    #pragma unroll
    for (int c=0;c<2;c++)
      #pragma unroll
      for (int k=0;k<9;k++) wr[c][k]=wlds[(c0+c)*WP+cw*9+k];
    const uint32_t* ib = &inlds[cw*HP*PITCH + y*PITCH + xs];
    #pragma unroll
    for (int rrow=0; rrow<3; rrow++){
      uint32_t row[NX+2];
      #pragma unroll
      for (int j=0;j<NX+2;j++) row[j] = ib[rrow*PITCH + j];
      #pragma unroll
      for (int q=0;q<NX;q++){
        acc[0][q] += __popc(row[q]^wr[0][3*rrow+0])+__popc(row[q+1]^wr[0][3*rrow+1])+__popc(row[q+2]^wr[0][3*rrow+2]);
        acc[1][q] += __popc(row[q]^wr[1][3*rrow+0])+__popc(row[q+1]^wr[1][3*rrow+1])+__popc(row[q+2]^wr[1][3*rrow+2]);
      }
    }
  }
  int kyi = (y==0)?0:((y==H-1)?2:-1);
  #pragma unroll
  for (int c=0;c<2;c++){
    const int* cp = colpc[c0+c];
    int16_t rbuf[NX];
    int ssum=0; long long ssq=0;
    #pragma unroll
    for (int q=0;q<NX;q++){
      int x = xs+q;
      int kxi = (x==0)?0:((x==W-1)?2:-1);
      int corr=0, nv=9;
      if (kyi>=0){ corr += cp[kyi*3+0]+cp[kyi*3+1]+cp[kyi*3+2]; }
      if (kxi>=0){ corr += cp[0+kxi]+cp[3+kxi]+cp[6+kxi]; }
      if (kyi>=0 && kxi>=0){ corr -= cp[kyi*3+kxi]; nv=4; }
      else if (kyi>=0 || kxi>=0) nv=6;
      int dot = 32*CW*nv - 2*(acc[c][q] - corr);
      rbuf[q] = (int16_t)dot;
      ssum+=dot; ssq+=(long long)(dot*dot);
    }
    int16_t* op = out + (((size_t)n*CO + (co0+c0+c))*H + y)*W + xs;
    #pragma unroll
    for (int q=0;q<NX;q++) op[q]=rbuf[q];
    long long s=(long long)ssum, q2=ssq;
    #pragma unroll
    for (int off=UNITS>>1; off; off>>=1){ s += __shfl_down(s,off,UNITS); q2 += __shfl_down(q2,off,UNITS); }
    if (rem==0){
      size_t pi = (size_t)(co0+c0+c)*BATCH + n;
      part[pi*2+0]=s; part[pi*2+1]=q2;
    }
  }
}

// ---------------- parallel per-channel finalize from [c][256] int64 ----------------
__global__ __launch_bounds__(256) void k_chstats_fin_p(const long long* __restrict__ part,
        const float* __restrict__ g, const float* __restrict__ b,
        double* __restrict__ A, double* __restrict__ Bv, double invCount){
  int c = blockIdx.x;
  long long s  = part[((size_t)c*BATCH+threadIdx.x)*2+0];
  long long s2 = part[((size_t)c*BATCH+threadIdx.x)*2+1];
  for (int off=32; off; off>>=1){ s+=__shfl_down(s,off,64); s2+=__shfl_down(s2,off,64); }
  __shared__ long long sh[8];
  int wid=threadIdx.x>>6, lane=threadIdx.x&63;
  if(lane==0){sh[wid]=s;sh[4+wid]=s2;}
  __syncthreads();
  if(threadIdx.x==0){
    long long S=0,S2=0;
    #pragma unroll
    for(int i=0;i<4;i++){S+=sh[i];S2+=sh[4+i];}
    double m=(double)S*invCount, v=(double)S2*invCount-m*m;
    double a=(double)g[c]/sqrt(v+1e-5);
    A[c]=a; Bv[c]=(double)b[c]-m*a;
  }
}

// ---------------- binarize BN(conv) and pack ----------------
__global__ void k_binarize_pack(const int16_t* __restrict__ in, const double* __restrict__ A,
                                const double* __restrict__ Bv, uint32_t* __restrict__ bits,
                                int C, int HW){
  int CW = C>>5;
  size_t total = (size_t)BATCH*CW*HW;
  size_t idx = (size_t)blockIdx.x*256+threadIdx.x;
  if (idx>=total) return;
  int hw = (int)(idx % HW); size_t t = idx/HW;
  int cw = (int)(t % CW); int n = (int)(t / CW);
  uint32_t wordv=0;
  for (int b=0;b<32;b++){
    int c = cw*32+b;
    double v = (double)in[((size_t)n*C + c)*HW + hw];
    if (v*A[c]+Bv[c] >= 0.0) wordv |= 1u<<b;
  }
  bits[idx]=wordv;
}

// ---------------- FC1 ----------------
__global__ void k_fc1(const uint32_t* __restrict__ actbits, const uint32_t* __restrict__ wb,
                      int16_t* __restrict__ out){
  int og = blockIdx.x & 3; int n = blockIdx.x >> 2;
  int o = og*256 + threadIdx.x;
  __shared__ uint32_t sact[256];
  sact[threadIdx.x] = actbits[(size_t)n*256 + threadIdx.x];
  __syncthreads();
  const uint32_t* wp = wb + (size_t)o*256;
  int acc=0;
  #pragma unroll 8
  for (int k=0;k<256;k++) acc += __popc(sact[k]^wp[k]);
  out[(size_t)n*1024 + o] = (int16_t)(8192 - 2*acc);
}

__global__ void k_fc_stats(const int16_t* __restrict__ in, const float* __restrict__ g,
                           const float* __restrict__ b, double* __restrict__ A, double* __restrict__ Bv){
  int f = blockIdx.x;
  double v = (double)in[(size_t)threadIdx.x*1024 + f];
  double s=v, s2=v*v;
  __shared__ double sh[8];
  for (int off=32; off; off>>=1){ s+=__shfl_down(s,off,64); s2+=__shfl_down(s2,off,64); }
  int wid=threadIdx.x>>6, lane=threadIdx.x&63;
  if(lane==0){sh[wid]=s;sh[4+wid]=s2;}
  __syncthreads();
  if(threadIdx.x==0){
    double S=0,S2=0;
    #pragma unroll
    for(int i=0;i<4;i++){S+=sh[i];S2+=sh[4+i];}
    double m=S/256.0, var=S2/256.0-m*m;
    double a=(double)g[f]/sqrt(var+1e-5);
    A[f]=a; Bv[f]=(double)b[f]-m*a;
  }
}

__global__ void k_binpack_fc(const int16_t* __restrict__ in, const double* __restrict__ A,
                             const double* __restrict__ Bv, uint32_t* __restrict__ bits){
  int idx = blockIdx.x*256+threadIdx.x;
  if (idx >= 256*32) return;
  int w = idx & 31, n = idx >> 5;
  uint32_t word=0;
  for (int b=0;b<32;b++){
    int f = w*32+b;
    double v=(double)in[(size_t)n*1024+f];
    if (v*A[f]+Bv[f] >= 0.0) word|=1u<<b;
  }
  bits[idx]=word;
}

// ---------------- FC2 + final BN -> float out ----------------
__global__ void k_fc2_out(const uint32_t* __restrict__ actbits, const uint32_t* __restrict__ wb,
                          const float* __restrict__ bias2, const float* __restrict__ g,
                          const float* __restrict__ b, float* __restrict__ out){
  int o = blockIdx.x;     // 0..9
  int n = threadIdx.x;    // 0..255
  const uint32_t* ap = actbits + (size_t)n*32;
  const uint32_t* wp = wb + (size_t)o*32;
  int acc=0;
  #pragma unroll
  for (int k=0;k<32;k++) acc += __popc(ap[k]^wp[k]);
  double h = (double)(1024 - 2*acc) + (double)bias2[o];
  double s=h, s2=h*h;
  __shared__ double sh[8];
  for(int off=32;off;off>>=1){s+=__shfl_down(s,off,64);s2+=__shfl_down(s2,off,64);}
  int wid=threadIdx.x>>6,lane=threadIdx.x&63;
  if(lane==0){sh[wid]=s;sh[4+wid]=s2;}
  __syncthreads();
  __shared__ double sm, sinv;
  if(threadIdx.x==0){
    double S=0,S2=0;
    #pragma unroll
    for(int i=0;i<4;i++){S+=sh[i];S2+=sh[4+i];}
    double m=S/256.0, v=S2/256.0-m*m;
    sm=m; sinv=1.0/sqrt(v+1e-5);
  }
  __syncthreads();
  double r = (h - sm)*sinv*(double)g[o] + (double)b[o];
  out[(size_t)n*10 + o] = (float)r;
}

extern "C" void kernel_launch(void* const* d_in, const int* in_sizes, int n_in,
                              void* d_out, int out_size, void* d_ws, size_t ws_size,
                              hipStream_t stream) {
  const float* x   = (const float*)d_in[0];
  const float* w1  = (const float*)d_in[1];
  const float* g1  = (const float*)d_in[2];
  const float* b1  = (const float*)d_in[3];
  const float* w2  = (const float*)d_in[4];
  const float* g2  = (const float*)d_in[5];
  const float* b2  = (const float*)d_in[6];
  const float* w3  = (const float*)d_in[7];
  const float* g3  = (const float*)d_in[8];
  const float* b3  = (const float*)d_in[9];
  const float* w4  = (const float*)d_in[10];
  const float* g4  = (const float*)d_in[11];
  const float* b4  = (const float*)d_in[12];
  const float* w5  = (const float*)d_in[13];
  const float* g5  = (const float*)d_in[14];
  const float* b5  = (const float*)d_in[15];
  const float* w6  = (const float*)d_in[16];
  const float* g6  = (const float*)d_in[17];
  const float* b6  = (const float*)d_in[18];
  const float* wf1 = (const float*)d_in[19];
  const float* gf1 = (const float*)d_in[20];
  const float* bf1 = (const float*)d_in[21];
  const float* wf2 = (const float*)d_in[22];
  const float* bias2=(const float*)d_in[23];
  const float* gf2 = (const float*)d_in[24];
  const float* bf2 = (const float*)d_in[25];
  float* out = (float*)d_out;

  char* ws = (char*)d_ws;
  size_t off = 0;
  auto alloc = [&](size_t bytes)->char*{ char* p = ws + off; off = (off + bytes + 255) & ~(size_t)255; return p; };

  uint32_t* wb2  = (uint32_t*)alloc(4608ull*4);
  uint32_t* wb3  = (uint32_t*)alloc(9216ull*4);
  uint32_t* wb4  = (uint32_t*)alloc(18432ull*4);
  uint32_t* wb5  = (uint32_t*)alloc(36864ull*4);
  uint32_t* wb6  = (uint32_t*)alloc(73728ull*4);
  uint32_t* wf1b = (uint32_t*)alloc(262144ull*4);
  uint32_t* wf2b = (uint32_t*)alloc(320ull*4);
  double*   part = (double*)  alloc(128ull*2048*2*8);
  long long* pll = (long long*)alloc(512ull*256*2*8);
  double*   Abuf = (double*)  alloc(1024ull*8);
  double*   Bbuf = (double*)  alloc(1024ull*8);
  uint32_t* bitsA= (uint32_t*)alloc(1048576ull*4);
  uint32_t* bitsB= (uint32_t*)alloc(262144ull*4);
  int16_t*  conv = (int16_t*) alloc(16777216ull*2);

  // pack weights
  k_pack_conv_w<<<CDIV(4608,256),256,0,stream>>>(w2, wb2, 128, 4);
  k_pack_conv_w<<<CDIV(9216,256),256,0,stream>>>(w3, wb3, 256, 4);
  k_pack_conv_w<<<CDIV(18432,256),256,0,stream>>>(w4, wb4, 256, 8);
  k_pack_conv_w<<<CDIV(36864,256),256,0,stream>>>(w5, wb5, 512, 8);
  k_pack_conv_w<<<CDIV(73728,256),256,0,stream>>>(w6, wb6, 512, 16);
  k_pack_fc1_w<<<CDIV(262144,256),256,0,stream>>>(wf1, wf1b);
  k_pack_fc2_w<<<CDIV(320,256),256,0,stream>>>(wf2, wf2b);

  // ---- layer 1 ----
  k_conv1_stats3<<<1024,256,0,stream>>>(x, w1, part);
  k_finalize_partials_p<<<128,256,0,stream>>>(part, g1, b1, Abuf, Bbuf, 2048, 1.0/(256.0*1024.0));
  k_conv1_binarize4<<<1024,256,0,stream>>>(x, w1, Abuf, Bbuf, bitsA);

  // ---- layer 2: conv+pool -> [256,128,16,16] ----
  k_xconv_pool2<4,32,32,128,8,8><<<256*16,256,0,stream>>>(bitsA, wb2, conv, pll);
  k_chstats_fin_p<<<128,256,0,stream>>>(pll, g2, b2, Abuf, Bbuf, 1.0/(256.0*256.0));
  k_binarize_pack<<<CDIV(256ull*4*256,256),256,0,stream>>>(conv, Abuf, Bbuf, bitsB, 128, 256);

  // ---- layer 3: conv -> [256,256,16,16] ----
  k_xconv<4,16,16,256,16,8><<<256*16,256,0,stream>>>(bitsB, wb3, conv, pll);
  k_chstats_fin_p<<<256,256,0,stream>>>(pll, g3, b3, Abuf, Bbuf, 1.0/(256.0*256.0));
  k_binarize_pack<<<CDIV(256ull*8*256,256),256,0,stream>>>(conv, Abuf, Bbuf, bitsA, 256, 256);

  // ---- layer 4: conv+pool -> [256,256,8,8] ----
  k_xconv_pool2<8,16,16,256,32,8><<<256*8,256,0,stream>>>(bitsA, wb4, conv, pll);
  k_chstats_fin_p<<<256,256,0,stream>>>(pll, g4, b4, Abuf, Bbuf, 1.0/(256.0*64.0));
  k_binarize_pack<<<CDIV(256ull*8*64,256),256,0,stream>>>(conv, Abuf, Bbuf, bitsB, 256, 64);

  // ---- layer 5: conv -> [256,512,8,8] ----
  k_xconv<8,8,8,512,64,8><<<256*8,256,0,stream>>>(bitsB, wb5, conv, pll);
  k_chstats_fin_p<<<512,256,0,stream>>>(pll, g5, b5, Abuf, Bbuf, 1.0/(256.0*64.0));
  k_binarize_pack<<<CDIV(256ull*16*64,256),256,0,stream>>>(conv, Abuf, Bbuf, bitsA, 512, 64);

  // ---- layer 6: conv+pool -> [256,512,4,4] ----
  k_xconv_pool<16,8,8,512,64,8><<<256*8,256,0,stream>>>(bitsA, wb6, conv, pll);
  k_chstats_fin_p<<<512,256,0,stream>>>(pll, g6, b6, Abuf, Bbuf, 1.0/(256.0*16.0));
  k_binarize_pack<<<CDIV(256ull*16*16,256),256,0,stream>>>(conv, Abuf, Bbuf, bitsB, 512, 16);

  // ---- FC1 ----
  k_fc1<<<256*4,256,0,stream>>>(bitsB, wf1b, conv);
  k_fc_stats<<<1024,256,0,stream>>>(conv, gf1, bf1, Abuf, Bbuf);
  k_binpack_fc<<<CDIV(256*32,256),256,0,stream>>>(conv, Abuf, Bbuf, bitsA);

  // ---- FC2 + final BN ----
  k_fc2_out<<<10,256,0,stream>>>(bitsA, wf2b, bias2, gf2, bf2, out);

  (void)in_sizes; (void)n_in; (void)out_size; (void)ws_size;
}

// Round 14
// 667.178 us; speedup vs baseline: 1.4022x; 1.0698x over previous
//
#include <hip/hip_runtime.h>
#include <hip/hip_bf16.h>
#include <stdint.h>

static constexpr int BATCH = 256;

#define CDIV(a,b) (((a)+(b)-1)/(b))

// ---------------- weight packing ----------------
__global__ void k_pack_conv_w(const float* __restrict__ w, uint32_t* __restrict__ out, int Co, int CW){
  int idx = blockIdx.x*256 + threadIdx.x;
  int total = Co*CW*9;
  if (idx >= total) return;
  int tap = idx % 9; int t = idx / 9; int cw = t % CW; int co = t / CW;
  int Ci = CW*32;
  const float* src = w + ((size_t)co*Ci + (size_t)cw*32)*9 + tap;
  uint32_t bits = 0;
  #pragma unroll
  for (int b=0;b<32;b++) bits |= (src[(size_t)b*9] >= 0.f ? 1u:0u) << b;
  out[idx] = bits;
}

__global__ void k_pack_fc1_w(const float* __restrict__ w, uint32_t* __restrict__ out){
  int idx = blockIdx.x*256 + threadIdx.x;
  if (idx >= 1024*256) return;
  int wd = idx & 255, o = idx >> 8;
  int cw = wd >> 4, p = wd & 15;
  const float* src = w + (size_t)o*8192;
  uint32_t bits=0;
  #pragma unroll
  for (int b=0;b<32;b++) bits |= (src[(cw*32+b)*16 + p] >= 0.f ? 1u:0u) << b;
  out[idx]=bits;
}

__global__ void k_pack_fc2_w(const float* __restrict__ w, uint32_t* __restrict__ out){
  int idx = blockIdx.x*256+threadIdx.x; if (idx >= 10*32) return;
  int wd = idx & 31, o = idx >> 5;
  uint32_t bits=0;
  #pragma unroll
  for (int b=0;b<32;b++) bits |= (w[o*1024 + wd*32 + b] >= 0.f ? 1u:0u)<<b;
  out[idx]=bits;
}

// =====================================================================
// conv1 (f64-exact)
// =====================================================================
__global__ __launch_bounds__(256) void k_conv1_stats3(const float* __restrict__ x,
        const float* __restrict__ w1, double* __restrict__ partials){
  __shared__ double xs[3][10][34];
  __shared__ float wf[128][27];
  int n = blockIdx.x >> 2, rg = blockIdx.x & 3;
  int y0 = rg*8;
  const float* xp = x + (size_t)n*3*1024;
  for (int i=threadIdx.x; i<3*10*34; i+=256){
    int ci = i/340, r = i%340, ly = r/34, lx = r%34;
    int gy = y0 - 1 + ly, gx = lx - 1;
    double v = 0.0;
    if (gy>=0 && gy<32 && gx>=0 && gx<32) v = (double)xp[ci*1024 + gy*32 + gx];
    (&xs[0][0][0])[i] = v;
  }
  for (int i=threadIdx.x; i<128*27; i+=256)
    (&wf[0][0])[i] = w1[i];
  __syncthreads();
  int wave = threadIdx.x>>6, lane = threadIdx.x&63;
  int c0 = (wave&1)*64, rsub = wave>>1;
  int co = c0 + lane;
  double w[27];
  #pragma unroll
  for (int k=0;k<27;k++) w[k] = (wf[co][k] >= 0.f) ? 1.0 : -1.0;
  double s=0.0, s2=0.0;
  for (int rr = rsub*4; rr < rsub*4+4; ++rr){
    for (int xx=0; xx<32; ++xx){
      double a0=0.0, a1=0.0, a2=0.0;
      #pragma unroll
      for (int ci=0;ci<3;ci++){
        const double* r0 = &xs[ci][rr+0][xx];
        const double* r1 = &xs[ci][rr+1][xx];
        const double* r2 = &xs[ci][rr+2][xx];
        a0 += r0[0]*w[ci*9+0] + r0[1]*w[ci*9+1] + r0[2]*w[ci*9+2];
        a1 += r1[0]*w[ci*9+3] + r1[1]*w[ci*9+4] + r1[2]*w[ci*9+5];
        a2 += r2[0]*w[ci*9+6] + r2[1]*w[ci*9+7] + r2[2]*w[ci*9+8];
      }
      double acc = (a0 + a1) + a2;
      s += acc; s2 += acc*acc;
    }
  }
  size_t pi = (size_t)co*2048 + (size_t)n*8 + rg*2 + rsub;
  partials[pi*2+0]=s; partials[pi*2+1]=s2;
}

__global__ __launch_bounds__(256) void k_finalize_partials_p(const double* __restrict__ partials,
        const float* __restrict__ g, const float* __restrict__ b,
        double* __restrict__ A, double* __restrict__ Bv, int nPart, double invCount){
  int c = blockIdx.x;
  double s=0.0, s2=0.0;
  for (int i=threadIdx.x; i<nPart; i+=256){
    s  += partials[((size_t)c*nPart+i)*2+0];
    s2 += partials[((size_t)c*nPart+i)*2+1];
  }
  for (int off=32; off; off>>=1){ s+=__shfl_down(s,off,64); s2+=__shfl_down(s2,off,64); }
  __shared__ double sh[8];
  int wid=threadIdx.x>>6, lane=threadIdx.x&63;
  if(lane==0){sh[wid]=s;sh[4+wid]=s2;}
  __syncthreads();
  if(threadIdx.x==0){
    double S=0,S2=0;
    #pragma unroll
    for(int i=0;i<4;i++){S+=sh[i];S2+=sh[4+i];}
    double m=S*invCount, v=S2*invCount-m*m;
    double a=(double)g[c]/sqrt(v+1e-5);
    A[c]=a; Bv[c]=(double)b[c]-m*a;
  }
}

// binarize: grid 2048 = (n, rowgroup of 4 rows). Quad-pixel inner loop
// (4 indep f64 FMA chains, shared row reads), per-pixel __ballot pack.
__global__ __launch_bounds__(256) void k_conv1_binarize5(const float* __restrict__ x,
        const float* __restrict__ w1, const double* __restrict__ A, const double* __restrict__ Bv,
        uint32_t* __restrict__ bits){
  __shared__ double xs[3][6][34];
  __shared__ float wf[128][27];
  __shared__ uint32_t wordbuf[4][128];
  int n = blockIdx.x >> 3, rg = blockIdx.x & 7;
  int y0 = rg*4;
  const float* xp = x + (size_t)n*3*1024;
  for (int i=threadIdx.x; i<3*6*34; i+=256){
    int ci = i/204, r = i%204, ly = r/34, lx = r%34;
    int gy = y0 - 1 + ly, gx = lx - 1;
    double v = 0.0;
    if (gy>=0 && gy<32 && gx>=0 && gx<32) v = (double)xp[ci*1024 + gy*32 + gx];
    (&xs[0][0][0])[i] = v;
  }
  for (int i=threadIdx.x; i<128*27; i+=256)
    (&wf[0][0])[i] = w1[i];
  __syncthreads();
  int wave = threadIdx.x>>6, lane = threadIdx.x&63;
  int c0 = (wave&1)*64, rsub = wave>>1;
  int co = c0 + lane;
  double w[27];
  #pragma unroll
  for (int k=0;k<27;k++) w[k] = (wf[co][k] >= 0.f) ? 1.0 : -1.0;
  double av = A[co], bv = Bv[co];
  for (int rr = rsub*2; rr < rsub*2+2; ++rr){
    for (int x0=0; x0<32; x0+=4){
      double acc[4] = {0,0,0,0};
      #pragma unroll
      for (int ci=0;ci<3;ci++)
        #pragma unroll
        for (int ky=0;ky<3;ky++){
          const double* r = &xs[ci][rr+ky][x0];
          double v0=r[0],v1=r[1],v2=r[2],v3=r[3],v4=r[4],v5=r[5];
          double w0=w[ci*9+ky*3+0], w1v=w[ci*9+ky*3+1], w2=w[ci*9+ky*3+2];
          acc[0] += v0*w0 + v1*w1v + v2*w2;
          acc[1] += v1*w0 + v2*w1v + v3*w2;
          acc[2] += v2*w0 + v3*w1v + v4*w2;
          acc[3] += v3*w0 + v4*w1v + v5*w2;
        }
      #pragma unroll
      for (int j=0;j<4;j++){
        int pred = (acc[j]*av + bv >= 0.0) ? 1 : 0;
        unsigned long long m = __ballot(pred);
        if (lane == 0){
          int p = rr*32 + x0 + j;
          wordbuf[(c0>>5)+0][p] = (uint32_t)m;
          wordbuf[(c0>>5)+1][p] = (uint32_t)(m>>32);
        }
      }
    }
  }
  __syncthreads();
  for (int i=threadIdx.x; i<512; i+=256){
    int cw = i>>7, p = i&127;
    bits[(size_t)n*4096 + cw*1024 + rg*128 + p] = wordbuf[cw][p];
  }
}

// =====================================================================
// XNOR conv family: zero+fill staging (pow2 shifts only), odd PITCH,
// row-wise inner loop, fused exact int64 stats.
// =====================================================================
template<int CW,int H,int W,int HP,int PITCH>
__device__ __forceinline__ void stage_bits(const uint32_t* __restrict__ ip, uint32_t* __restrict__ inlds){
  for (int i=threadIdx.x; i<CW*HP*PITCH; i+=256) inlds[i]=0u;
}

template<int CW,int H,int W,int HP,int PITCH>
__device__ __forceinline__ void fill_bits(const uint32_t* __restrict__ ip, uint32_t* __restrict__ inlds){
  constexpr int LOGW  = (W==32)?5:(W==16)?4:3;
  constexpr int LOGHW = ((H*W)==1024)?10:((H*W)==256)?8:6;
  for (int i=threadIdx.x; i<CW*H*W; i+=256){
    int cw = i >> LOGHW;
    int rem = i & (H*W-1);
    int y = rem >> LOGW;
    int x = rem & (W-1);
    inlds[cw*HP*PITCH + (y+1)*PITCH + (x+1)] = ip[i];
  }
}

// ---- fused conv + pool, TWO output channels per thread (L2, L4)
template<int CW,int H,int W,int CO,int COB,int NX>
__global__ __launch_bounds__(256) void k_xconv_pool2(const uint32_t* __restrict__ in,
        const uint32_t* __restrict__ wb, int16_t* __restrict__ out, long long* __restrict__ part){
  constexpr int HP = H+2;
  constexpr int PITCH = W+3;          // odd
  constexpr int WP = CW*9+1;
  constexpr int NG = CO/COB;
  constexpr int XS = W/NX;
  constexpr int UNITS = (H/2)*XS;
  static_assert((COB/2)*UNITS==256, "thread mapping");
  __shared__ uint32_t inlds[CW*HP*PITCH];
  __shared__ uint32_t wlds[COB*WP];
  __shared__ int colpc[COB][10];
  int n = blockIdx.x / NG, cg = blockIdx.x % NG;
  int co0 = cg*COB;
  const uint32_t* ip = in + (size_t)n*CW*H*W;
  stage_bits<CW,H,W,HP,PITCH>(ip, inlds);
  for (int i=threadIdx.x; i<COB*CW*9; i+=256){
    int co = i/(CW*9); int r = i%(CW*9);
    wlds[co*WP + r] = wb[(size_t)(co0+co)*CW*9 + r];
  }
  __syncthreads();
  fill_bits<CW,H,W,HP,PITCH>(ip, inlds);
  for (int i=threadIdx.x; i<COB*9; i+=256){
    int co=i/9, tap=i%9; int s=0;
    #pragma unroll
    for (int cw=0;cw<CW;cw++) s += __popc(wlds[co*WP + cw*9 + tap]);
    colpc[co][tap]=s;
  }
  __syncthreads();
  int t = threadIdx.x;
  int cog = t / UNITS;
  int rem = t % UNITS;
  int yy = rem / XS;
  int xs = (rem % XS)*NX;
  int c0 = cog*2;
  int acc0[2][NX], acc1[2][NX];
  #pragma unroll
  for (int c=0;c<2;c++)
    #pragma unroll
    for (int i2=0;i2<NX;i2++){acc0[c][i2]=0;acc1[c][i2]=0;}
  for (int cw=0; cw<CW; cw++){
    uint32_t wr[2][9];
    #pragma unroll
    for (int c=0;c<2;c++)
      #pragma unroll
      for (int k=0;k<9;k++) wr[c][k]=wlds[(c0+c)*WP+cw*9+k];
    const uint32_t* ib = &inlds[cw*HP*PITCH + (2*yy)*PITCH + xs];
    {
      uint32_t row[NX+2];
      #pragma unroll
      for (int j=0;j<NX+2;j++) row[j] = ib[j];
      #pragma unroll
      for (int q=0;q<NX;q++)
        #pragma unroll
        for (int c=0;c<2;c++)
          acc0[c][q] += __popc(row[q]^wr[c][0])+__popc(row[q+1]^wr[c][1])+__popc(row[q+2]^wr[c][2]);
    }
    #pragma unroll
    for (int rrow=1; rrow<=2; rrow++){
      uint32_t row[NX+2];
      #pragma unroll
      for (int j=0;j<NX+2;j++) row[j] = ib[rrow*PITCH + j];
      #pragma unroll
      for (int q=0;q<NX;q++)
        #pragma unroll
        for (int c=0;c<2;c++){
          acc0[c][q] += __popc(row[q]^wr[c][3*rrow+0])+__popc(row[q+1]^wr[c][3*rrow+1])+__popc(row[q+2]^wr[c][3*rrow+2]);
          acc1[c][q] += __popc(row[q]^wr[c][3*rrow-3])+__popc(row[q+1]^wr[c][3*rrow-2])+__popc(row[q+2]^wr[c][3*rrow-1]);
        }
    }
    {
      uint32_t row[NX+2];
      #pragma unroll
      for (int j=0;j<NX+2;j++) row[j] = ib[3*PITCH + j];
      #pragma unroll
      for (int q=0;q<NX;q++)
        #pragma unroll
        for (int c=0;c<2;c++)
          acc1[c][q] += __popc(row[q]^wr[c][6])+__popc(row[q+1]^wr[c][7])+__popc(row[q+2]^wr[c][8]);
    }
  }
  #pragma unroll
  for (int c=0;c<2;c++){
    const int* cp = colpc[c0+c];
    int16_t res[NX/2];
    #pragma unroll
    for (int tp=0; tp<NX/2; tp++){
      int best=-32768;
      #pragma unroll
      for (int rrow=0;rrow<2;rrow++){
        int kyi = (rrow==0 && yy==0) ? 0 : ((rrow==1 && yy==H/2-1) ? 2 : -1);
        #pragma unroll
        for (int dx=0;dx<2;dx++){
          int q = 2*tp+dx;
          int x = xs+q;
          int kxi = (x==0)?0:((x==W-1)?2:-1);
          int acc = rrow? acc1[c][q]:acc0[c][q];
          int corr=0, nv=9;
          if (kyi>=0){ corr += cp[kyi*3+0]+cp[kyi*3+1]+cp[kyi*3+2]; }
          if (kxi>=0){ corr += cp[0+kxi]+cp[3+kxi]+cp[6+kxi]; }
          if (kyi>=0 && kxi>=0){ corr -= cp[kyi*3+kxi]; nv=4; }
          else if (kyi>=0 || kxi>=0) nv=6;
          int dot = 32*CW*nv - 2*(acc - corr);
          best = dot>best?dot:best;
        }
      }
      res[tp]=(int16_t)best;
    }
    int16_t* op = out + (((size_t)n*CO + (co0+c0+c))*(H/2) + yy)*(W/2) + xs/2;
    #pragma unroll
    for (int tp=0;tp<NX/2;tp++) op[tp]=res[tp];
    int ssum=0; long long ssq=0;
    #pragma unroll
    for (int tp=0;tp<NX/2;tp++){ int v=res[tp]; ssum+=v; ssq += (long long)(v*v); }
    long long s = (long long)ssum;
    #pragma unroll
    for (int off=UNITS>>1; off; off>>=1){ s += __shfl_down(s,off,UNITS); ssq += __shfl_down(ssq,off,UNITS); }
    if (rem==0){
      size_t pi = (size_t)(co0+c0+c)*BATCH + n;
      part[pi*2+0]=s; part[pi*2+1]=ssq;
    }
  }
}

// ---- fused conv + pool, one channel per thread (L6)
template<int CW,int H,int W,int CO,int COB,int NX>
__global__ __launch_bounds__(256) void k_xconv_pool(const uint32_t* __restrict__ in,
        const uint32_t* __restrict__ wb, int16_t* __restrict__ out, long long* __restrict__ part){
  constexpr int HP = H+2;
  constexpr int PITCH = W+3;          // odd
  constexpr int WP = CW*9+1;
  constexpr int NG = CO/COB;
  constexpr int XS = W/NX;
  constexpr int UNITS = (H/2)*XS;
  static_assert(COB*UNITS==256, "thread mapping");
  __shared__ uint32_t inlds[CW*HP*PITCH];
  __shared__ uint32_t wlds[COB*WP];
  __shared__ int colpc[COB][10];
  int n = blockIdx.x / NG, cg = blockIdx.x % NG;
  int co0 = cg*COB;
  const uint32_t* ip = in + (size_t)n*CW*H*W;
  stage_bits<CW,H,W,HP,PITCH>(ip, inlds);
  for (int i=threadIdx.x; i<COB*CW*9; i+=256){
    int co = i/(CW*9); int r = i%(CW*9);
    wlds[co*WP + r] = wb[(size_t)(co0+co)*CW*9 + r];
  }
  __syncthreads();
  fill_bits<CW,H,W,HP,PITCH>(ip, inlds);
  for (int i=threadIdx.x; i<COB*9; i+=256){
    int co=i/9, tap=i%9; int s=0;
    #pragma unroll
    for (int cw=0;cw<CW;cw++) s += __popc(wlds[co*WP + cw*9 + tap]);
    colpc[co][tap]=s;
  }
  __syncthreads();
  int t = threadIdx.x;
  int col = t / UNITS;
  int rem = t % UNITS;
  int yy = rem / XS;
  int xs = (rem % XS)*NX;
  int co = co0 + col;
  int acc0[NX], acc1[NX];
  #pragma unroll
  for (int i2=0;i2<NX;i2++){acc0[i2]=0;acc1[i2]=0;}
  for (int cw=0; cw<CW; cw++){
    uint32_t wr[9];
    #pragma unroll
    for (int k=0;k<9;k++) wr[k]=wlds[col*WP+cw*9+k];
    const uint32_t* ib = &inlds[cw*HP*PITCH + (2*yy)*PITCH + xs];
    {
      uint32_t row[NX+2];
      #pragma unroll
      for (int j=0;j<NX+2;j++) row[j] = ib[j];
      #pragma unroll
      for (int q=0;q<NX;q++)
        acc0[q] += __popc(row[q]^wr[0])+__popc(row[q+1]^wr[1])+__popc(row[q+2]^wr[2]);
    }
    #pragma unroll
    for (int rrow=1; rrow<=2; rrow++){
      uint32_t row[NX+2];
      #pragma unroll
      for (int j=0;j<NX+2;j++) row[j] = ib[rrow*PITCH + j];
      #pragma unroll
      for (int q=0;q<NX;q++){
        acc0[q] += __popc(row[q]^wr[3*rrow+0])+__popc(row[q+1]^wr[3*rrow+1])+__popc(row[q+2]^wr[3*rrow+2]);
        acc1[q] += __popc(row[q]^wr[3*rrow-3])+__popc(row[q+1]^wr[3*rrow-2])+__popc(row[q+2]^wr[3*rrow-1]);
      }
    }
    {
      uint32_t row[NX+2];
      #pragma unroll
      for (int j=0;j<NX+2;j++) row[j] = ib[3*PITCH + j];
      #pragma unroll
      for (int q=0;q<NX;q++)
        acc1[q] += __popc(row[q]^wr[6])+__popc(row[q+1]^wr[7])+__popc(row[q+2]^wr[8]);
    }
  }
  const int* cp = colpc[col];
  int16_t res[NX/2];
  #pragma unroll
  for (int tp=0; tp<NX/2; tp++){
    int best=-32768;
    #pragma unroll
    for (int rrow=0;rrow<2;rrow++){
      int kyi = (rrow==0 && yy==0) ? 0 : ((rrow==1 && yy==H/2-1) ? 2 : -1);
      #pragma unroll
      for (int dx=0;dx<2;dx++){
        int q = 2*tp+dx;
        int x = xs+q;
        int kxi = (x==0)?0:((x==W-1)?2:-1);
        int acc = rrow? acc1[q]:acc0[q];
        int corr=0, nv=9;
        if (kyi>=0){ corr += cp[kyi*3+0]+cp[kyi*3+1]+cp[kyi*3+2]; }
        if (kxi>=0){ corr += cp[0+kxi]+cp[3+kxi]+cp[6+kxi]; }
        if (kyi>=0 && kxi>=0){ corr -= cp[kyi*3+kxi]; nv=4; }
        else if (kyi>=0 || kxi>=0) nv=6;
        int dot = 32*CW*nv - 2*(acc - corr);
        best = dot>best?dot:best;
      }
    }
    res[tp]=(int16_t)best;
  }
  int16_t* op = out + (((size_t)n*CO + co)*(H/2) + yy)*(W/2) + xs/2;
  #pragma unroll
  for (int tp=0;tp<NX/2;tp++) op[tp]=res[tp];
  int ssum=0; long long ssq=0;
  #pragma unroll
  for (int tp=0;tp<NX/2;tp++){ int v=res[tp]; ssum+=v; ssq += (long long)(v*v); }
  long long s = (long long)ssum;
  #pragma unroll
  for (int off=UNITS>>1; off; off>>=1){ s += __shfl_down(s,off,UNITS); ssq += __shfl_down(ssq,off,UNITS); }
  if (rem==0){
    size_t pi = (size_t)co*BATCH + n;
    part[pi*2+0]=s; part[pi*2+1]=ssq;
  }
}

// ---- plain conv, two channels per thread (L3, L5)
template<int CW,int H,int W,int CO,int COB,int NX>
__global__ __launch_bounds__(256) void k_xconv(const uint32_t* __restrict__ in,
        const uint32_t* __restrict__ wb, int16_t* __restrict__ out, long long* __restrict__ part){
  constexpr int HP = H+2;
  constexpr int PITCH = W+3;          // odd
  constexpr int WP = CW*9+1;
  constexpr int NG = CO/COB;
  constexpr int XS = W/NX;
  constexpr int UNITS = H*XS;
  static_assert((COB/2)*UNITS==256, "thread mapping");
  __shared__ uint32_t inlds[CW*HP*PITCH];
  __shared__ uint32_t wlds[COB*WP];
  __shared__ int colpc[COB][10];
  int n = blockIdx.x / NG, cg = blockIdx.x % NG;
  int co0 = cg*COB;
  const uint32_t* ip = in + (size_t)n*CW*H*W;
  stage_bits<CW,H,W,HP,PITCH>(ip, inlds);
  for (int i=threadIdx.x; i<COB*CW*9; i+=256){
    int co = i/(CW*9); int r = i%(CW*9);
    wlds[co*WP + r] = wb[(size_t)(co0+co)*CW*9 + r];
  }
  __syncthreads();
  fill_bits<CW,H,W,HP,PITCH>(ip, inlds);
  for (int i=threadIdx.x; i<COB*9; i+=256){
    int co=i/9, tap=i%9; int s=0;
    #pragma unroll
    for (int cw=0;cw<CW;cw++) s += __popc(wlds[co*WP + cw*9 + tap]);
    colpc[co][tap]=s;
  }
  __syncthreads();
  int t = threadIdx.x;
  int cog = t / UNITS;
  int rem = t % UNITS;
  int y = rem / XS;
  int xs = (rem % XS)*NX;
  int c0 = cog*2;
  int acc[2][NX];
  #pragma unroll
  for (int c=0;c<2;c++)
    #pragma unroll
    for (int i2=0;i2<NX;i2++) acc[c][i2]=0;
  for (int cw=0; cw<CW; cw++){
    uint32_t wr[2][9];
    #pragma unroll
    for (int c=0;c<2;c++)
      #pragma unroll
      for (int k=0;k<9;k++) wr[c][k]=wlds[(c0+c)*WP+cw*9+k];
    const uint32_t* ib = &inlds[cw*HP*PITCH + y*PITCH + xs];
    #pragma unroll
    for (int rrow=0; rrow<3; rrow++){
      uint32_t row[NX+2];
      #pragma unroll
      for (int j=0;j<NX+2;j++) row[j] = ib[rrow*PITCH + j];
      #pragma unroll
      for (int q=0;q<NX;q++){
        acc[0][q] += __popc(row[q]^wr[0][3*rrow+0])+__popc(row[q+1]^wr[0][3*rrow+1])+__popc(row[q+2]^wr[0][3*rrow+2]);
        acc[1][q] += __popc(row[q]^wr[1][3*rrow+0])+__popc(row[q+1]^wr[1][3*rrow+1])+__popc(row[q+2]^wr[1][3*rrow+2]);
      }
    }
  }
  int kyi = (y==0)?0:((y==H-1)?2:-1);
  #pragma unroll
  for (int c=0;c<2;c++){
    const int* cp = colpc[c0+c];
    int16_t rbuf[NX];
    int ssum=0; long long ssq=0;
    #pragma unroll
    for (int q=0;q<NX;q++){
      int x = xs+q;
      int kxi = (x==0)?0:((x==W-1)?2:-1);
      int corr=0, nv=9;
      if (kyi>=0){ corr += cp[kyi*3+0]+cp[kyi*3+1]+cp[kyi*3+2]; }
      if (kxi>=0){ corr += cp[0+kxi]+cp[3+kxi]+cp[6+kxi]; }
      if (kyi>=0 && kxi>=0){ corr -= cp[kyi*3+kxi]; nv=4; }
      else if (kyi>=0 || kxi>=0) nv=6;
      int dot = 32*CW*nv - 2*(acc[c][q] - corr);
      rbuf[q] = (int16_t)dot;
      ssum+=dot; ssq+=(long long)(dot*dot);
    }
    int16_t* op = out + (((size_t)n*CO + (co0+c0+c))*H + y)*W + xs;
    #pragma unroll
    for (int q=0;q<NX;q++) op[q]=rbuf[q];
    long long s=(long long)ssum, q2=ssq;
    #pragma unroll
    for (int off=UNITS>>1; off; off>>=1){ s += __shfl_down(s,off,UNITS); q2 += __shfl_down(q2,off,UNITS); }
    if (rem==0){
      size_t pi = (size_t)(co0+c0+c)*BATCH + n;
      part[pi*2+0]=s; part[pi*2+1]=q2;
    }
  }
}

// ---------------- parallel per-channel finalize from [c][256] int64 ----------------
__global__ __launch_bounds__(256) void k_chstats_fin_p(const long long* __restrict__ part,
        const float* __restrict__ g, const float* __restrict__ b,
        double* __restrict__ A, double* __restrict__ Bv, double invCount){
  int c = blockIdx.x;
  long long s  = part[((size_t)c*BATCH+threadIdx.x)*2+0];
  long long s2 = part[((size_t)c*BATCH+threadIdx.x)*2+1];
  for (int off=32; off; off>>=1){ s+=__shfl_down(s,off,64); s2+=__shfl_down(s2,off,64); }
  __shared__ long long sh[8];
  int wid=threadIdx.x>>6, lane=threadIdx.x&63;
  if(lane==0){sh[wid]=s;sh[4+wid]=s2;}
  __syncthreads();
  if(threadIdx.x==0){
    long long S=0,S2=0;
    #pragma unroll
    for(int i=0;i<4;i++){S+=sh[i];S2+=sh[4+i];}
    double m=(double)S*invCount, v=(double)S2*invCount-m*m;
    double a=(double)g[c]/sqrt(v+1e-5);
    A[c]=a; Bv[c]=(double)b[c]-m*a;
  }
}

// ---------------- binarize BN(conv) and pack ----------------
__global__ void k_binarize_pack(const int16_t* __restrict__ in, const double* __restrict__ A,
                                const double* __restrict__ Bv, uint32_t* __restrict__ bits,
                                int C, int HW){
  int CW = C>>5;
  size_t total = (size_t)BATCH*CW*HW;
  size_t idx = (size_t)blockIdx.x*256+threadIdx.x;
  if (idx>=total) return;
  int hw = (int)(idx % HW); size_t t = idx/HW;
  int cw = (int)(t % CW); int n = (int)(t / CW);
  uint32_t wordv=0;
  for (int b=0;b<32;b++){
    int c = cw*32+b;
    double v = (double)in[((size_t)n*C + c)*HW + hw];
    if (v*A[c]+Bv[c] >= 0.0) wordv |= 1u<<b;
  }
  bits[idx]=wordv;
}

// ---------------- FC1 ----------------
__global__ void k_fc1(const uint32_t* __restrict__ actbits, const uint32_t* __restrict__ wb,
                      int16_t* __restrict__ out){
  int og = blockIdx.x & 3; int n = blockIdx.x >> 2;
  int o = og*256 + threadIdx.x;
  __shared__ uint32_t sact[256];
  sact[threadIdx.x] = actbits[(size_t)n*256 + threadIdx.x];
  __syncthreads();
  const uint32_t* wp = wb + (size_t)o*256;
  int acc=0;
  #pragma unroll 8
  for (int k=0;k<256;k++) acc += __popc(sact[k]^wp[k]);
  out[(size_t)n*1024 + o] = (int16_t)(8192 - 2*acc);
}

__global__ void k_fc_stats(const int16_t* __restrict__ in, const float* __restrict__ g,
                           const float* __restrict__ b, double* __restrict__ A, double* __restrict__ Bv){
  int f = blockIdx.x;
  double v = (double)in[(size_t)threadIdx.x*1024 + f];
  double s=v, s2=v*v;
  __shared__ double sh[8];
  for (int off=32; off; off>>=1){ s+=__shfl_down(s,off,64); s2+=__shfl_down(s2,off,64); }
  int wid=threadIdx.x>>6, lane=threadIdx.x&63;
  if(lane==0){sh[wid]=s;sh[4+wid]=s2;}
  __syncthreads();
  if(threadIdx.x==0){
    double S=0,S2=0;
    #pragma unroll
    for(int i=0;i<4;i++){S+=sh[i];S2+=sh[4+i];}
    double m=S/256.0, var=S2/256.0-m*m;
    double a=(double)g[f]/sqrt(var+1e-5);
    A[f]=a; Bv[f]=(double)b[f]-m*a;
  }
}

__global__ void k_binpack_fc(const int16_t* __restrict__ in, const double* __restrict__ A,
                             const double* __restrict__ Bv, uint32_t* __restrict__ bits){
  int idx = blockIdx.x*256+threadIdx.x;
  if (idx >= 256*32) return;
  int w = idx & 31, n = idx >> 5;
  uint32_t word=0;
  for (int b=0;b<32;b++){
    int f = w*32+b;
    double v=(double)in[(size_t)n*1024+f];
    if (v*A[f]+Bv[f] >= 0.0) word|=1u<<b;
  }
  bits[idx]=word;
}

// ---------------- FC2 + final BN -> float out ----------------
__global__ void k_fc2_out(const uint32_t* __restrict__ actbits, const uint32_t* __restrict__ wb,
                          const float* __restrict__ bias2, const float* __restrict__ g,
                          const float* __restrict__ b, float* __restrict__ out){
  int o = blockIdx.x;     // 0..9
  int n = threadIdx.x;    // 0..255
  const uint32_t* ap = actbits + (size_t)n*32;
  const uint32_t* wp = wb + (size_t)o*32;
  int acc=0;
  #pragma unroll
  for (int k=0;k<32;k++) acc += __popc(ap[k]^wp[k]);
  double h = (double)(1024 - 2*acc) + (double)bias2[o];
  double s=h, s2=h*h;
  __shared__ double sh[8];
  for(int off=32;off;off>>=1){s+=__shfl_down(s,off,64);s2+=__shfl_down(s2,off,64);}
  int wid=threadIdx.x>>6,lane=threadIdx.x&63;
  if(lane==0){sh[wid]=s;sh[4+wid]=s2;}
  __syncthreads();
  __shared__ double sm, sinv;
  if(threadIdx.x==0){
    double S=0,S2=0;
    #pragma unroll
    for(int i=0;i<4;i++){S+=sh[i];S2+=sh[4+i];}
    double m=S/256.0, v=S2/256.0-m*m;
    sm=m; sinv=1.0/sqrt(v+1e-5);
  }
  __syncthreads();
  double r = (h - sm)*sinv*(double)g[o] + (double)b[o];
  out[(size_t)n*10 + o] = (float)r;
}

extern "C" void kernel_launch(void* const* d_in, const int* in_sizes, int n_in,
                              void* d_out, int out_size, void* d_ws, size_t ws_size,
                              hipStream_t stream) {
  const float* x   = (const float*)d_in[0];
  const float* w1  = (const float*)d_in[1];
  const float* g1  = (const float*)d_in[2];
  const float* b1  = (const float*)d_in[3];
  const float* w2  = (const float*)d_in[4];
  const float* g2  = (const float*)d_in[5];
  const float* b2  = (const float*)d_in[6];
  const float* w3  = (const float*)d_in[7];
  const float* g3  = (const float*)d_in[8];
  const float* b3  = (const float*)d_in[9];
  const float* w4  = (const float*)d_in[10];
  const float* g4  = (const float*)d_in[11];
  const float* b4  = (const float*)d_in[12];
  const float* w5  = (const float*)d_in[13];
  const float* g5  = (const float*)d_in[14];
  const float* b5  = (const float*)d_in[15];
  const float* w6  = (const float*)d_in[16];
  const float* g6  = (const float*)d_in[17];
  const float* b6  = (const float*)d_in[18];
  const float* wf1 = (const float*)d_in[19];
  const float* gf1 = (const float*)d_in[20];
  const float* bf1 = (const float*)d_in[21];
  const float* wf2 = (const float*)d_in[22];
  const float* bias2=(const float*)d_in[23];
  const float* gf2 = (const float*)d_in[24];
  const float* bf2 = (const float*)d_in[25];
  float* out = (float*)d_out;

  char* ws = (char*)d_ws;
  size_t off = 0;
  auto alloc = [&](size_t bytes)->char*{ char* p = ws + off; off = (off + bytes + 255) & ~(size_t)255; return p; };

  uint32_t* wb2  = (uint32_t*)alloc(4608ull*4);
  uint32_t* wb3  = (uint32_t*)alloc(9216ull*4);
  uint32_t* wb4  = (uint32_t*)alloc(18432ull*4);
  uint32_t* wb5  = (uint32_t*)alloc(36864ull*4);
  uint32_t* wb6  = (uint32_t*)alloc(73728ull*4);
  uint32_t* wf1b = (uint32_t*)alloc(262144ull*4);
  uint32_t* wf2b = (uint32_t*)alloc(320ull*4);
  double*   part = (double*)  alloc(128ull*2048*2*8);
  long long* pll = (long long*)alloc(512ull*256*2*8);
  double*   Abuf = (double*)  alloc(1024ull*8);
  double*   Bbuf = (double*)  alloc(1024ull*8);
  uint32_t* bitsA= (uint32_t*)alloc(1048576ull*4);
  uint32_t* bitsB= (uint32_t*)alloc(262144ull*4);
  int16_t*  conv = (int16_t*) alloc(16777216ull*2);

  // pack weights
  k_pack_conv_w<<<CDIV(4608,256),256,0,stream>>>(w2, wb2, 128, 4);
  k_pack_conv_w<<<CDIV(9216,256),256,0,stream>>>(w3, wb3, 256, 4);
  k_pack_conv_w<<<CDIV(18432,256),256,0,stream>>>(w4, wb4, 256, 8);
  k_pack_conv_w<<<CDIV(36864,256),256,0,stream>>>(w5, wb5, 512, 8);
  k_pack_conv_w<<<CDIV(73728,256),256,0,stream>>>(w6, wb6, 512, 16);
  k_pack_fc1_w<<<CDIV(262144,256),256,0,stream>>>(wf1, wf1b);
  k_pack_fc2_w<<<CDIV(320,256),256,0,stream>>>(wf2, wf2b);

  // ---- layer 1 ----
  k_conv1_stats3<<<1024,256,0,stream>>>(x, w1, part);
  k_finalize_partials_p<<<128,256,0,stream>>>(part, g1, b1, Abuf, Bbuf, 2048, 1.0/(256.0*1024.0));
  k_conv1_binarize5<<<2048,256,0,stream>>>(x, w1, Abuf, Bbuf, bitsA);

  // ---- layer 2: conv+pool -> [256,128,16,16] ----
  k_xconv_pool2<4,32,32,128,8,8><<<256*16,256,0,stream>>>(bitsA, wb2, conv, pll);
  k_chstats_fin_p<<<128,256,0,stream>>>(pll, g2, b2, Abuf, Bbuf, 1.0/(256.0*256.0));
  k_binarize_pack<<<CDIV(256ull*4*256,256),256,0,stream>>>(conv, Abuf, Bbuf, bitsB, 128, 256);

  // ---- layer 3: conv -> [256,256,16,16] ----
  k_xconv<4,16,16,256,16,8><<<256*16,256,0,stream>>>(bitsB, wb3, conv, pll);
  k_chstats_fin_p<<<256,256,0,stream>>>(pll, g3, b3, Abuf, Bbuf, 1.0/(256.0*256.0));
  k_binarize_pack<<<CDIV(256ull*8*256,256),256,0,stream>>>(conv, Abuf, Bbuf, bitsA, 256, 256);

  // ---- layer 4: conv+pool -> [256,256,8,8] ----
  k_xconv_pool2<8,16,16,256,32,8><<<256*8,256,0,stream>>>(bitsA, wb4, conv, pll);
  k_chstats_fin_p<<<256,256,0,stream>>>(pll, g4, b4, Abuf, Bbuf, 1.0/(256.0*64.0));
  k_binarize_pack<<<CDIV(256ull*8*64,256),256,0,stream>>>(conv, Abuf, Bbuf, bitsB, 256, 64);

  // ---- layer 5: conv -> [256,512,8,8] ----
  k_xconv<8,8,8,512,64,8><<<256*8,256,0,stream>>>(bitsB, wb5, conv, pll);
  k_chstats_fin_p<<<512,256,0,stream>>>(pll, g5, b5, Abuf, Bbuf, 1.0/(256.0*64.0));
  k_binarize_pack<<<CDIV(256ull*16*64,256),256,0,stream>>>(conv, Abuf, Bbuf, bitsA, 512, 64);

  // ---- layer 6: conv+pool -> [256,512,4,4] ----
  k_xconv_pool<16,8,8,512,64,8><<<256*8,256,0,stream>>>(bitsA, wb6, conv, pll);
  k_chstats_fin_p<<<512,256,0,stream>>>(pll, g6, b6, Abuf, Bbuf, 1.0/(256.0*16.0));
  k_binarize_pack<<<CDIV(256ull*16*16,256),256,0,stream>>>(conv, Abuf, Bbuf, bitsB, 512, 16);

  // ---- FC1 ----
  k_fc1<<<256*4,256,0,stream>>>(bitsB, wf1b, conv);
  k_fc_stats<<<1024,256,0,stream>>>(conv, gf1, bf1, Abuf, Bbuf);
  k_binpack_fc<<<CDIV(256*32,256),256,0,stream>>>(conv, Abuf, Bbuf, bitsA);

  // ---- FC2 + final BN ----
  k_fc2_out<<<10,256,0,stream>>>(bitsA, wf2b, bias2, gf2, bf2, out);

  (void)in_sizes; (void)n_in; (void)out_size; (void)ws_size;
}

// Round 15
// 634.557 us; speedup vs baseline: 1.4743x; 1.0514x over previous
//
#include <hip/hip_runtime.h>
#include <hip/hip_bf16.h>
#include <stdint.h>

static constexpr int BATCH = 256;

#define CDIV(a,b) (((a)+(b)-1)/(b))

// fused-accumulate popcount MAC: matches v_bcnt_u32_b32 dst, src, accum
__device__ __forceinline__ int BMAC(uint32_t a, uint32_t b, int acc){
  return (int)__popc(a^b) + acc;
}

// ---------------- weight packing ----------------
__global__ void k_pack_conv_w(const float* __restrict__ w, uint32_t* __restrict__ out, int Co, int CW){
  int idx = blockIdx.x*256 + threadIdx.x;
  int total = Co*CW*9;
  if (idx >= total) return;
  int tap = idx % 9; int t = idx / 9; int cw = t % CW; int co = t / CW;
  int Ci = CW*32;
  const float* src = w + ((size_t)co*Ci + (size_t)cw*32)*9 + tap;
  uint32_t bits = 0;
  #pragma unroll
  for (int b=0;b<32;b++) bits |= (src[(size_t)b*9] >= 0.f ? 1u:0u) << b;
  out[idx] = bits;
}

__global__ void k_pack_fc1_w(const float* __restrict__ w, uint32_t* __restrict__ out){
  int idx = blockIdx.x*256 + threadIdx.x;
  if (idx >= 1024*256) return;
  int wd = idx & 255, o = idx >> 8;
  int cw = wd >> 4, p = wd & 15;
  const float* src = w + (size_t)o*8192;
  uint32_t bits=0;
  #pragma unroll
  for (int b=0;b<32;b++) bits |= (src[(cw*32+b)*16 + p] >= 0.f ? 1u:0u) << b;
  out[idx]=bits;
}

__global__ void k_pack_fc2_w(const float* __restrict__ w, uint32_t* __restrict__ out){
  int idx = blockIdx.x*256+threadIdx.x; if (idx >= 10*32) return;
  int wd = idx & 31, o = idx >> 5;
  uint32_t bits=0;
  #pragma unroll
  for (int b=0;b<32;b++) bits |= (w[o*1024 + wd*32 + b] >= 0.f ? 1u:0u)<<b;
  out[idx]=bits;
}

// =====================================================================
// conv1 (f64-exact)
// =====================================================================
__global__ __launch_bounds__(256) void k_conv1_stats3(const float* __restrict__ x,
        const float* __restrict__ w1, double* __restrict__ partials){
  __shared__ double xs[3][10][34];
  __shared__ float wf[128][27];
  int n = blockIdx.x >> 2, rg = blockIdx.x & 3;
  int y0 = rg*8;
  const float* xp = x + (size_t)n*3*1024;
  for (int i=threadIdx.x; i<3*10*34; i+=256){
    int ci = i/340, r = i%340, ly = r/34, lx = r%34;
    int gy = y0 - 1 + ly, gx = lx - 1;
    double v = 0.0;
    if (gy>=0 && gy<32 && gx>=0 && gx<32) v = (double)xp[ci*1024 + gy*32 + gx];
    (&xs[0][0][0])[i] = v;
  }
  for (int i=threadIdx.x; i<128*27; i+=256)
    (&wf[0][0])[i] = w1[i];
  __syncthreads();
  int wave = threadIdx.x>>6, lane = threadIdx.x&63;
  int c0 = (wave&1)*64, rsub = wave>>1;
  int co = c0 + lane;
  double w[27];
  #pragma unroll
  for (int k=0;k<27;k++) w[k] = (wf[co][k] >= 0.f) ? 1.0 : -1.0;
  double s=0.0, s2=0.0;
  for (int rr = rsub*4; rr < rsub*4+4; ++rr){
    for (int xx=0; xx<32; ++xx){
      double a0=0.0, a1=0.0, a2=0.0;
      #pragma unroll
      for (int ci=0;ci<3;ci++){
        const double* r0 = &xs[ci][rr+0][xx];
        const double* r1 = &xs[ci][rr+1][xx];
        const double* r2 = &xs[ci][rr+2][xx];
        a0 += r0[0]*w[ci*9+0] + r0[1]*w[ci*9+1] + r0[2]*w[ci*9+2];
        a1 += r1[0]*w[ci*9+3] + r1[1]*w[ci*9+4] + r1[2]*w[ci*9+5];
        a2 += r2[0]*w[ci*9+6] + r2[1]*w[ci*9+7] + r2[2]*w[ci*9+8];
      }
      double acc = (a0 + a1) + a2;
      s += acc; s2 += acc*acc;
    }
  }
  size_t pi = (size_t)co*2048 + (size_t)n*8 + rg*2 + rsub;
  partials[pi*2+0]=s; partials[pi*2+1]=s2;
}

__global__ __launch_bounds__(256) void k_finalize_partials_p(const double* __restrict__ partials,
        const float* __restrict__ g, const float* __restrict__ b,
        double* __restrict__ A, double* __restrict__ Bv, int nPart, double invCount){
  int c = blockIdx.x;
  double s=0.0, s2=0.0;
  for (int i=threadIdx.x; i<nPart; i+=256){
    s  += partials[((size_t)c*nPart+i)*2+0];
    s2 += partials[((size_t)c*nPart+i)*2+1];
  }
  for (int off=32; off; off>>=1){ s+=__shfl_down(s,off,64); s2+=__shfl_down(s2,off,64); }
  __shared__ double sh[8];
  int wid=threadIdx.x>>6, lane=threadIdx.x&63;
  if(lane==0){sh[wid]=s;sh[4+wid]=s2;}
  __syncthreads();
  if(threadIdx.x==0){
    double S=0,S2=0;
    #pragma unroll
    for(int i=0;i<4;i++){S+=sh[i];S2+=sh[4+i];}
    double m=S*invCount, v=S2*invCount-m*m;
    double a=(double)g[c]/sqrt(v+1e-5);
    A[c]=a; Bv[c]=(double)b[c]-m*a;
  }
}

// binarize: grid 2048, quad-pixel inner loop, per-pixel ballot pack.
__global__ __launch_bounds__(256) void k_conv1_binarize5(const float* __restrict__ x,
        const float* __restrict__ w1, const double* __restrict__ A, const double* __restrict__ Bv,
        uint32_t* __restrict__ bits){
  __shared__ double xs[3][6][34];
  __shared__ float wf[128][27];
  __shared__ uint32_t wordbuf[4][128];
  int n = blockIdx.x >> 3, rg = blockIdx.x & 7;
  int y0 = rg*4;
  const float* xp = x + (size_t)n*3*1024;
  for (int i=threadIdx.x; i<3*6*34; i+=256){
    int ci = i/204, r = i%204, ly = r/34, lx = r%34;
    int gy = y0 - 1 + ly, gx = lx - 1;
    double v = 0.0;
    if (gy>=0 && gy<32 && gx>=0 && gx<32) v = (double)xp[ci*1024 + gy*32 + gx];
    (&xs[0][0][0])[i] = v;
  }
  for (int i=threadIdx.x; i<128*27; i+=256)
    (&wf[0][0])[i] = w1[i];
  __syncthreads();
  int wave = threadIdx.x>>6, lane = threadIdx.x&63;
  int c0 = (wave&1)*64, rsub = wave>>1;
  int co = c0 + lane;
  double w[27];
  #pragma unroll
  for (int k=0;k<27;k++) w[k] = (wf[co][k] >= 0.f) ? 1.0 : -1.0;
  double av = A[co], bv = Bv[co];
  for (int rr = rsub*2; rr < rsub*2+2; ++rr){
    for (int x0=0; x0<32; x0+=4){
      double acc[4] = {0,0,0,0};
      #pragma unroll
      for (int ci=0;ci<3;ci++)
        #pragma unroll
        for (int ky=0;ky<3;ky++){
          const double* r = &xs[ci][rr+ky][x0];
          double v0=r[0],v1=r[1],v2=r[2],v3=r[3],v4=r[4],v5=r[5];
          double w0=w[ci*9+ky*3+0], w1v=w[ci*9+ky*3+1], w2=w[ci*9+ky*3+2];
          acc[0] += v0*w0 + v1*w1v + v2*w2;
          acc[1] += v1*w0 + v2*w1v + v3*w2;
          acc[2] += v2*w0 + v3*w1v + v4*w2;
          acc[3] += v3*w0 + v4*w1v + v5*w2;
        }
      #pragma unroll
      for (int j=0;j<4;j++){
        int pred = (acc[j]*av + bv >= 0.0) ? 1 : 0;
        unsigned long long m = __ballot(pred);
        if (lane == 0){
          int p = rr*32 + x0 + j;
          wordbuf[(c0>>5)+0][p] = (uint32_t)m;
          wordbuf[(c0>>5)+1][p] = (uint32_t)(m>>32);
        }
      }
    }
  }
  __syncthreads();
  for (int i=threadIdx.x; i<512; i+=256){
    int cw = i>>7, p = i&127;
    bits[(size_t)n*4096 + cw*1024 + rg*128 + p] = wordbuf[cw][p];
  }
}

// =====================================================================
// XNOR conv family: zero+fill staging, odd PITCH, row-wise inner loop,
// fused-bcnt MAC chains, fused exact int64 stats.
// =====================================================================
template<int CW,int H,int W,int HP,int PITCH>
__device__ __forceinline__ void stage_bits(const uint32_t* __restrict__ ip, uint32_t* __restrict__ inlds){
  for (int i=threadIdx.x; i<CW*HP*PITCH; i+=256) inlds[i]=0u;
}

template<int CW,int H,int W,int HP,int PITCH>
__device__ __forceinline__ void fill_bits(const uint32_t* __restrict__ ip, uint32_t* __restrict__ inlds){
  constexpr int LOGW  = (W==32)?5:(W==16)?4:3;
  constexpr int LOGHW = ((H*W)==1024)?10:((H*W)==256)?8:6;
  for (int i=threadIdx.x; i<CW*H*W; i+=256){
    int cw = i >> LOGHW;
    int rem = i & (H*W-1);
    int y = rem >> LOGW;
    int x = rem & (W-1);
    inlds[cw*HP*PITCH + (y+1)*PITCH + (x+1)] = ip[i];
  }
}

// ---- fused conv + pool, TWO output channels per thread (L2, L4)
template<int CW,int H,int W,int CO,int COB,int NX>
__global__ __launch_bounds__(256) void k_xconv_pool2(const uint32_t* __restrict__ in,
        const uint32_t* __restrict__ wb, int16_t* __restrict__ out, long long* __restrict__ part){
  constexpr int HP = H+2;
  constexpr int PITCH = W+3;          // odd
  constexpr int WP = CW*9+1;
  constexpr int NG = CO/COB;
  constexpr int XS = W/NX;
  constexpr int UNITS = (H/2)*XS;
  static_assert((COB/2)*UNITS==256, "thread mapping");
  __shared__ uint32_t inlds[CW*HP*PITCH];
  __shared__ uint32_t wlds[COB*WP];
  __shared__ int colpc[COB][10];
  int n = blockIdx.x / NG, cg = blockIdx.x % NG;
  int co0 = cg*COB;
  const uint32_t* ip = in + (size_t)n*CW*H*W;
  stage_bits<CW,H,W,HP,PITCH>(ip, inlds);
  for (int i=threadIdx.x; i<COB*CW*9; i+=256){
    int co = i/(CW*9); int r = i%(CW*9);
    wlds[co*WP + r] = wb[(size_t)(co0+co)*CW*9 + r];
  }
  __syncthreads();
  fill_bits<CW,H,W,HP,PITCH>(ip, inlds);
  for (int i=threadIdx.x; i<COB*9; i+=256){
    int co=i/9, tap=i%9; int s=0;
    #pragma unroll
    for (int cw=0;cw<CW;cw++) s += __popc(wlds[co*WP + cw*9 + tap]);
    colpc[co][tap]=s;
  }
  __syncthreads();
  int t = threadIdx.x;
  int cog = t / UNITS;
  int rem = t % UNITS;
  int yy = rem / XS;
  int xs = (rem % XS)*NX;
  int c0 = cog*2;
  int acc0[2][NX], acc1[2][NX];
  #pragma unroll
  for (int c=0;c<2;c++)
    #pragma unroll
    for (int i2=0;i2<NX;i2++){acc0[c][i2]=0;acc1[c][i2]=0;}
  for (int cw=0; cw<CW; cw++){
    uint32_t wr[2][9];
    #pragma unroll
    for (int c=0;c<2;c++)
      #pragma unroll
      for (int k=0;k<9;k++) wr[c][k]=wlds[(c0+c)*WP+cw*9+k];
    const uint32_t* ib = &inlds[cw*HP*PITCH + (2*yy)*PITCH + xs];
    {
      uint32_t row[NX+2];
      #pragma unroll
      for (int j=0;j<NX+2;j++) row[j] = ib[j];
      #pragma unroll
      for (int q=0;q<NX;q++)
        #pragma unroll
        for (int c=0;c<2;c++){
          acc0[c][q] = BMAC(row[q],  wr[c][0], acc0[c][q]);
          acc0[c][q] = BMAC(row[q+1],wr[c][1], acc0[c][q]);
          acc0[c][q] = BMAC(row[q+2],wr[c][2], acc0[c][q]);
        }
    }
    #pragma unroll
    for (int rrow=1; rrow<=2; rrow++){
      uint32_t row[NX+2];
      #pragma unroll
      for (int j=0;j<NX+2;j++) row[j] = ib[rrow*PITCH + j];
      #pragma unroll
      for (int q=0;q<NX;q++)
        #pragma unroll
        for (int c=0;c<2;c++){
          acc0[c][q] = BMAC(row[q],  wr[c][3*rrow+0], acc0[c][q]);
          acc0[c][q] = BMAC(row[q+1],wr[c][3*rrow+1], acc0[c][q]);
          acc0[c][q] = BMAC(row[q+2],wr[c][3*rrow+2], acc0[c][q]);
          acc1[c][q] = BMAC(row[q],  wr[c][3*rrow-3], acc1[c][q]);
          acc1[c][q] = BMAC(row[q+1],wr[c][3*rrow-2], acc1[c][q]);
          acc1[c][q] = BMAC(row[q+2],wr[c][3*rrow-1], acc1[c][q]);
        }
    }
    {
      uint32_t row[NX+2];
      #pragma unroll
      for (int j=0;j<NX+2;j++) row[j] = ib[3*PITCH + j];
      #pragma unroll
      for (int q=0;q<NX;q++)
        #pragma unroll
        for (int c=0;c<2;c++){
          acc1[c][q] = BMAC(row[q],  wr[c][6], acc1[c][q]);
          acc1[c][q] = BMAC(row[q+1],wr[c][7], acc1[c][q]);
          acc1[c][q] = BMAC(row[q+2],wr[c][8], acc1[c][q]);
        }
    }
  }
  #pragma unroll
  for (int c=0;c<2;c++){
    const int* cp = colpc[c0+c];
    int16_t res[NX/2];
    #pragma unroll
    for (int tp=0; tp<NX/2; tp++){
      int best=-32768;
      #pragma unroll
      for (int rrow=0;rrow<2;rrow++){
        int kyi = (rrow==0 && yy==0) ? 0 : ((rrow==1 && yy==H/2-1) ? 2 : -1);
        #pragma unroll
        for (int dx=0;dx<2;dx++){
          int q = 2*tp+dx;
          int x = xs+q;
          int kxi = (x==0)?0:((x==W-1)?2:-1);
          int acc = rrow? acc1[c][q]:acc0[c][q];
          int corr=0, nv=9;
          if (kyi>=0){ corr += cp[kyi*3+0]+cp[kyi*3+1]+cp[kyi*3+2]; }
          if (kxi>=0){ corr += cp[0+kxi]+cp[3+kxi]+cp[6+kxi]; }
          if (kyi>=0 && kxi>=0){ corr -= cp[kyi*3+kxi]; nv=4; }
          else if (kyi>=0 || kxi>=0) nv=6;
          int dot = 32*CW*nv - 2*(acc - corr);
          best = dot>best?dot:best;
        }
      }
      res[tp]=(int16_t)best;
    }
    int16_t* op = out + (((size_t)n*CO + (co0+c0+c))*(H/2) + yy)*(W/2) + xs/2;
    #pragma unroll
    for (int tp=0;tp<NX/2;tp++) op[tp]=res[tp];
    int ssum=0; long long ssq=0;
    #pragma unroll
    for (int tp=0;tp<NX/2;tp++){ int v=res[tp]; ssum+=v; ssq += (long long)(v*v); }
    long long s = (long long)ssum;
    #pragma unroll
    for (int off=UNITS>>1; off; off>>=1){ s += __shfl_down(s,off,UNITS); ssq += __shfl_down(ssq,off,UNITS); }
    if (rem==0){
      size_t pi = (size_t)(co0+c0+c)*BATCH + n;
      part[pi*2+0]=s; part[pi*2+1]=ssq;
    }
  }
}

// ---- fused conv + pool, one channel per thread (L6)
template<int CW,int H,int W,int CO,int COB,int NX>
__global__ __launch_bounds__(256) void k_xconv_pool(const uint32_t* __restrict__ in,
        const uint32_t* __restrict__ wb, int16_t* __restrict__ out, long long* __restrict__ part){
  constexpr int HP = H+2;
  constexpr int PITCH = W+3;          // odd
  constexpr int WP = CW*9+1;
  constexpr int NG = CO/COB;
  constexpr int XS = W/NX;
  constexpr int UNITS = (H/2)*XS;
  static_assert(COB*UNITS==256, "thread mapping");
  __shared__ uint32_t inlds[CW*HP*PITCH];
  __shared__ uint32_t wlds[COB*WP];
  __shared__ int colpc[COB][10];
  int n = blockIdx.x / NG, cg = blockIdx.x % NG;
  int co0 = cg*COB;
  const uint32_t* ip = in + (size_t)n*CW*H*W;
  stage_bits<CW,H,W,HP,PITCH>(ip, inlds);
  for (int i=threadIdx.x; i<COB*CW*9; i+=256){
    int co = i/(CW*9); int r = i%(CW*9);
    wlds[co*WP + r] = wb[(size_t)(co0+co)*CW*9 + r];
  }
  __syncthreads();
  fill_bits<CW,H,W,HP,PITCH>(ip, inlds);
  for (int i=threadIdx.x; i<COB*9; i+=256){
    int co=i/9, tap=i%9; int s=0;
    #pragma unroll
    for (int cw=0;cw<CW;cw++) s += __popc(wlds[co*WP + cw*9 + tap]);
    colpc[co][tap]=s;
  }
  __syncthreads();
  int t = threadIdx.x;
  int col = t / UNITS;
  int rem = t % UNITS;
  int yy = rem / XS;
  int xs = (rem % XS)*NX;
  int co = co0 + col;
  int acc0[NX], acc1[NX];
  #pragma unroll
  for (int i2=0;i2<NX;i2++){acc0[i2]=0;acc1[i2]=0;}
  for (int cw=0; cw<CW; cw++){
    uint32_t wr[9];
    #pragma unroll
    for (int k=0;k<9;k++) wr[k]=wlds[col*WP+cw*9+k];
    const uint32_t* ib = &inlds[cw*HP*PITCH + (2*yy)*PITCH + xs];
    {
      uint32_t row[NX+2];
      #pragma unroll
      for (int j=0;j<NX+2;j++) row[j] = ib[j];
      #pragma unroll
      for (int q=0;q<NX;q++){
        acc0[q] = BMAC(row[q],  wr[0], acc0[q]);
        acc0[q] = BMAC(row[q+1],wr[1], acc0[q]);
        acc0[q] = BMAC(row[q+2],wr[2], acc0[q]);
      }
    }
    #pragma unroll
    for (int rrow=1; rrow<=2; rrow++){
      uint32_t row[NX+2];
      #pragma unroll
      for (int j=0;j<NX+2;j++) row[j] = ib[rrow*PITCH + j];
      #pragma unroll
      for (int q=0;q<NX;q++){
        acc0[q] = BMAC(row[q],  wr[3*rrow+0], acc0[q]);
        acc0[q] = BMAC(row[q+1],wr[3*rrow+1], acc0[q]);
        acc0[q] = BMAC(row[q+2],wr[3*rrow+2], acc0[q]);
        acc1[q] = BMAC(row[q],  wr[3*rrow-3], acc1[q]);
        acc1[q] = BMAC(row[q+1],wr[3*rrow-2], acc1[q]);
        acc1[q] = BMAC(row[q+2],wr[3*rrow-1], acc1[q]);
      }
    }
    {
      uint32_t row[NX+2];
      #pragma unroll
      for (int j=0;j<NX+2;j++) row[j] = ib[3*PITCH + j];
      #pragma unroll
      for (int q=0;q<NX;q++){
        acc1[q] = BMAC(row[q],  wr[6], acc1[q]);
        acc1[q] = BMAC(row[q+1],wr[7], acc1[q]);
        acc1[q] = BMAC(row[q+2],wr[8], acc1[q]);
      }
    }
  }
  const int* cp = colpc[col];
  int16_t res[NX/2];
  #pragma unroll
  for (int tp=0; tp<NX/2; tp++){
    int best=-32768;
    #pragma unroll
    for (int rrow=0;rrow<2;rrow++){
      int kyi = (rrow==0 && yy==0) ? 0 : ((rrow==1 && yy==H/2-1) ? 2 : -1);
      #pragma unroll
      for (int dx=0;dx<2;dx++){
        int q = 2*tp+dx;
        int x = xs+q;
        int kxi = (x==0)?0:((x==W-1)?2:-1);
        int acc = rrow? acc1[q]:acc0[q];
        int corr=0, nv=9;
        if (kyi>=0){ corr += cp[kyi*3+0]+cp[kyi*3+1]+cp[kyi*3+2]; }
        if (kxi>=0){ corr += cp[0+kxi]+cp[3+kxi]+cp[6+kxi]; }
        if (kyi>=0 && kxi>=0){ corr -= cp[kyi*3+kxi]; nv=4; }
        else if (kyi>=0 || kxi>=0) nv=6;
        int dot = 32*CW*nv - 2*(acc - corr);
        best = dot>best?dot:best;
      }
    }
    res[tp]=(int16_t)best;
  }
  int16_t* op = out + (((size_t)n*CO + co)*(H/2) + yy)*(W/2) + xs/2;
  #pragma unroll
  for (int tp=0;tp<NX/2;tp++) op[tp]=res[tp];
  int ssum=0; long long ssq=0;
  #pragma unroll
  for (int tp=0;tp<NX/2;tp++){ int v=res[tp]; ssum+=v; ssq += (long long)(v*v); }
  long long s = (long long)ssum;
  #pragma unroll
  for (int off=UNITS>>1; off; off>>=1){ s += __shfl_down(s,off,UNITS); ssq += __shfl_down(ssq,off,UNITS); }
  if (rem==0){
    size_t pi = (size_t)co*BATCH + n;
    part[pi*2+0]=s; part[pi*2+1]=ssq;
  }
}

// ---- plain conv, two channels per thread (L3, L5)
template<int CW,int H,int W,int CO,int COB,int NX>
__global__ __launch_bounds__(256) void k_xconv(const uint32_t* __restrict__ in,
        const uint32_t* __restrict__ wb, int16_t* __restrict__ out, long long* __restrict__ part){
  constexpr int HP = H+2;
  constexpr int PITCH = W+3;          // odd
  constexpr int WP = CW*9+1;
  constexpr int NG = CO/COB;
  constexpr int XS = W/NX;
  constexpr int UNITS = H*XS;
  static_assert((COB/2)*UNITS==256, "thread mapping");
  __shared__ uint32_t inlds[CW*HP*PITCH];
  __shared__ uint32_t wlds[COB*WP];
  __shared__ int colpc[COB][10];
  int n = blockIdx.x / NG, cg = blockIdx.x % NG;
  int co0 = cg*COB;
  const uint32_t* ip = in + (size_t)n*CW*H*W;
  stage_bits<CW,H,W,HP,PITCH>(ip, inlds);
  for (int i=threadIdx.x; i<COB*CW*9; i+=256){
    int co = i/(CW*9); int r = i%(CW*9);
    wlds[co*WP + r] = wb[(size_t)(co0+co)*CW*9 + r];
  }
  __syncthreads();
  fill_bits<CW,H,W,HP,PITCH>(ip, inlds);
  for (int i=threadIdx.x; i<COB*9; i+=256){
    int co=i/9, tap=i%9; int s=0;
    #pragma unroll
    for (int cw=0;cw<CW;cw++) s += __popc(wlds[co*WP + cw*9 + tap]);
    colpc[co][tap]=s;
  }
  __syncthreads();
  int t = threadIdx.x;
  int cog = t / UNITS;
  int rem = t % UNITS;
  int y = rem / XS;
  int xs = (rem % XS)*NX;
  int c0 = cog*2;
  int acc[2][NX];
  #pragma unroll
  for (int c=0;c<2;c++)
    #pragma unroll
    for (int i2=0;i2<NX;i2++) acc[c][i2]=0;
  for (int cw=0; cw<CW; cw++){
    uint32_t wr[2][9];
    #pragma unroll
    for (int c=0;c<2;c++)
      #pragma unroll
      for (int k=0;k<9;k++) wr[c][k]=wlds[(c0+c)*WP+cw*9+k];
    const uint32_t* ib = &inlds[cw*HP*PITCH + y*PITCH + xs];
    #pragma unroll
    for (int rrow=0; rrow<3; rrow++){
      uint32_t row[NX+2];
      #pragma unroll
      for (int j=0;j<NX+2;j++) row[j] = ib[rrow*PITCH + j];
      #pragma unroll
      for (int q=0;q<NX;q++){
        acc[0][q] = BMAC(row[q],  wr[0][3*rrow+0], acc[0][q]);
        acc[0][q] = BMAC(row[q+1],wr[0][3*rrow+1], acc[0][q]);
        acc[0][q] = BMAC(row[q+2],wr[0][3*rrow+2], acc[0][q]);
        acc[1][q] = BMAC(row[q],  wr[1][3*rrow+0], acc[1][q]);
        acc[1][q] = BMAC(row[q+1],wr[1][3*rrow+1], acc[1][q]);
        acc[1][q] = BMAC(row[q+2],wr[1][3*rrow+2], acc[1][q]);
      }
    }
  }
  int kyi = (y==0)?0:((y==H-1)?2:-1);
  #pragma unroll
  for (int c=0;c<2;c++){
    const int* cp = colpc[c0+c];
    int16_t rbuf[NX];
    int ssum=0; long long ssq=0;
    #pragma unroll
    for (int q=0;q<NX;q++){
      int x = xs+q;
      int kxi = (x==0)?0:((x==W-1)?2:-1);
      int corr=0, nv=9;
      if (kyi>=0){ corr += cp[kyi*3+0]+cp[kyi*3+1]+cp[kyi*3+2]; }
      if (kxi>=0){ corr += cp[0+kxi]+cp[3+kxi]+cp[6+kxi]; }
      if (kyi>=0 && kxi>=0){ corr -= cp[kyi*3+kxi]; nv=4; }
      else if (kyi>=0 || kxi>=0) nv=6;
      int dot = 32*CW*nv - 2*(acc[c][q] - corr);
      rbuf[q] = (int16_t)dot;
      ssum+=dot; ssq+=(long long)(dot*dot);
    }
    int16_t* op = out + (((size_t)n*CO + (co0+c0+c))*H + y)*W + xs;
    #pragma unroll
    for (int q=0;q<NX;q++) op[q]=rbuf[q];
    long long s=(long long)ssum, q2=ssq;
    #pragma unroll
    for (int off=UNITS>>1; off; off>>=1){ s += __shfl_down(s,off,UNITS); q2 += __shfl_down(q2,off,UNITS); }
    if (rem==0){
      size_t pi = (size_t)(co0+c0+c)*BATCH + n;
      part[pi*2+0]=s; part[pi*2+1]=q2;
    }
  }
}

// ---------------- parallel per-channel finalize from [c][256] int64 ----------------
__global__ __launch_bounds__(256) void k_chstats_fin_p(const long long* __restrict__ part,
        const float* __restrict__ g, const float* __restrict__ b,
        double* __restrict__ A, double* __restrict__ Bv, double invCount){
  int c = blockIdx.x;
  long long s  = part[((size_t)c*BATCH+threadIdx.x)*2+0];
  long long s2 = part[((size_t)c*BATCH+threadIdx.x)*2+1];
  for (int off=32; off; off>>=1){ s+=__shfl_down(s,off,64); s2+=__shfl_down(s2,off,64); }
  __shared__ long long sh[8];
  int wid=threadIdx.x>>6, lane=threadIdx.x&63;
  if(lane==0){sh[wid]=s;sh[4+wid]=s2;}
  __syncthreads();
  if(threadIdx.x==0){
    long long S=0,S2=0;
    #pragma unroll
    for(int i=0;i<4;i++){S+=sh[i];S2+=sh[4+i];}
    double m=(double)S*invCount, v=(double)S2*invCount-m*m;
    double a=(double)g[c]/sqrt(v+1e-5);
    A[c]=a; Bv[c]=(double)b[c]-m*a;
  }
}

// ---------------- binarize BN(conv) and pack ----------------
__global__ void k_binarize_pack(const int16_t* __restrict__ in, const double* __restrict__ A,
                                const double* __restrict__ Bv, uint32_t* __restrict__ bits,
                                int C, int HW){
  int CW = C>>5;
  size_t total = (size_t)BATCH*CW*HW;
  size_t idx = (size_t)blockIdx.x*256+threadIdx.x;
  if (idx>=total) return;
  int hw = (int)(idx % HW); size_t t = idx/HW;
  int cw = (int)(t % CW); int n = (int)(t / CW);
  uint32_t wordv=0;
  for (int b=0;b<32;b++){
    int c = cw*32+b;
    double v = (double)in[((size_t)n*C + c)*HW + hw];
    if (v*A[c]+Bv[c] >= 0.0) wordv |= 1u<<b;
  }
  bits[idx]=wordv;
}

// ---------------- FC1 ----------------
__global__ void k_fc1(const uint32_t* __restrict__ actbits, const uint32_t* __restrict__ wb,
                      int16_t* __restrict__ out){
  int og = blockIdx.x & 3; int n = blockIdx.x >> 2;
  int o = og*256 + threadIdx.x;
  __shared__ uint32_t sact[256];
  sact[threadIdx.x] = actbits[(size_t)n*256 + threadIdx.x];
  __syncthreads();
  const uint32_t* wp = wb + (size_t)o*256;
  int acc=0;
  #pragma unroll 8
  for (int k=0;k<256;k++) acc = BMAC(sact[k], wp[k], acc);
  out[(size_t)n*1024 + o] = (int16_t)(8192 - 2*acc);
}

__global__ void k_fc_stats(const int16_t* __restrict__ in, const float* __restrict__ g,
                           const float* __restrict__ b, double* __restrict__ A, double* __restrict__ Bv){
  int f = blockIdx.x;
  double v = (double)in[(size_t)threadIdx.x*1024 + f];
  double s=v, s2=v*v;
  __shared__ double sh[8];
  for (int off=32; off; off>>=1){ s+=__shfl_down(s,off,64); s2+=__shfl_down(s2,off,64); }
  int wid=threadIdx.x>>6, lane=threadIdx.x&63;
  if(lane==0){sh[wid]=s;sh[4+wid]=s2;}
  __syncthreads();
  if(threadIdx.x==0){
    double S=0,S2=0;
    #pragma unroll
    for(int i=0;i<4;i++){S+=sh[i];S2+=sh[4+i];}
    double m=S/256.0, var=S2/256.0-m*m;
    double a=(double)g[f]/sqrt(var+1e-5);
    A[f]=a; Bv[f]=(double)b[f]-m*a;
  }
}

__global__ void k_binpack_fc(const int16_t* __restrict__ in, const double* __restrict__ A,
                             const double* __restrict__ Bv, uint32_t* __restrict__ bits){
  int idx = blockIdx.x*256+threadIdx.x;
  if (idx >= 256*32) return;
  int w = idx & 31, n = idx >> 5;
  uint32_t word=0;
  for (int b=0;b<32;b++){
    int f = w*32+b;
    double v=(double)in[(size_t)n*1024+f];
    if (v*A[f]+Bv[f] >= 0.0) word|=1u<<b;
  }
  bits[idx]=word;
}

// ---------------- FC2 + final BN -> float out ----------------
__global__ void k_fc2_out(const uint32_t* __restrict__ actbits, const uint32_t* __restrict__ wb,
                          const float* __restrict__ bias2, const float* __restrict__ g,
                          const float* __restrict__ b, float* __restrict__ out){
  int o = blockIdx.x;     // 0..9
  int n = threadIdx.x;    // 0..255
  const uint32_t* ap = actbits + (size_t)n*32;
  const uint32_t* wp = wb + (size_t)o*32;
  int acc=0;
  #pragma unroll
  for (int k=0;k<32;k++) acc = BMAC(ap[k], wp[k], acc);
  double h = (double)(1024 - 2*acc) + (double)bias2[o];
  double s=h, s2=h*h;
  __shared__ double sh[8];
  for(int off=32;off;off>>=1){s+=__shfl_down(s,off,64);s2+=__shfl_down(s2,off,64);}
  int wid=threadIdx.x>>6,lane=threadIdx.x&63;
  if(lane==0){sh[wid]=s;sh[4+wid]=s2;}
  __syncthreads();
  __shared__ double sm, sinv;
  if(threadIdx.x==0){
    double S=0,S2=0;
    #pragma unroll
    for(int i=0;i<4;i++){S+=sh[i];S2+=sh[4+i];}
    double m=S/256.0, v=S2/256.0-m*m;
    sm=m; sinv=1.0/sqrt(v+1e-5);
  }
  __syncthreads();
  double r = (h - sm)*sinv*(double)g[o] + (double)b[o];
  out[(size_t)n*10 + o] = (float)r;
}

extern "C" void kernel_launch(void* const* d_in, const int* in_sizes, int n_in,
                              void* d_out, int out_size, void* d_ws, size_t ws_size,
                              hipStream_t stream) {
  const float* x   = (const float*)d_in[0];
  const float* w1  = (const float*)d_in[1];
  const float* g1  = (const float*)d_in[2];
  const float* b1  = (const float*)d_in[3];
  const float* w2  = (const float*)d_in[4];
  const float* g2  = (const float*)d_in[5];
  const float* b2  = (const float*)d_in[6];
  const float* w3  = (const float*)d_in[7];
  const float* g3  = (const float*)d_in[8];
  const float* b3  = (const float*)d_in[9];
  const float* w4  = (const float*)d_in[10];
  const float* g4  = (const float*)d_in[11];
  const float* b4  = (const float*)d_in[12];
  const float* w5  = (const float*)d_in[13];
  const float* g5  = (const float*)d_in[14];
  const float* b5  = (const float*)d_in[15];
  const float* w6  = (const float*)d_in[16];
  const float* g6  = (const float*)d_in[17];
  const float* b6  = (const float*)d_in[18];
  const float* wf1 = (const float*)d_in[19];
  const float* gf1 = (const float*)d_in[20];
  const float* bf1 = (const float*)d_in[21];
  const float* wf2 = (const float*)d_in[22];
  const float* bias2=(const float*)d_in[23];
  const float* gf2 = (const float*)d_in[24];
  const float* bf2 = (const float*)d_in[25];
  float* out = (float*)d_out;

  char* ws = (char*)d_ws;
  size_t off = 0;
  auto alloc = [&](size_t bytes)->char*{ char* p = ws + off; off = (off + bytes + 255) & ~(size_t)255; return p; };

  uint32_t* wb2  = (uint32_t*)alloc(4608ull*4);
  uint32_t* wb3  = (uint32_t*)alloc(9216ull*4);
  uint32_t* wb4  = (uint32_t*)alloc(18432ull*4);
  uint32_t* wb5  = (uint32_t*)alloc(36864ull*4);
  uint32_t* wb6  = (uint32_t*)alloc(73728ull*4);
  uint32_t* wf1b = (uint32_t*)alloc(262144ull*4);
  uint32_t* wf2b = (uint32_t*)alloc(320ull*4);
  double*   part = (double*)  alloc(128ull*2048*2*8);
  long long* pll = (long long*)alloc(512ull*256*2*8);
  double*   Abuf = (double*)  alloc(1024ull*8);
  double*   Bbuf = (double*)  alloc(1024ull*8);
  uint32_t* bitsA= (uint32_t*)alloc(1048576ull*4);
  uint32_t* bitsB= (uint32_t*)alloc(262144ull*4);
  int16_t*  conv = (int16_t*) alloc(16777216ull*2);

  // pack weights
  k_pack_conv_w<<<CDIV(4608,256),256,0,stream>>>(w2, wb2, 128, 4);
  k_pack_conv_w<<<CDIV(9216,256),256,0,stream>>>(w3, wb3, 256, 4);
  k_pack_conv_w<<<CDIV(18432,256),256,0,stream>>>(w4, wb4, 256, 8);
  k_pack_conv_w<<<CDIV(36864,256),256,0,stream>>>(w5, wb5, 512, 8);
  k_pack_conv_w<<<CDIV(73728,256),256,0,stream>>>(w6, wb6, 512, 16);
  k_pack_fc1_w<<<CDIV(262144,256),256,0,stream>>>(wf1, wf1b);
  k_pack_fc2_w<<<CDIV(320,256),256,0,stream>>>(wf2, wf2b);

  // ---- layer 1 ----
  k_conv1_stats3<<<1024,256,0,stream>>>(x, w1, part);
  k_finalize_partials_p<<<128,256,0,stream>>>(part, g1, b1, Abuf, Bbuf, 2048, 1.0/(256.0*1024.0));
  k_conv1_binarize5<<<2048,256,0,stream>>>(x, w1, Abuf, Bbuf, bitsA);

  // ---- layer 2: conv+pool -> [256,128,16,16] ----
  k_xconv_pool2<4,32,32,128,8,8><<<256*16,256,0,stream>>>(bitsA, wb2, conv, pll);
  k_chstats_fin_p<<<128,256,0,stream>>>(pll, g2, b2, Abuf, Bbuf, 1.0/(256.0*256.0));
  k_binarize_pack<<<CDIV(256ull*4*256,256),256,0,stream>>>(conv, Abuf, Bbuf, bitsB, 128, 256);

  // ---- layer 3: conv -> [256,256,16,16] ----
  k_xconv<4,16,16,256,16,8><<<256*16,256,0,stream>>>(bitsB, wb3, conv, pll);
  k_chstats_fin_p<<<256,256,0,stream>>>(pll, g3, b3, Abuf, Bbuf, 1.0/(256.0*256.0));
  k_binarize_pack<<<CDIV(256ull*8*256,256),256,0,stream>>>(conv, Abuf, Bbuf, bitsA, 256, 256);

  // ---- layer 4: conv+pool -> [256,256,8,8] ----
  k_xconv_pool2<8,16,16,256,32,8><<<256*8,256,0,stream>>>(bitsA, wb4, conv, pll);
  k_chstats_fin_p<<<256,256,0,stream>>>(pll, g4, b4, Abuf, Bbuf, 1.0/(256.0*64.0));
  k_binarize_pack<<<CDIV(256ull*8*64,256),256,0,stream>>>(conv, Abuf, Bbuf, bitsB, 256, 64);

  // ---- layer 5: conv -> [256,512,8,8] ----
  k_xconv<8,8,8,512,64,8><<<256*8,256,0,stream>>>(bitsB, wb5, conv, pll);
  k_chstats_fin_p<<<512,256,0,stream>>>(pll, g5, b5, Abuf, Bbuf, 1.0/(256.0*64.0));
  k_binarize_pack<<<CDIV(256ull*16*64,256),256,0,stream>>>(conv, Abuf, Bbuf, bitsA, 512, 64);

  // ---- layer 6: conv+pool -> [256,512,4,4] ----
  k_xconv_pool<16,8,8,512,64,8><<<256*8,256,0,stream>>>(bitsA, wb6, conv, pll);
  k_chstats_fin_p<<<512,256,0,stream>>>(pll, g6, b6, Abuf, Bbuf, 1.0/(256.0*16.0));
  k_binarize_pack<<<CDIV(256ull*16*16,256),256,0,stream>>>(conv, Abuf, Bbuf, bitsB, 512, 16);

  // ---- FC1 ----
  k_fc1<<<256*4,256,0,stream>>>(bitsB, wf1b, conv);
  k_fc_stats<<<1024,256,0,stream>>>(conv, gf1, bf1, Abuf, Bbuf);
  k_binpack_fc<<<CDIV(256*32,256),256,0,stream>>>(conv, Abuf, Bbuf, bitsA);

  // ---- FC2 + final BN ----
  k_fc2_out<<<10,256,0,stream>>>(bitsA, wf2b, bias2, gf2, bf2, out);

  (void)in_sizes; (void)n_in; (void)out_size; (void)ws_size;
}

// Round 16
// 618.063 us; speedup vs baseline: 1.5136x; 1.0267x over previous
//
#include <hip/hip_runtime.h>
#include <hip/hip_bf16.h>
#include <stdint.h>

static constexpr int BATCH = 256;

#define CDIV(a,b) (((a)+(b)-1)/(b))

// fused-accumulate popcount MAC: matches v_bcnt_u32_b32 dst, src, accum
__device__ __forceinline__ int BMAC(uint32_t a, uint32_t b, int acc){
  return (int)__popc(a^b) + acc;
}

// ---------------- weight packing (all conv layers in one launch) ----------------
__global__ void k_pack_conv_all(const float* __restrict__ w2,const float* __restrict__ w3,
        const float* __restrict__ w4,const float* __restrict__ w5,const float* __restrict__ w6,
        uint32_t* __restrict__ o2,uint32_t* __restrict__ o3,uint32_t* __restrict__ o4,
        uint32_t* __restrict__ o5,uint32_t* __restrict__ o6){
  int idx = blockIdx.x*256 + threadIdx.x;
  const float* w; uint32_t* o; int CW; int rel;
  if      (idx <   4608){ w=w2; o=o2; CW=4;  rel=idx; }
  else if (idx <  13824){ w=w3; o=o3; CW=4;  rel=idx-4608; }
  else if (idx <  32256){ w=w4; o=o4; CW=8;  rel=idx-13824; }
  else if (idx <  69120){ w=w5; o=o5; CW=8;  rel=idx-32256; }
  else if (idx < 142848){ w=w6; o=o6; CW=16; rel=idx-69120; }
  else return;
  int tap = rel % 9; int t = rel / 9; int cw = t % CW; int co = t / CW;
  int Ci = CW*32;
  const float* src = w + ((size_t)co*Ci + (size_t)cw*32)*9 + tap;
  uint32_t bits = 0;
  #pragma unroll
  for (int b=0;b<32;b++) bits |= (src[(size_t)b*9] >= 0.f ? 1u:0u) << b;
  o[rel] = bits;
}

__global__ void k_pack_fc1_w(const float* __restrict__ w, uint32_t* __restrict__ out){
  int idx = blockIdx.x*256 + threadIdx.x;
  if (idx >= 1024*256) return;
  int wd = idx & 255, o = idx >> 8;
  int cw = wd >> 4, p = wd & 15;
  const float* src = w + (size_t)o*8192;
  uint32_t bits=0;
  #pragma unroll
  for (int b=0;b<32;b++) bits |= (src[(cw*32+b)*16 + p] >= 0.f ? 1u:0u) << b;
  out[idx]=bits;
}

__global__ void k_pack_fc2_w(const float* __restrict__ w, uint32_t* __restrict__ out){
  int idx = blockIdx.x*256+threadIdx.x; if (idx >= 10*32) return;
  int wd = idx & 31, o = idx >> 5;
  uint32_t bits=0;
  #pragma unroll
  for (int b=0;b<32;b++) bits |= (w[o*1024 + wd*32 + b] >= 0.f ? 1u:0u)<<b;
  out[idx]=bits;
}

// =====================================================================
// conv1 (f64-exact). Both passes: grid 2048 = (n, rowgroup of 4 rows),
// quad-pixel inner loop (4 independent f64 FMA chains, shared row reads).
// =====================================================================
__global__ __launch_bounds__(256) void k_conv1_stats4(const float* __restrict__ x,
        const float* __restrict__ w1, double* __restrict__ partials){
  __shared__ double xs[3][6][34];
  __shared__ float wf[128][27];
  int n = blockIdx.x >> 3, rg = blockIdx.x & 7;
  int y0 = rg*4;
  const float* xp = x + (size_t)n*3*1024;
  for (int i=threadIdx.x; i<3*6*34; i+=256){
    int ci = i/204, r = i%204, ly = r/34, lx = r%34;
    int gy = y0 - 1 + ly, gx = lx - 1;
    double v = 0.0;
    if (gy>=0 && gy<32 && gx>=0 && gx<32) v = (double)xp[ci*1024 + gy*32 + gx];
    (&xs[0][0][0])[i] = v;
  }
  for (int i=threadIdx.x; i<128*27; i+=256)
    (&wf[0][0])[i] = w1[i];
  __syncthreads();
  int wave = threadIdx.x>>6, lane = threadIdx.x&63;
  int c0 = (wave&1)*64, rsub = wave>>1;
  int co = c0 + lane;
  double w[27];
  #pragma unroll
  for (int k=0;k<27;k++) w[k] = (wf[co][k] >= 0.f) ? 1.0 : -1.0;
  double s=0.0, s2=0.0;
  for (int rr = rsub*2; rr < rsub*2+2; ++rr){
    for (int x0=0; x0<32; x0+=4){
      double acc[4] = {0,0,0,0};
      #pragma unroll
      for (int ci=0;ci<3;ci++)
        #pragma unroll
        for (int ky=0;ky<3;ky++){
          const double* r = &xs[ci][rr+ky][x0];
          double v0=r[0],v1=r[1],v2=r[2],v3=r[3],v4=r[4],v5=r[5];
          double w0=w[ci*9+ky*3+0], w1v=w[ci*9+ky*3+1], w2=w[ci*9+ky*3+2];
          acc[0] += v0*w0 + v1*w1v + v2*w2;
          acc[1] += v1*w0 + v2*w1v + v3*w2;
          acc[2] += v2*w0 + v3*w1v + v4*w2;
          acc[3] += v3*w0 + v4*w1v + v5*w2;
        }
      #pragma unroll
      for (int j=0;j<4;j++){ s += acc[j]; s2 += acc[j]*acc[j]; }
    }
  }
  size_t pi = (size_t)co*4096 + (size_t)n*16 + rg*2 + rsub;
  partials[pi*2+0]=s; partials[pi*2+1]=s2;
}

__global__ __launch_bounds__(256) void k_finalize_partials_p(const double* __restrict__ partials,
        const float* __restrict__ g, const float* __restrict__ b,
        double* __restrict__ A, double* __restrict__ Bv, int nPart, double invCount){
  int c = blockIdx.x;
  double s=0.0, s2=0.0;
  for (int i=threadIdx.x; i<nPart; i+=256){
    s  += partials[((size_t)c*nPart+i)*2+0];
    s2 += partials[((size_t)c*nPart+i)*2+1];
  }
  for (int off=32; off; off>>=1){ s+=__shfl_down(s,off,64); s2+=__shfl_down(s2,off,64); }
  __shared__ double sh[8];
  int wid=threadIdx.x>>6, lane=threadIdx.x&63;
  if(lane==0){sh[wid]=s;sh[4+wid]=s2;}
  __syncthreads();
  if(threadIdx.x==0){
    double S=0,S2=0;
    #pragma unroll
    for(int i=0;i<4;i++){S+=sh[i];S2+=sh[4+i];}
    double m=S*invCount, v=S2*invCount-m*m;
    double a=(double)g[c]/sqrt(v+1e-5);
    A[c]=a; Bv[c]=(double)b[c]-m*a;
  }
}

// binarize: grid 2048, quad-pixel inner loop, per-pixel ballot pack.
__global__ __launch_bounds__(256) void k_conv1_binarize5(const float* __restrict__ x,
        const float* __restrict__ w1, const double* __restrict__ A, const double* __restrict__ Bv,
        uint32_t* __restrict__ bits){
  __shared__ double xs[3][6][34];
  __shared__ float wf[128][27];
  __shared__ uint32_t wordbuf[4][128];
  int n = blockIdx.x >> 3, rg = blockIdx.x & 7;
  int y0 = rg*4;
  const float* xp = x + (size_t)n*3*1024;
  for (int i=threadIdx.x; i<3*6*34; i+=256){
    int ci = i/204, r = i%204, ly = r/34, lx = r%34;
    int gy = y0 - 1 + ly, gx = lx - 1;
    double v = 0.0;
    if (gy>=0 && gy<32 && gx>=0 && gx<32) v = (double)xp[ci*1024 + gy*32 + gx];
    (&xs[0][0][0])[i] = v;
  }
  for (int i=threadIdx.x; i<128*27; i+=256)
    (&wf[0][0])[i] = w1[i];
  __syncthreads();
  int wave = threadIdx.x>>6, lane = threadIdx.x&63;
  int c0 = (wave&1)*64, rsub = wave>>1;
  int co = c0 + lane;
  double w[27];
  #pragma unroll
  for (int k=0;k<27;k++) w[k] = (wf[co][k] >= 0.f) ? 1.0 : -1.0;
  double av = A[co], bv = Bv[co];
  for (int rr = rsub*2; rr < rsub*2+2; ++rr){
    for (int x0=0; x0<32; x0+=4){
      double acc[4] = {0,0,0,0};
      #pragma unroll
      for (int ci=0;ci<3;ci++)
        #pragma unroll
        for (int ky=0;ky<3;ky++){
          const double* r = &xs[ci][rr+ky][x0];
          double v0=r[0],v1=r[1],v2=r[2],v3=r[3],v4=r[4],v5=r[5];
          double w0=w[ci*9+ky*3+0], w1v=w[ci*9+ky*3+1], w2=w[ci*9+ky*3+2];
          acc[0] += v0*w0 + v1*w1v + v2*w2;
          acc[1] += v1*w0 + v2*w1v + v3*w2;
          acc[2] += v2*w0 + v3*w1v + v4*w2;
          acc[3] += v3*w0 + v4*w1v + v5*w2;
        }
      #pragma unroll
      for (int j=0;j<4;j++){
        int pred = (acc[j]*av + bv >= 0.0) ? 1 : 0;
        unsigned long long m = __ballot(pred);
        if (lane == 0){
          int p = rr*32 + x0 + j;
          wordbuf[(c0>>5)+0][p] = (uint32_t)m;
          wordbuf[(c0>>5)+1][p] = (uint32_t)(m>>32);
        }
      }
    }
  }
  __syncthreads();
  for (int i=threadIdx.x; i<512; i+=256){
    int cw = i>>7, p = i&127;
    bits[(size_t)n*4096 + cw*1024 + rg*128 + p] = wordbuf[cw][p];
  }
}

// =====================================================================
// XNOR conv family: zero+fill staging, odd PITCH, row-wise inner loop,
// fused-bcnt MAC chains, fused exact int64 stats.
// =====================================================================
template<int CW,int H,int W,int HP,int PITCH>
__device__ __forceinline__ void stage_bits(const uint32_t* __restrict__ ip, uint32_t* __restrict__ inlds){
  for (int i=threadIdx.x; i<CW*HP*PITCH; i+=256) inlds[i]=0u;
}

template<int CW,int H,int W,int HP,int PITCH>
__device__ __forceinline__ void fill_bits(const uint32_t* __restrict__ ip, uint32_t* __restrict__ inlds){
  constexpr int LOGW  = (W==32)?5:(W==16)?4:3;
  constexpr int LOGHW = ((H*W)==1024)?10:((H*W)==256)?8:6;
  for (int i=threadIdx.x; i<CW*H*W; i+=256){
    int cw = i >> LOGHW;
    int rem = i & (H*W-1);
    int y = rem >> LOGW;
    int x = rem & (W-1);
    inlds[cw*HP*PITCH + (y+1)*PITCH + (x+1)] = ip[i];
  }
}

// ---- fused conv + pool, TWO output channels per thread (L2, L4)
template<int CW,int H,int W,int CO,int COB,int NX>
__global__ __launch_bounds__(256) void k_xconv_pool2(const uint32_t* __restrict__ in,
        const uint32_t* __restrict__ wb, int16_t* __restrict__ out, long long* __restrict__ part){
  constexpr int HP = H+2;
  constexpr int PITCH = W+3;          // odd
  constexpr int WP = CW*9+1;
  constexpr int NG = CO/COB;
  constexpr int XS = W/NX;
  constexpr int UNITS = (H/2)*XS;
  static_assert((COB/2)*UNITS==256, "thread mapping");
  __shared__ uint32_t inlds[CW*HP*PITCH];
  __shared__ uint32_t wlds[COB*WP];
  __shared__ int colpc[COB][10];
  int n = blockIdx.x / NG, cg = blockIdx.x % NG;
  int co0 = cg*COB;
  const uint32_t* ip = in + (size_t)n*CW*H*W;
  stage_bits<CW,H,W,HP,PITCH>(ip, inlds);
  for (int i=threadIdx.x; i<COB*CW*9; i+=256){
    int co = i/(CW*9); int r = i%(CW*9);
    wlds[co*WP + r] = wb[(size_t)(co0+co)*CW*9 + r];
  }
  __syncthreads();
  fill_bits<CW,H,W,HP,PITCH>(ip, inlds);
  for (int i=threadIdx.x; i<COB*9; i+=256){
    int co=i/9, tap=i%9; int s=0;
    #pragma unroll
    for (int cw=0;cw<CW;cw++) s += __popc(wlds[co*WP + cw*9 + tap]);
    colpc[co][tap]=s;
  }
  __syncthreads();
  int t = threadIdx.x;
  int cog = t / UNITS;
  int rem = t % UNITS;
  int yy = rem / XS;
  int xs = (rem % XS)*NX;
  int c0 = cog*2;
  int acc0[2][NX], acc1[2][NX];
  #pragma unroll
  for (int c=0;c<2;c++)
    #pragma unroll
    for (int i2=0;i2<NX;i2++){acc0[c][i2]=0;acc1[c][i2]=0;}
  for (int cw=0; cw<CW; cw++){
    uint32_t wr[2][9];
    #pragma unroll
    for (int c=0;c<2;c++)
      #pragma unroll
      for (int k=0;k<9;k++) wr[c][k]=wlds[(c0+c)*WP+cw*9+k];
    const uint32_t* ib = &inlds[cw*HP*PITCH + (2*yy)*PITCH + xs];
    {
      uint32_t row[NX+2];
      #pragma unroll
      for (int j=0;j<NX+2;j++) row[j] = ib[j];
      #pragma unroll
      for (int q=0;q<NX;q++)
        #pragma unroll
        for (int c=0;c<2;c++){
          acc0[c][q] = BMAC(row[q],  wr[c][0], acc0[c][q]);
          acc0[c][q] = BMAC(row[q+1],wr[c][1], acc0[c][q]);
          acc0[c][q] = BMAC(row[q+2],wr[c][2], acc0[c][q]);
        }
    }
    #pragma unroll
    for (int rrow=1; rrow<=2; rrow++){
      uint32_t row[NX+2];
      #pragma unroll
      for (int j=0;j<NX+2;j++) row[j] = ib[rrow*PITCH + j];
      #pragma unroll
      for (int q=0;q<NX;q++)
        #pragma unroll
        for (int c=0;c<2;c++){
          acc0[c][q] = BMAC(row[q],  wr[c][3*rrow+0], acc0[c][q]);
          acc0[c][q] = BMAC(row[q+1],wr[c][3*rrow+1], acc0[c][q]);
          acc0[c][q] = BMAC(row[q+2],wr[c][3*rrow+2], acc0[c][q]);
          acc1[c][q] = BMAC(row[q],  wr[c][3*rrow-3], acc1[c][q]);
          acc1[c][q] = BMAC(row[q+1],wr[c][3*rrow-2], acc1[c][q]);
          acc1[c][q] = BMAC(row[q+2],wr[c][3*rrow-1], acc1[c][q]);
        }
    }
    {
      uint32_t row[NX+2];
      #pragma unroll
      for (int j=0;j<NX+2;j++) row[j] = ib[3*PITCH + j];
      #pragma unroll
      for (int q=0;q<NX;q++)
        #pragma unroll
        for (int c=0;c<2;c++){
          acc1[c][q] = BMAC(row[q],  wr[c][6], acc1[c][q]);
          acc1[c][q] = BMAC(row[q+1],wr[c][7], acc1[c][q]);
          acc1[c][q] = BMAC(row[q+2],wr[c][8], acc1[c][q]);
        }
    }
  }
  #pragma unroll
  for (int c=0;c<2;c++){
    const int* cp = colpc[c0+c];
    int16_t res[NX/2];
    #pragma unroll
    for (int tp=0; tp<NX/2; tp++){
      int best=-32768;
      #pragma unroll
      for (int rrow=0;rrow<2;rrow++){
        int kyi = (rrow==0 && yy==0) ? 0 : ((rrow==1 && yy==H/2-1) ? 2 : -1);
        #pragma unroll
        for (int dx=0;dx<2;dx++){
          int q = 2*tp+dx;
          int x = xs+q;
          int kxi = (x==0)?0:((x==W-1)?2:-1);
          int acc = rrow? acc1[c][q]:acc0[c][q];
          int corr=0, nv=9;
          if (kyi>=0){ corr += cp[kyi*3+0]+cp[kyi*3+1]+cp[kyi*3+2]; }
          if (kxi>=0){ corr += cp[0+kxi]+cp[3+kxi]+cp[6+kxi]; }
          if (kyi>=0 && kxi>=0){ corr -= cp[kyi*3+kxi]; nv=4; }
          else if (kyi>=0 || kxi>=0) nv=6;
          int dot = 32*CW*nv - 2*(acc - corr);
          best = dot>best?dot:best;
        }
      }
      res[tp]=(int16_t)best;
    }
    int16_t* op = out + (((size_t)n*CO + (co0+c0+c))*(H/2) + yy)*(W/2) + xs/2;
    #pragma unroll
    for (int tp=0;tp<NX/2;tp++) op[tp]=res[tp];
    int ssum=0; long long ssq=0;
    #pragma unroll
    for (int tp=0;tp<NX/2;tp++){ int v=res[tp]; ssum+=v; ssq += (long long)(v*v); }
    long long s = (long long)ssum;
    #pragma unroll
    for (int off=UNITS>>1; off; off>>=1){ s += __shfl_down(s,off,UNITS); ssq += __shfl_down(ssq,off,UNITS); }
    if (rem==0){
      size_t pi = (size_t)(co0+c0+c)*BATCH + n;
      part[pi*2+0]=s; part[pi*2+1]=ssq;
    }
  }
}

// ---- fused conv + pool, one channel per thread (L6)
template<int CW,int H,int W,int CO,int COB,int NX>
__global__ __launch_bounds__(256) void k_xconv_pool(const uint32_t* __restrict__ in,
        const uint32_t* __restrict__ wb, int16_t* __restrict__ out, long long* __restrict__ part){
  constexpr int HP = H+2;
  constexpr int PITCH = W+3;          // odd
  constexpr int WP = CW*9+1;
  constexpr int NG = CO/COB;
  constexpr int XS = W/NX;
  constexpr int UNITS = (H/2)*XS;
  static_assert(COB*UNITS==256, "thread mapping");
  __shared__ uint32_t inlds[CW*HP*PITCH];
  __shared__ uint32_t wlds[COB*WP];
  __shared__ int colpc[COB][10];
  int n = blockIdx.x / NG, cg = blockIdx.x % NG;
  int co0 = cg*COB;
  const uint32_t* ip = in + (size_t)n*CW*H*W;
  stage_bits<CW,H,W,HP,PITCH>(ip, inlds);
  for (int i=threadIdx.x; i<COB*CW*9; i+=256){
    int co = i/(CW*9); int r = i%(CW*9);
    wlds[co*WP + r] = wb[(size_t)(co0+co)*CW*9 + r];
  }
  __syncthreads();
  fill_bits<CW,H,W,HP,PITCH>(ip, inlds);
  for (int i=threadIdx.x; i<COB*9; i+=256){
    int co=i/9, tap=i%9; int s=0;
    #pragma unroll
    for (int cw=0;cw<CW;cw++) s += __popc(wlds[co*WP + cw*9 + tap]);
    colpc[co][tap]=s;
  }
  __syncthreads();
  int t = threadIdx.x;
  int col = t / UNITS;
  int rem = t % UNITS;
  int yy = rem / XS;
  int xs = (rem % XS)*NX;
  int co = co0 + col;
  int acc0[NX], acc1[NX];
  #pragma unroll
  for (int i2=0;i2<NX;i2++){acc0[i2]=0;acc1[i2]=0;}
  for (int cw=0; cw<CW; cw++){
    uint32_t wr[9];
    #pragma unroll
    for (int k=0;k<9;k++) wr[k]=wlds[col*WP+cw*9+k];
    const uint32_t* ib = &inlds[cw*HP*PITCH + (2*yy)*PITCH + xs];
    {
      uint32_t row[NX+2];
      #pragma unroll
      for (int j=0;j<NX+2;j++) row[j] = ib[j];
      #pragma unroll
      for (int q=0;q<NX;q++){
        acc0[q] = BMAC(row[q],  wr[0], acc0[q]);
        acc0[q] = BMAC(row[q+1],wr[1], acc0[q]);
        acc0[q] = BMAC(row[q+2],wr[2], acc0[q]);
      }
    }
    #pragma unroll
    for (int rrow=1; rrow<=2; rrow++){
      uint32_t row[NX+2];
      #pragma unroll
      for (int j=0;j<NX+2;j++) row[j] = ib[rrow*PITCH + j];
      #pragma unroll
      for (int q=0;q<NX;q++){
        acc0[q] = BMAC(row[q],  wr[3*rrow+0], acc0[q]);
        acc0[q] = BMAC(row[q+1],wr[3*rrow+1], acc0[q]);
        acc0[q] = BMAC(row[q+2],wr[3*rrow+2], acc0[q]);
        acc1[q] = BMAC(row[q],  wr[3*rrow-3], acc1[q]);
        acc1[q] = BMAC(row[q+1],wr[3*rrow-2], acc1[q]);
        acc1[q] = BMAC(row[q+2],wr[3*rrow-1], acc1[q]);
      }
    }
    {
      uint32_t row[NX+2];
      #pragma unroll
      for (int j=0;j<NX+2;j++) row[j] = ib[3*PITCH + j];
      #pragma unroll
      for (int q=0;q<NX;q++){
        acc1[q] = BMAC(row[q],  wr[6], acc1[q]);
        acc1[q] = BMAC(row[q+1],wr[7], acc1[q]);
        acc1[q] = BMAC(row[q+2],wr[8], acc1[q]);
      }
    }
  }
  const int* cp = colpc[col];
  int16_t res[NX/2];
  #pragma unroll
  for (int tp=0; tp<NX/2; tp++){
    int best=-32768;
    #pragma unroll
    for (int rrow=0;rrow<2;rrow++){
      int kyi = (rrow==0 && yy==0) ? 0 : ((rrow==1 && yy==H/2-1) ? 2 : -1);
      #pragma unroll
      for (int dx=0;dx<2;dx++){
        int q = 2*tp+dx;
        int x = xs+q;
        int kxi = (x==0)?0:((x==W-1)?2:-1);
        int acc = rrow? acc1[q]:acc0[q];
        int corr=0, nv=9;
        if (kyi>=0){ corr += cp[kyi*3+0]+cp[kyi*3+1]+cp[kyi*3+2]; }
        if (kxi>=0){ corr += cp[0+kxi]+cp[3+kxi]+cp[6+kxi]; }
        if (kyi>=0 && kxi>=0){ corr -= cp[kyi*3+kxi]; nv=4; }
        else if (kyi>=0 || kxi>=0) nv=6;
        int dot = 32*CW*nv - 2*(acc - corr);
        best = dot>best?dot:best;
      }
    }
    res[tp]=(int16_t)best;
  }
  int16_t* op = out + (((size_t)n*CO + co)*(H/2) + yy)*(W/2) + xs/2;
  #pragma unroll
  for (int tp=0;tp<NX/2;tp++) op[tp]=res[tp];
  int ssum=0; long long ssq=0;
  #pragma unroll
  for (int tp=0;tp<NX/2;tp++){ int v=res[tp]; ssum+=v; ssq += (long long)(v*v); }
  long long s = (long long)ssum;
  #pragma unroll
  for (int off=UNITS>>1; off; off>>=1){ s += __shfl_down(s,off,UNITS); ssq += __shfl_down(ssq,off,UNITS); }
  if (rem==0){
    size_t pi = (size_t)co*BATCH + n;
    part[pi*2+0]=s; part[pi*2+1]=ssq;
  }
}

// ---- plain conv, two channels per thread (L3, L5)
template<int CW,int H,int W,int CO,int COB,int NX>
__global__ __launch_bounds__(256) void k_xconv(const uint32_t* __restrict__ in,
        const uint32_t* __restrict__ wb, int16_t* __restrict__ out, long long* __restrict__ part){
  constexpr int HP = H+2;
  constexpr int PITCH = W+3;          // odd
  constexpr int WP = CW*9+1;
  constexpr int NG = CO/COB;
  constexpr int XS = W/NX;
  constexpr int UNITS = H*XS;
  static_assert((COB/2)*UNITS==256, "thread mapping");
  __shared__ uint32_t inlds[CW*HP*PITCH];
  __shared__ uint32_t wlds[COB*WP];
  __shared__ int colpc[COB][10];
  int n = blockIdx.x / NG, cg = blockIdx.x % NG;
  int co0 = cg*COB;
  const uint32_t* ip = in + (size_t)n*CW*H*W;
  stage_bits<CW,H,W,HP,PITCH>(ip, inlds);
  for (int i=threadIdx.x; i<COB*CW*9; i+=256){
    int co = i/(CW*9); int r = i%(CW*9);
    wlds[co*WP + r] = wb[(size_t)(co0+co)*CW*9 + r];
  }
  __syncthreads();
  fill_bits<CW,H,W,HP,PITCH>(ip, inlds);
  for (int i=threadIdx.x; i<COB*9; i+=256){
    int co=i/9, tap=i%9; int s=0;
    #pragma unroll
    for (int cw=0;cw<CW;cw++) s += __popc(wlds[co*WP + cw*9 + tap]);
    colpc[co][tap]=s;
  }
  __syncthreads();
  int t = threadIdx.x;
  int cog = t / UNITS;
  int rem = t % UNITS;
  int y = rem / XS;
  int xs = (rem % XS)*NX;
  int c0 = cog*2;
  int acc[2][NX];
  #pragma unroll
  for (int c=0;c<2;c++)
    #pragma unroll
    for (int i2=0;i2<NX;i2++) acc[c][i2]=0;
  for (int cw=0; cw<CW; cw++){
    uint32_t wr[2][9];
    #pragma unroll
    for (int c=0;c<2;c++)
      #pragma unroll
      for (int k=0;k<9;k++) wr[c][k]=wlds[(c0+c)*WP+cw*9+k];
    const uint32_t* ib = &inlds[cw*HP*PITCH + y*PITCH + xs];
    #pragma unroll
    for (int rrow=0; rrow<3; rrow++){
      uint32_t row[NX+2];
      #pragma unroll
      for (int j=0;j<NX+2;j++) row[j] = ib[rrow*PITCH + j];
      #pragma unroll
      for (int q=0;q<NX;q++){
        acc[0][q] = BMAC(row[q],  wr[0][3*rrow+0], acc[0][q]);
        acc[0][q] = BMAC(row[q+1],wr[0][3*rrow+1], acc[0][q]);
        acc[0][q] = BMAC(row[q+2],wr[0][3*rrow+2], acc[0][q]);
        acc[1][q] = BMAC(row[q],  wr[1][3*rrow+0], acc[1][q]);
        acc[1][q] = BMAC(row[q+1],wr[1][3*rrow+1], acc[1][q]);
        acc[1][q] = BMAC(row[q+2],wr[1][3*rrow+2], acc[1][q]);
      }
    }
  }
  int kyi = (y==0)?0:((y==H-1)?2:-1);
  #pragma unroll
  for (int c=0;c<2;c++){
    const int* cp = colpc[c0+c];
    int16_t rbuf[NX];
    int ssum=0; long long ssq=0;
    #pragma unroll
    for (int q=0;q<NX;q++){
      int x = xs+q;
      int kxi = (x==0)?0:((x==W-1)?2:-1);
      int corr=0, nv=9;
      if (kyi>=0){ corr += cp[kyi*3+0]+cp[kyi*3+1]+cp[kyi*3+2]; }
      if (kxi>=0){ corr += cp[0+kxi]+cp[3+kxi]+cp[6+kxi]; }
      if (kyi>=0 && kxi>=0){ corr -= cp[kyi*3+kxi]; nv=4; }
      else if (kyi>=0 || kxi>=0) nv=6;
      int dot = 32*CW*nv - 2*(acc[c][q] - corr);
      rbuf[q] = (int16_t)dot;
      ssum+=dot; ssq+=(long long)(dot*dot);
    }
    int16_t* op = out + (((size_t)n*CO + (co0+c0+c))*H + y)*W + xs;
    #pragma unroll
    for (int q=0;q<NX;q++) op[q]=rbuf[q];
    long long s=(long long)ssum, q2=ssq;
    #pragma unroll
    for (int off=UNITS>>1; off; off>>=1){ s += __shfl_down(s,off,UNITS); q2 += __shfl_down(q2,off,UNITS); }
    if (rem==0){
      size_t pi = (size_t)(co0+c0+c)*BATCH + n;
      part[pi*2+0]=s; part[pi*2+1]=q2;
    }
  }
}

// ---------------- parallel per-channel finalize from [c][256] int64 ----------------
__global__ __launch_bounds__(256) void k_chstats_fin_p(const long long* __restrict__ part,
        const float* __restrict__ g, const float* __restrict__ b,
        double* __restrict__ A, double* __restrict__ Bv, double invCount){
  int c = blockIdx.x;
  long long s  = part[((size_t)c*BATCH+threadIdx.x)*2+0];
  long long s2 = part[((size_t)c*BATCH+threadIdx.x)*2+1];
  for (int off=32; off; off>>=1){ s+=__shfl_down(s,off,64); s2+=__shfl_down(s2,off,64); }
  __shared__ long long sh[8];
  int wid=threadIdx.x>>6, lane=threadIdx.x&63;
  if(lane==0){sh[wid]=s;sh[4+wid]=s2;}
  __syncthreads();
  if(threadIdx.x==0){
    long long S=0,S2=0;
    #pragma unroll
    for(int i=0;i<4;i++){S+=sh[i];S2+=sh[4+i];}
    double m=(double)S*invCount, v=(double)S2*invCount-m*m;
    double a=(double)g[c]/sqrt(v+1e-5);
    A[c]=a; Bv[c]=(double)b[c]-m*a;
  }
}

// ---------------- binarize BN(conv) and pack ----------------
__global__ void k_binarize_pack(const int16_t* __restrict__ in, const double* __restrict__ A,
                                const double* __restrict__ Bv, uint32_t* __restrict__ bits,
                                int C, int HW){
  int CW = C>>5;
  size_t total = (size_t)BATCH*CW*HW;
  size_t idx = (size_t)blockIdx.x*256+threadIdx.x;
  if (idx>=total) return;
  int hw = (int)(idx % HW); size_t t = idx/HW;
  int cw = (int)(t % CW); int n = (int)(t / CW);
  uint32_t wordv=0;
  for (int b=0;b<32;b++){
    int c = cw*32+b;
    double v = (double)in[((size_t)n*C + c)*HW + hw];
    if (v*A[c]+Bv[c] >= 0.0) wordv |= 1u<<b;
  }
  bits[idx]=wordv;
}

// ---------------- FC1 ----------------
__global__ void k_fc1(const uint32_t* __restrict__ actbits, const uint32_t* __restrict__ wb,
                      int16_t* __restrict__ out){
  int og = blockIdx.x & 3; int n = blockIdx.x >> 2;
  int o = og*256 + threadIdx.x;
  __shared__ uint32_t sact[256];
  sact[threadIdx.x] = actbits[(size_t)n*256 + threadIdx.x];
  __syncthreads();
  const uint32_t* wp = wb + (size_t)o*256;
  int acc=0;
  #pragma unroll 8
  for (int k=0;k<256;k++) acc = BMAC(sact[k], wp[k], acc);
  out[(size_t)n*1024 + o] = (int16_t)(8192 - 2*acc);
}

__global__ void k_fc_stats(const int16_t* __restrict__ in, const float* __restrict__ g,
                           const float* __restrict__ b, double* __restrict__ A, double* __restrict__ Bv){
  int f = blockIdx.x;
  double v = (double)in[(size_t)threadIdx.x*1024 + f];
  double s=v, s2=v*v;
  __shared__ double sh[8];
  for (int off=32; off; off>>=1){ s+=__shfl_down(s,off,64); s2+=__shfl_down(s2,off,64); }
  int wid=threadIdx.x>>6, lane=threadIdx.x&63;
  if(lane==0){sh[wid]=s;sh[4+wid]=s2;}
  __syncthreads();
  if(threadIdx.x==0){
    double S=0,S2=0;
    #pragma unroll
    for(int i=0;i<4;i++){S+=sh[i];S2+=sh[4+i];}
    double m=S/256.0, var=S2/256.0-m*m;
    double a=(double)g[f]/sqrt(var+1e-5);
    A[f]=a; Bv[f]=(double)b[f]-m*a;
  }
}

__global__ void k_binpack_fc(const int16_t* __restrict__ in, const double* __restrict__ A,
                             const double* __restrict__ Bv, uint32_t* __restrict__ bits){
  int idx = blockIdx.x*256+threadIdx.x;
  if (idx >= 256*32) return;
  int w = idx & 31, n = idx >> 5;
  uint32_t word=0;
  for (int b=0;b<32;b++){
    int f = w*32+b;
    double v=(double)in[(size_t)n*1024+f];
    if (v*A[f]+Bv[f] >= 0.0) word|=1u<<b;
  }
  bits[idx]=word;
}

// ---------------- FC2 + final BN -> float out ----------------
__global__ void k_fc2_out(const uint32_t* __restrict__ actbits, const uint32_t* __restrict__ wb,
                          const float* __restrict__ bias2, const float* __restrict__ g,
                          const float* __restrict__ b, float* __restrict__ out){
  int o = blockIdx.x;     // 0..9
  int n = threadIdx.x;    // 0..255
  const uint32_t* ap = actbits + (size_t)n*32;
  const uint32_t* wp = wb + (size_t)o*32;
  int acc=0;
  #pragma unroll
  for (int k=0;k<32;k++) acc = BMAC(ap[k], wp[k], acc);
  double h = (double)(1024 - 2*acc) + (double)bias2[o];
  double s=h, s2=h*h;
  __shared__ double sh[8];
  for(int off=32;off;off>>=1){s+=__shfl_down(s,off,64);s2+=__shfl_down(s2,off,64);}
  int wid=threadIdx.x>>6,lane=threadIdx.x&63;
  if(lane==0){sh[wid]=s;sh[4+wid]=s2;}
  __syncthreads();
  __shared__ double sm, sinv;
  if(threadIdx.x==0){
    double S=0,S2=0;
    #pragma unroll
    for(int i=0;i<4;i++){S+=sh[i];S2+=sh[4+i];}
    double m=S/256.0, v=S2/256.0-m*m;
    sm=m; sinv=1.0/sqrt(v+1e-5);
  }
  __syncthreads();
  double r = (h - sm)*sinv*(double)g[o] + (double)b[o];
  out[(size_t)n*10 + o] = (float)r;
}

extern "C" void kernel_launch(void* const* d_in, const int* in_sizes, int n_in,
                              void* d_out, int out_size, void* d_ws, size_t ws_size,
                              hipStream_t stream) {
  const float* x   = (const float*)d_in[0];
  const float* w1  = (const float*)d_in[1];
  const float* g1  = (const float*)d_in[2];
  const float* b1  = (const float*)d_in[3];
  const float* w2  = (const float*)d_in[4];
  const float* g2  = (const float*)d_in[5];
  const float* b2  = (const float*)d_in[6];
  const float* w3  = (const float*)d_in[7];
  const float* g3  = (const float*)d_in[8];
  const float* b3  = (const float*)d_in[9];
  const float* w4  = (const float*)d_in[10];
  const float* g4  = (const float*)d_in[11];
  const float* b4  = (const float*)d_in[12];
  const float* w5  = (const float*)d_in[13];
  const float* g5  = (const float*)d_in[14];
  const float* b5  = (const float*)d_in[15];
  const float* w6  = (const float*)d_in[16];
  const float* g6  = (const float*)d_in[17];
  const float* b6  = (const float*)d_in[18];
  const float* wf1 = (const float*)d_in[19];
  const float* gf1 = (const float*)d_in[20];
  const float* bf1 = (const float*)d_in[21];
  const float* wf2 = (const float*)d_in[22];
  const float* bias2=(const float*)d_in[23];
  const float* gf2 = (const float*)d_in[24];
  const float* bf2 = (const float*)d_in[25];
  float* out = (float*)d_out;

  char* ws = (char*)d_ws;
  size_t off = 0;
  auto alloc = [&](size_t bytes)->char*{ char* p = ws + off; off = (off + bytes + 255) & ~(size_t)255; return p; };

  uint32_t* wb2  = (uint32_t*)alloc(4608ull*4);
  uint32_t* wb3  = (uint32_t*)alloc(9216ull*4);
  uint32_t* wb4  = (uint32_t*)alloc(18432ull*4);
  uint32_t* wb5  = (uint32_t*)alloc(36864ull*4);
  uint32_t* wb6  = (uint32_t*)alloc(73728ull*4);
  uint32_t* wf1b = (uint32_t*)alloc(262144ull*4);
  uint32_t* wf2b = (uint32_t*)alloc(320ull*4);
  double*   part = (double*)  alloc(128ull*4096*2*8);
  long long* pll = (long long*)alloc(512ull*256*2*8);
  double*   Abuf = (double*)  alloc(1024ull*8);
  double*   Bbuf = (double*)  alloc(1024ull*8);
  uint32_t* bitsA= (uint32_t*)alloc(1048576ull*4);
  uint32_t* bitsB= (uint32_t*)alloc(262144ull*4);
  int16_t*  conv = (int16_t*) alloc(16777216ull*2);

  // pack weights (single launch for all conv layers)
  k_pack_conv_all<<<CDIV(142848,256),256,0,stream>>>(w2,w3,w4,w5,w6, wb2,wb3,wb4,wb5,wb6);
  k_pack_fc1_w<<<CDIV(262144,256),256,0,stream>>>(wf1, wf1b);
  k_pack_fc2_w<<<CDIV(320,256),256,0,stream>>>(wf2, wf2b);

  // ---- layer 1 ----
  k_conv1_stats4<<<2048,256,0,stream>>>(x, w1, part);
  k_finalize_partials_p<<<128,256,0,stream>>>(part, g1, b1, Abuf, Bbuf, 4096, 1.0/(256.0*1024.0));
  k_conv1_binarize5<<<2048,256,0,stream>>>(x, w1, Abuf, Bbuf, bitsA);

  // ---- layer 2: conv+pool -> [256,128,16,16] ----
  k_xconv_pool2<4,32,32,128,8,8><<<256*16,256,0,stream>>>(bitsA, wb2, conv, pll);
  k_chstats_fin_p<<<128,256,0,stream>>>(pll, g2, b2, Abuf, Bbuf, 1.0/(256.0*256.0));
  k_binarize_pack<<<CDIV(256ull*4*256,256),256,0,stream>>>(conv, Abuf, Bbuf, bitsB, 128, 256);

  // ---- layer 3: conv -> [256,256,16,16] ----
  k_xconv<4,16,16,256,16,8><<<256*16,256,0,stream>>>(bitsB, wb3, conv, pll);
  k_chstats_fin_p<<<256,256,0,stream>>>(pll, g3, b3, Abuf, Bbuf, 1.0/(256.0*256.0));
  k_binarize_pack<<<CDIV(256ull*8*256,256),256,0,stream>>>(conv, Abuf, Bbuf, bitsA, 256, 256);

  // ---- layer 4: conv+pool -> [256,256,8,8] ----
  k_xconv_pool2<8,16,16,256,32,8><<<256*8,256,0,stream>>>(bitsA, wb4, conv, pll);
  k_chstats_fin_p<<<256,256,0,stream>>>(pll, g4, b4, Abuf, Bbuf, 1.0/(256.0*64.0));
  k_binarize_pack<<<CDIV(256ull*8*64,256),256,0,stream>>>(conv, Abuf, Bbuf, bitsB, 256, 64);

  // ---- layer 5: conv -> [256,512,8,8] ----
  k_xconv<8,8,8,512,64,8><<<256*8,256,0,stream>>>(bitsB, wb5, conv, pll);
  k_chstats_fin_p<<<512,256,0,stream>>>(pll, g5, b5, Abuf, Bbuf, 1.0/(256.0*64.0));
  k_binarize_pack<<<CDIV(256ull*16*64,256),256,0,stream>>>(conv, Abuf, Bbuf, bitsA, 512, 64);

  // ---- layer 6: conv+pool -> [256,512,4,4] ----
  k_xconv_pool<16,8,8,512,64,8><<<256*8,256,0,stream>>>(bitsA, wb6, conv, pll);
  k_chstats_fin_p<<<512,256,0,stream>>>(pll, g6, b6, Abuf, Bbuf, 1.0/(256.0*16.0));
  k_binarize_pack<<<CDIV(256ull*16*16,256),256,0,stream>>>(conv, Abuf, Bbuf, bitsB, 512, 16);

  // ---- FC1 ----
  k_fc1<<<256*4,256,0,stream>>>(bitsB, wf1b, conv);
  k_fc_stats<<<1024,256,0,stream>>>(conv, gf1, bf1, Abuf, Bbuf);
  k_binpack_fc<<<CDIV(256*32,256),256,0,stream>>>(conv, Abuf, Bbuf, bitsA);

  // ---- FC2 + final BN ----
  k_fc2_out<<<10,256,0,stream>>>(bitsA, wf2b, bias2, gf2, bf2, out);

  (void)in_sizes; (void)n_in; (void)out_size; (void)ws_size;
}

// Round 17
// 535.620 us; speedup vs baseline: 1.7466x; 1.1539x over previous
//
#include <hip/hip_runtime.h>
#include <hip/hip_bf16.h>
#include <stdint.h>

static constexpr int BATCH = 256;

#define CDIV(a,b) (((a)+(b)-1)/(b))

// fused-accumulate popcount MAC, forced via inline asm:
//   v_xor_b32  x, a, b
//   v_bcnt_u32_b32 r, x, acc      (bcnt's 2nd src is the accumulate operand)
__device__ __forceinline__ int BMAC(uint32_t a, uint32_t b, int acc){
  uint32_t x; int r;
  asm("v_xor_b32 %0, %1, %2" : "=v"(x) : "v"(a), "v"(b));
  asm("v_bcnt_u32_b32 %0, %1, %2" : "=v"(r) : "v"(x), "v"(acc));
  return r;
}

// ---------------- weight packing (all conv layers in one launch) ----------------
__global__ void k_pack_conv_all(const float* __restrict__ w2,const float* __restrict__ w3,
        const float* __restrict__ w4,const float* __restrict__ w5,const float* __restrict__ w6,
        uint32_t* __restrict__ o2,uint32_t* __restrict__ o3,uint32_t* __restrict__ o4,
        uint32_t* __restrict__ o5,uint32_t* __restrict__ o6){
  int idx = blockIdx.x*256 + threadIdx.x;
  const float* w; uint32_t* o; int CW; int rel;
  if      (idx <   4608){ w=w2; o=o2; CW=4;  rel=idx; }
  else if (idx <  13824){ w=w3; o=o3; CW=4;  rel=idx-4608; }
  else if (idx <  32256){ w=w4; o=o4; CW=8;  rel=idx-13824; }
  else if (idx <  69120){ w=w5; o=o5; CW=8;  rel=idx-32256; }
  else if (idx < 142848){ w=w6; o=o6; CW=16; rel=idx-69120; }
  else return;
  int tap = rel % 9; int t = rel / 9; int cw = t % CW; int co = t / CW;
  int Ci = CW*32;
  const float* src = w + ((size_t)co*Ci + (size_t)cw*32)*9 + tap;
  uint32_t bits = 0;
  #pragma unroll
  for (int b=0;b<32;b++) bits |= (src[(size_t)b*9] >= 0.f ? 1u:0u) << b;
  o[rel] = bits;
}

__global__ void k_pack_fc1_w(const float* __restrict__ w, uint32_t* __restrict__ out){
  int idx = blockIdx.x*256 + threadIdx.x;
  if (idx >= 1024*256) return;
  int wd = idx & 255, o = idx >> 8;
  int cw = wd >> 4, p = wd & 15;
  const float* src = w + (size_t)o*8192;
  uint32_t bits=0;
  #pragma unroll
  for (int b=0;b<32;b++) bits |= (src[(cw*32+b)*16 + p] >= 0.f ? 1u:0u) << b;
  out[idx]=bits;
}

__global__ void k_pack_fc2_w(const float* __restrict__ w, uint32_t* __restrict__ out){
  int idx = blockIdx.x*256+threadIdx.x; if (idx >= 10*32) return;
  int wd = idx & 31, o = idx >> 5;
  uint32_t bits=0;
  #pragma unroll
  for (int b=0;b<32;b++) bits |= (w[o*1024 + wd*32 + b] >= 0.f ? 1u:0u)<<b;
  out[idx]=bits;
}

// =====================================================================
// conv1 (f64-exact). Both passes: grid 2048 = (n, rowgroup of 4 rows),
// quad-pixel inner loop (4 independent f64 FMA chains, shared row reads).
// =====================================================================
__global__ __launch_bounds__(256) void k_conv1_stats4(const float* __restrict__ x,
        const float* __restrict__ w1, double* __restrict__ partials){
  __shared__ double xs[3][6][34];
  __shared__ float wf[128][27];
  int n = blockIdx.x >> 3, rg = blockIdx.x & 7;
  int y0 = rg*4;
  const float* xp = x + (size_t)n*3*1024;
  for (int i=threadIdx.x; i<3*6*34; i+=256){
    int ci = i/204, r = i%204, ly = r/34, lx = r%34;
    int gy = y0 - 1 + ly, gx = lx - 1;
    double v = 0.0;
    if (gy>=0 && gy<32 && gx>=0 && gx<32) v = (double)xp[ci*1024 + gy*32 + gx];
    (&xs[0][0][0])[i] = v;
  }
  for (int i=threadIdx.x; i<128*27; i+=256)
    (&wf[0][0])[i] = w1[i];
  __syncthreads();
  int wave = threadIdx.x>>6, lane = threadIdx.x&63;
  int c0 = (wave&1)*64, rsub = wave>>1;
  int co = c0 + lane;
  double w[27];
  #pragma unroll
  for (int k=0;k<27;k++) w[k] = (wf[co][k] >= 0.f) ? 1.0 : -1.0;
  double s=0.0, s2=0.0;
  for (int rr = rsub*2; rr < rsub*2+2; ++rr){
    for (int x0=0; x0<32; x0+=4){
      double acc[4] = {0,0,0,0};
      #pragma unroll
      for (int ci=0;ci<3;ci++)
        #pragma unroll
        for (int ky=0;ky<3;ky++){
          const double* r = &xs[ci][rr+ky][x0];
          double v0=r[0],v1=r[1],v2=r[2],v3=r[3],v4=r[4],v5=r[5];
          double w0=w[ci*9+ky*3+0], w1v=w[ci*9+ky*3+1], w2=w[ci*9+ky*3+2];
          acc[0] += v0*w0 + v1*w1v + v2*w2;
          acc[1] += v1*w0 + v2*w1v + v3*w2;
          acc[2] += v2*w0 + v3*w1v + v4*w2;
          acc[3] += v3*w0 + v4*w1v + v5*w2;
        }
      #pragma unroll
      for (int j=0;j<4;j++){ s += acc[j]; s2 += acc[j]*acc[j]; }
    }
  }
  size_t pi = (size_t)co*4096 + (size_t)n*16 + rg*2 + rsub;
  partials[pi*2+0]=s; partials[pi*2+1]=s2;
}

__global__ __launch_bounds__(256) void k_finalize_partials_p(const double* __restrict__ partials,
        const float* __restrict__ g, const float* __restrict__ b,
        double* __restrict__ A, double* __restrict__ Bv, int nPart, double invCount){
  int c = blockIdx.x;
  double s=0.0, s2=0.0;
  for (int i=threadIdx.x; i<nPart; i+=256){
    s  += partials[((size_t)c*nPart+i)*2+0];
    s2 += partials[((size_t)c*nPart+i)*2+1];
  }
  for (int off=32; off; off>>=1){ s+=__shfl_down(s,off,64); s2+=__shfl_down(s2,off,64); }
  __shared__ double sh[8];
  int wid=threadIdx.x>>6, lane=threadIdx.x&63;
  if(lane==0){sh[wid]=s;sh[4+wid]=s2;}
  __syncthreads();
  if(threadIdx.x==0){
    double S=0,S2=0;
    #pragma unroll
    for(int i=0;i<4;i++){S+=sh[i];S2+=sh[4+i];}
    double m=S*invCount, v=S2*invCount-m*m;
    double a=(double)g[c]/sqrt(v+1e-5);
    A[c]=a; Bv[c]=(double)b[c]-m*a;
  }
}

// binarize: grid 2048, quad-pixel inner loop, per-pixel ballot pack.
__global__ __launch_bounds__(256) void k_conv1_binarize5(const float* __restrict__ x,
        const float* __restrict__ w1, const double* __restrict__ A, const double* __restrict__ Bv,
        uint32_t* __restrict__ bits){
  __shared__ double xs[3][6][34];
  __shared__ float wf[128][27];
  __shared__ uint32_t wordbuf[4][128];
  int n = blockIdx.x >> 3, rg = blockIdx.x & 7;
  int y0 = rg*4;
  const float* xp = x + (size_t)n*3*1024;
  for (int i=threadIdx.x; i<3*6*34; i+=256){
    int ci = i/204, r = i%204, ly = r/34, lx = r%34;
    int gy = y0 - 1 + ly, gx = lx - 1;
    double v = 0.0;
    if (gy>=0 && gy<32 && gx>=0 && gx<32) v = (double)xp[ci*1024 + gy*32 + gx];
    (&xs[0][0][0])[i] = v;
  }
  for (int i=threadIdx.x; i<128*27; i+=256)
    (&wf[0][0])[i] = w1[i];
  __syncthreads();
  int wave = threadIdx.x>>6, lane = threadIdx.x&63;
  int c0 = (wave&1)*64, rsub = wave>>1;
  int co = c0 + lane;
  double w[27];
  #pragma unroll
  for (int k=0;k<27;k++) w[k] = (wf[co][k] >= 0.f) ? 1.0 : -1.0;
  double av = A[co], bv = Bv[co];
  for (int rr = rsub*2; rr < rsub*2+2; ++rr){
    for (int x0=0; x0<32; x0+=4){
      double acc[4] = {0,0,0,0};
      #pragma unroll
      for (int ci=0;ci<3;ci++)
        #pragma unroll
        for (int ky=0;ky<3;ky++){
          const double* r = &xs[ci][rr+ky][x0];
          double v0=r[0],v1=r[1],v2=r[2],v3=r[3],v4=r[4],v5=r[5];
          double w0=w[ci*9+ky*3+0], w1v=w[ci*9+ky*3+1], w2=w[ci*9+ky*3+2];
          acc[0] += v0*w0 + v1*w1v + v2*w2;
          acc[1] += v1*w0 + v2*w1v + v3*w2;
          acc[2] += v2*w0 + v3*w1v + v4*w2;
          acc[3] += v3*w0 + v4*w1v + v5*w2;
        }
      #pragma unroll
      for (int j=0;j<4;j++){
        int pred = (acc[j]*av + bv >= 0.0) ? 1 : 0;
        unsigned long long m = __ballot(pred);
        if (lane == 0){
          int p = rr*32 + x0 + j;
          wordbuf[(c0>>5)+0][p] = (uint32_t)m;
          wordbuf[(c0>>5)+1][p] = (uint32_t)(m>>32);
        }
      }
    }
  }
  __syncthreads();
  for (int i=threadIdx.x; i<512; i+=256){
    int cw = i>>7, p = i&127;
    bits[(size_t)n*4096 + cw*1024 + rg*128 + p] = wordbuf[cw][p];
  }
}

// =====================================================================
// XNOR conv family
// =====================================================================
template<int CW,int H,int W,int HP,int PITCH>
__device__ __forceinline__ void stage_bits(const uint32_t* __restrict__ ip, uint32_t* __restrict__ inlds){
  for (int i=threadIdx.x; i<CW*HP*PITCH; i+=256) inlds[i]=0u;
}

template<int CW,int H,int W,int HP,int PITCH>
__device__ __forceinline__ void fill_bits(const uint32_t* __restrict__ ip, uint32_t* __restrict__ inlds){
  constexpr int LOGW  = (W==32)?5:(W==16)?4:3;
  constexpr int LOGHW = ((H*W)==1024)?10:((H*W)==256)?8:6;
  for (int i=threadIdx.x; i<CW*H*W; i+=256){
    int cw = i >> LOGHW;
    int rem = i & (H*W-1);
    int y = rem >> LOGW;
    int x = rem & (W-1);
    inlds[cw*HP*PITCH + (y+1)*PITCH + (x+1)] = ip[i];
  }
}

// ---- fused conv + pool, TWO output channels per thread (L2, L4)
template<int CW,int H,int W,int CO,int COB,int NX>
__global__ __launch_bounds__(256) void k_xconv_pool2(const uint32_t* __restrict__ in,
        const uint32_t* __restrict__ wb, int16_t* __restrict__ out, long long* __restrict__ part){
  constexpr int HP = H+2;
  constexpr int PITCH = W+3;          // odd
  constexpr int WP = CW*9+1;
  constexpr int NG = CO/COB;
  constexpr int XS = W/NX;
  constexpr int UNITS = (H/2)*XS;
  static_assert((COB/2)*UNITS==256, "thread mapping");
  __shared__ uint32_t inlds[CW*HP*PITCH];
  __shared__ uint32_t wlds[COB*WP];
  __shared__ int colpc[COB][10];
  int n = blockIdx.x / NG, cg = blockIdx.x % NG;
  int co0 = cg*COB;
  const uint32_t* ip = in + (size_t)n*CW*H*W;
  stage_bits<CW,H,W,HP,PITCH>(ip, inlds);
  for (int i=threadIdx.x; i<COB*CW*9; i+=256){
    int co = i/(CW*9); int r = i%(CW*9);
    wlds[co*WP + r] = wb[(size_t)(co0+co)*CW*9 + r];
  }
  __syncthreads();
  fill_bits<CW,H,W,HP,PITCH>(ip, inlds);
  for (int i=threadIdx.x; i<COB*9; i+=256){
    int co=i/9, tap=i%9; int s=0;
    #pragma unroll
    for (int cw=0;cw<CW;cw++) s += __popc(wlds[co*WP + cw*9 + tap]);
    colpc[co][tap]=s;
  }
  __syncthreads();
  int t = threadIdx.x;
  int cog = t / UNITS;
  int rem = t % UNITS;
  int yy = rem / XS;
  int xs = (rem % XS)*NX;
  int c0 = cog*2;
  int acc0[2][NX], acc1[2][NX];
  #pragma unroll
  for (int c=0;c<2;c++)
    #pragma unroll
    for (int i2=0;i2<NX;i2++){acc0[c][i2]=0;acc1[c][i2]=0;}
  for (int cw=0; cw<CW; cw++){
    uint32_t wr[2][9];
    #pragma unroll
    for (int c=0;c<2;c++)
      #pragma unroll
      for (int k=0;k<9;k++) wr[c][k]=wlds[(c0+c)*WP+cw*9+k];
    const uint32_t* ib = &inlds[cw*HP*PITCH + (2*yy)*PITCH + xs];
    {
      uint32_t row[NX+2];
      #pragma unroll
      for (int j=0;j<NX+2;j++) row[j] = ib[j];
      #pragma unroll
      for (int q=0;q<NX;q++)
        #pragma unroll
        for (int c=0;c<2;c++){
          acc0[c][q] = BMAC(row[q],  wr[c][0], acc0[c][q]);
          acc0[c][q] = BMAC(row[q+1],wr[c][1], acc0[c][q]);
          acc0[c][q] = BMAC(row[q+2],wr[c][2], acc0[c][q]);
        }
    }
    #pragma unroll
    for (int rrow=1; rrow<=2; rrow++){
      uint32_t row[NX+2];
      #pragma unroll
      for (int j=0;j<NX+2;j++) row[j] = ib[rrow*PITCH + j];
      #pragma unroll
      for (int q=0;q<NX;q++)
        #pragma unroll
        for (int c=0;c<2;c++){
          acc0[c][q] = BMAC(row[q],  wr[c][3*rrow+0], acc0[c][q]);
          acc0[c][q] = BMAC(row[q+1],wr[c][3*rrow+1], acc0[c][q]);
          acc0[c][q] = BMAC(row[q+2],wr[c][3*rrow+2], acc0[c][q]);
          acc1[c][q] = BMAC(row[q],  wr[c][3*rrow-3], acc1[c][q]);
          acc1[c][q] = BMAC(row[q+1],wr[c][3*rrow-2], acc1[c][q]);
          acc1[c][q] = BMAC(row[q+2],wr[c][3*rrow-1], acc1[c][q]);
        }
    }
    {
      uint32_t row[NX+2];
      #pragma unroll
      for (int j=0;j<NX+2;j++) row[j] = ib[3*PITCH + j];
      #pragma unroll
      for (int q=0;q<NX;q++)
        #pragma unroll
        for (int c=0;c<2;c++){
          acc1[c][q] = BMAC(row[q],  wr[c][6], acc1[c][q]);
          acc1[c][q] = BMAC(row[q+1],wr[c][7], acc1[c][q]);
          acc1[c][q] = BMAC(row[q+2],wr[c][8], acc1[c][q]);
        }
    }
  }
  #pragma unroll
  for (int c=0;c<2;c++){
    const int* cp = colpc[c0+c];
    int16_t res[NX/2];
    #pragma unroll
    for (int tp=0; tp<NX/2; tp++){
      int best=-32768;
      #pragma unroll
      for (int rrow=0;rrow<2;rrow++){
        int kyi = (rrow==0 && yy==0) ? 0 : ((rrow==1 && yy==H/2-1) ? 2 : -1);
        #pragma unroll
        for (int dx=0;dx<2;dx++){
          int q = 2*tp+dx;
          int x = xs+q;
          int kxi = (x==0)?0:((x==W-1)?2:-1);
          int acc = rrow? acc1[c][q]:acc0[c][q];
          int corr=0, nv=9;
          if (kyi>=0){ corr += cp[kyi*3+0]+cp[kyi*3+1]+cp[kyi*3+2]; }
          if (kxi>=0){ corr += cp[0+kxi]+cp[3+kxi]+cp[6+kxi]; }
          if (kyi>=0 && kxi>=0){ corr -= cp[kyi*3+kxi]; nv=4; }
          else if (kyi>=0 || kxi>=0) nv=6;
          int dot = 32*CW*nv - 2*(acc - corr);
          best = dot>best?dot:best;
        }
      }
      res[tp]=(int16_t)best;
    }
    int16_t* op = out + (((size_t)n*CO + (co0+c0+c))*(H/2) + yy)*(W/2) + xs/2;
    #pragma unroll
    for (int tp=0;tp<NX/2;tp++) op[tp]=res[tp];
    int ssum=0; long long ssq=0;
    #pragma unroll
    for (int tp=0;tp<NX/2;tp++){ int v=res[tp]; ssum+=v; ssq += (long long)(v*v); }
    long long s = (long long)ssum;
    #pragma unroll
    for (int off=UNITS>>1; off; off>>=1){ s += __shfl_down(s,off,UNITS); ssq += __shfl_down(ssq,off,UNITS); }
    if (rem==0){
      size_t pi = (size_t)(co0+c0+c)*BATCH + n;
      part[pi*2+0]=s; part[pi*2+1]=ssq;
    }
  }
}

// ---- fused conv + pool, one channel per thread (L6)
template<int CW,int H,int W,int CO,int COB,int NX>
__global__ __launch_bounds__(256) void k_xconv_pool(const uint32_t* __restrict__ in,
        const uint32_t* __restrict__ wb, int16_t* __restrict__ out, long long* __restrict__ part){
  constexpr int HP = H+2;
  constexpr int PITCH = W+3;          // odd
  constexpr int WP = CW*9+1;
  constexpr int NG = CO/COB;
  constexpr int XS = W/NX;
  constexpr int UNITS = (H/2)*XS;
  static_assert(COB*UNITS==256, "thread mapping");
  __shared__ uint32_t inlds[CW*HP*PITCH];
  __shared__ uint32_t wlds[COB*WP];
  __shared__ int colpc[COB][10];
  int n = blockIdx.x / NG, cg = blockIdx.x % NG;
  int co0 = cg*COB;
  const uint32_t* ip = in + (size_t)n*CW*H*W;
  stage_bits<CW,H,W,HP,PITCH>(ip, inlds);
  for (int i=threadIdx.x; i<COB*CW*9; i+=256){
    int co = i/(CW*9); int r = i%(CW*9);
    wlds[co*WP + r] = wb[(size_t)(co0+co)*CW*9 + r];
  }
  __syncthreads();
  fill_bits<CW,H,W,HP,PITCH>(ip, inlds);
  for (int i=threadIdx.x; i<COB*9; i+=256){
    int co=i/9, tap=i%9; int s=0;
    #pragma unroll
    for (int cw=0;cw<CW;cw++) s += __popc(wlds[co*WP + cw*9 + tap]);
    colpc[co][tap]=s;
  }
  __syncthreads();
  int t = threadIdx.x;
  int col = t / UNITS;
  int rem = t % UNITS;
  int yy = rem / XS;
  int xs = (rem % XS)*NX;
  int co = co0 + col;
  int acc0[NX], acc1[NX];
  #pragma unroll
  for (int i2=0;i2<NX;i2++){acc0[i2]=0;acc1[i2]=0;}
  for (int cw=0; cw<CW; cw++){
    uint32_t wr[9];
    #pragma unroll
    for (int k=0;k<9;k++) wr[k]=wlds[col*WP+cw*9+k];
    const uint32_t* ib = &inlds[cw*HP*PITCH + (2*yy)*PITCH + xs];
    {
      uint32_t row[NX+2];
      #pragma unroll
      for (int j=0;j<NX+2;j++) row[j] = ib[j];
      #pragma unroll
      for (int q=0;q<NX;q++){
        acc0[q] = BMAC(row[q],  wr[0], acc0[q]);
        acc0[q] = BMAC(row[q+1],wr[1], acc0[q]);
        acc0[q] = BMAC(row[q+2],wr[2], acc0[q]);
      }
    }
    #pragma unroll
    for (int rrow=1; rrow<=2; rrow++){
      uint32_t row[NX+2];
      #pragma unroll
      for (int j=0;j<NX+2;j++) row[j] = ib[rrow*PITCH + j];
      #pragma unroll
      for (int q=0;q<NX;q++){
        acc0[q] = BMAC(row[q],  wr[3*rrow+0], acc0[q]);
        acc0[q] = BMAC(row[q+1],wr[3*rrow+1], acc0[q]);
        acc0[q] = BMAC(row[q+2],wr[3*rrow+2], acc0[q]);
        acc1[q] = BMAC(row[q],  wr[3*rrow-3], acc1[q]);
        acc1[q] = BMAC(row[q+1],wr[3*rrow-2], acc1[q]);
        acc1[q] = BMAC(row[q+2],wr[3*rrow-1], acc1[q]);
      }
    }
    {
      uint32_t row[NX+2];
      #pragma unroll
      for (int j=0;j<NX+2;j++) row[j] = ib[3*PITCH + j];
      #pragma unroll
      for (int q=0;q<NX;q++){
        acc1[q] = BMAC(row[q],  wr[6], acc1[q]);
        acc1[q] = BMAC(row[q+1],wr[7], acc1[q]);
        acc1[q] = BMAC(row[q+2],wr[8], acc1[q]);
      }
    }
  }
  const int* cp = colpc[col];
  int16_t res[NX/2];
  #pragma unroll
  for (int tp=0; tp<NX/2; tp++){
    int best=-32768;
    #pragma unroll
    for (int rrow=0;rrow<2;rrow++){
      int kyi = (rrow==0 && yy==0) ? 0 : ((rrow==1 && yy==H/2-1) ? 2 : -1);
      #pragma unroll
      for (int dx=0;dx<2;dx++){
        int q = 2*tp+dx;
        int x = xs+q;
        int kxi = (x==0)?0:((x==W-1)?2:-1);
        int acc = rrow? acc1[q]:acc0[q];
        int corr=0, nv=9;
        if (kyi>=0){ corr += cp[kyi*3+0]+cp[kyi*3+1]+cp[kyi*3+2]; }
        if (kxi>=0){ corr += cp[0+kxi]+cp[3+kxi]+cp[6+kxi]; }
        if (kyi>=0 && kxi>=0){ corr -= cp[kyi*3+kxi]; nv=4; }
        else if (kyi>=0 || kxi>=0) nv=6;
        int dot = 32*CW*nv - 2*(acc - corr);
        best = dot>best?dot:best;
      }
    }
    res[tp]=(int16_t)best;
  }
  int16_t* op = out + (((size_t)n*CO + co)*(H/2) + yy)*(W/2) + xs/2;
  #pragma unroll
  for (int tp=0;tp<NX/2;tp++) op[tp]=res[tp];
  int ssum=0; long long ssq=0;
  #pragma unroll
  for (int tp=0;tp<NX/2;tp++){ int v=res[tp]; ssum+=v; ssq += (long long)(v*v); }
  long long s = (long long)ssum;
  #pragma unroll
  for (int off=UNITS>>1; off; off>>=1){ s += __shfl_down(s,off,UNITS); ssq += __shfl_down(ssq,off,UNITS); }
  if (rem==0){
    size_t pi = (size_t)co*BATCH + n;
    part[pi*2+0]=s; part[pi*2+1]=ssq;
  }
}

// ---- plain conv, two channels per thread (L3, L5)
template<int CW,int H,int W,int CO,int COB,int NX>
__global__ __launch_bounds__(256) void k_xconv(const uint32_t* __restrict__ in,
        const uint32_t* __restrict__ wb, int16_t* __restrict__ out, long long* __restrict__ part){
  constexpr int HP = H+2;
  constexpr int PITCH = W+3;          // odd
  constexpr int WP = CW*9+1;
  constexpr int NG = CO/COB;
  constexpr int XS = W/NX;
  constexpr int UNITS = H*XS;
  static_assert((COB/2)*UNITS==256, "thread mapping");
  __shared__ uint32_t inlds[CW*HP*PITCH];
  __shared__ uint32_t wlds[COB*WP];
  __shared__ int colpc[COB][10];
  int n = blockIdx.x / NG, cg = blockIdx.x % NG;
  int co0 = cg*COB;
  const uint32_t* ip = in + (size_t)n*CW*H*W;
  stage_bits<CW,H,W,HP,PITCH>(ip, inlds);
  for (int i=threadIdx.x; i<COB*CW*9; i+=256){
    int co = i/(CW*9); int r = i%(CW*9);
    wlds[co*WP + r] = wb[(size_t)(co0+co)*CW*9 + r];
  }
  __syncthreads();
  fill_bits<CW,H,W,HP,PITCH>(ip, inlds);
  for (int i=threadIdx.x; i<COB*9; i+=256){
    int co=i/9, tap=i%9; int s=0;
    #pragma unroll
    for (int cw=0;cw<CW;cw++) s += __popc(wlds[co*WP + cw*9 + tap]);
    colpc[co][tap]=s;
  }
  __syncthreads();
  int t = threadIdx.x;
  int cog = t / UNITS;
  int rem = t % UNITS;
  int y = rem / XS;
  int xs = (rem % XS)*NX;
  int c0 = cog*2;
  int acc[2][NX];
  #pragma unroll
  for (int c=0;c<2;c++)
    #pragma unroll
    for (int i2=0;i2<NX;i2++) acc[c][i2]=0;
  for (int cw=0; cw<CW; cw++){
    uint32_t wr[2][9];
    #pragma unroll
    for (int c=0;c<2;c++)
      #pragma unroll
      for (int k=0;k<9;k++) wr[c][k]=wlds[(c0+c)*WP+cw*9+k];
    const uint32_t* ib = &inlds[cw*HP*PITCH + y*PITCH + xs];
    #pragma unroll
    for (int rrow=0; rrow<3; rrow++){
      uint32_t row[NX+2];
      #pragma unroll
      for (int j=0;j<NX+2;j++) row[j] = ib[rrow*PITCH + j];
      #pragma unroll
      for (int q=0;q<NX;q++){
        acc[0][q] = BMAC(row[q],  wr[0][3*rrow+0], acc[0][q]);
        acc[0][q] = BMAC(row[q+1],wr[0][3*rrow+1], acc[0][q]);
        acc[0][q] = BMAC(row[q+2],wr[0][3*rrow+2], acc[0][q]);
        acc[1][q] = BMAC(row[q],  wr[1][3*rrow+0], acc[1][q]);
        acc[1][q] = BMAC(row[q+1],wr[1][3*rrow+1], acc[1][q]);
        acc[1][q] = BMAC(row[q+2],wr[1][3*rrow+2], acc[1][q]);
      }
    }
  }
  int kyi = (y==0)?0:((y==H-1)?2:-1);
  #pragma unroll
  for (int c=0;c<2;c++){
    const int* cp = colpc[c0+c];
    int16_t rbuf[NX];
    int ssum=0; long long ssq=0;
    #pragma unroll
    for (int q=0;q<NX;q++){
      int x = xs+q;
      int kxi = (x==0)?0:((x==W-1)?2:-1);
      int corr=0, nv=9;
      if (kyi>=0){ corr += cp[kyi*3+0]+cp[kyi*3+1]+cp[kyi*3+2]; }
      if (kxi>=0){ corr += cp[0+kxi]+cp[3+kxi]+cp[6+kxi]; }
      if (kyi>=0 && kxi>=0){ corr -= cp[kyi*3+kxi]; nv=4; }
      else if (kyi>=0 || kxi>=0) nv=6;
      int dot = 32*CW*nv - 2*(acc[c][q] - corr);
      rbuf[q] = (int16_t)dot;
      ssum+=dot; ssq+=(long long)(dot*dot);
    }
    int16_t* op = out + (((size_t)n*CO + (co0+c0+c))*H + y)*W + xs;
    #pragma unroll
    for (int q=0;q<NX;q++) op[q]=rbuf[q];
    long long s=(long long)ssum, q2=ssq;
    #pragma unroll
    for (int off=UNITS>>1; off; off>>=1){ s += __shfl_down(s,off,UNITS); q2 += __shfl_down(q2,off,UNITS); }
    if (rem==0){
      size_t pi = (size_t)(co0+c0+c)*BATCH + n;
      part[pi*2+0]=s; part[pi*2+1]=q2;
    }
  }
}

// ---------------- parallel per-channel finalize from [c][256] int64 ----------------
__global__ __launch_bounds__(256) void k_chstats_fin_p(const long long* __restrict__ part,
        const float* __restrict__ g, const float* __restrict__ b,
        double* __restrict__ A, double* __restrict__ Bv, double invCount){
  int c = blockIdx.x;
  long long s  = part[((size_t)c*BATCH+threadIdx.x)*2+0];
  long long s2 = part[((size_t)c*BATCH+threadIdx.x)*2+1];
  for (int off=32; off; off>>=1){ s+=__shfl_down(s,off,64); s2+=__shfl_down(s2,off,64); }
  __shared__ long long sh[8];
  int wid=threadIdx.x>>6, lane=threadIdx.x&63;
  if(lane==0){sh[wid]=s;sh[4+wid]=s2;}
  __syncthreads();
  if(threadIdx.x==0){
    long long S=0,S2=0;
    #pragma unroll
    for(int i=0;i<4;i++){S+=sh[i];S2+=sh[4+i];}
    double m=(double)S*invCount, v=(double)S2*invCount-m*m;
    double a=(double)g[c]/sqrt(v+1e-5);
    A[c]=a; Bv[c]=(double)b[c]-m*a;
  }
}

// ---------------- binarize BN(conv) and pack ----------------
__global__ void k_binarize_pack(const int16_t* __restrict__ in, const double* __restrict__ A,
                                const double* __restrict__ Bv, uint32_t* __restrict__ bits,
                                int C, int HW){
  int CW = C>>5;
  size_t total = (size_t)BATCH*CW*HW;
  size_t idx = (size_t)blockIdx.x*256+threadIdx.x;
  if (idx>=total) return;
  int hw = (int)(idx % HW); size_t t = idx/HW;
  int cw = (int)(t % CW); int n = (int)(t / CW);
  uint32_t wordv=0;
  for (int b=0;b<32;b++){
    int c = cw*32+b;
    double v = (double)in[((size_t)n*C + c)*HW + hw];
    if (v*A[c]+Bv[c] >= 0.0) wordv |= 1u<<b;
  }
  bits[idx]=wordv;
}

// ---------------- FC1 ----------------
__global__ void k_fc1(const uint32_t* __restrict__ actbits, const uint32_t* __restrict__ wb,
                      int16_t* __restrict__ out){
  int og = blockIdx.x & 3; int n = blockIdx.x >> 2;
  int o = og*256 + threadIdx.x;
  __shared__ uint32_t sact[256];
  sact[threadIdx.x] = actbits[(size_t)n*256 + threadIdx.x];
  __syncthreads();
  const uint32_t* wp = wb + (size_t)o*256;
  int acc=0;
  #pragma unroll 8
  for (int k=0;k<256;k++) acc = BMAC(sact[k], wp[k], acc);
  out[(size_t)n*1024 + o] = (int16_t)(8192 - 2*acc);
}

__global__ void k_fc_stats(const int16_t* __restrict__ in, const float* __restrict__ g,
                           const float* __restrict__ b, double* __restrict__ A, double* __restrict__ Bv){
  int f = blockIdx.x;
  double v = (double)in[(size_t)threadIdx.x*1024 + f];
  double s=v, s2=v*v;
  __shared__ double sh[8];
  for (int off=32; off; off>>=1){ s+=__shfl_down(s,off,64); s2+=__shfl_down(s2,off,64); }
  int wid=threadIdx.x>>6, lane=threadIdx.x&63;
  if(lane==0){sh[wid]=s;sh[4+wid]=s2;}
  __syncthreads();
  if(threadIdx.x==0){
    double S=0,S2=0;
    #pragma unroll
    for(int i=0;i<4;i++){S+=sh[i];S2+=sh[4+i];}
    double m=S/256.0, var=S2/256.0-m*m;
    double a=(double)g[f]/sqrt(var+1e-5);
    A[f]=a; Bv[f]=(double)b[f]-m*a;
  }
}

__global__ void k_binpack_fc(const int16_t* __restrict__ in, const double* __restrict__ A,
                             const double* __restrict__ Bv, uint32_t* __restrict__ bits){
  int idx = blockIdx.x*256+threadIdx.x;
  if (idx >= 256*32) return;
  int w = idx & 31, n = idx >> 5;
  uint32_t word=0;
  for (int b=0;b<32;b++){
    int f = w*32+b;
    double v=(double)in[(size_t)n*1024+f];
    if (v*A[f]+Bv[f] >= 0.0) word|=1u<<b;
  }
  bits[idx]=word;
}

// ---------------- FC2 + final BN -> float out ----------------
__global__ void k_fc2_out(const uint32_t* __restrict__ actbits, const uint32_t* __restrict__ wb,
                          const float* __restrict__ bias2, const float* __restrict__ g,
                          const float* __restrict__ b, float* __restrict__ out){
  int o = blockIdx.x;     // 0..9
  int n = threadIdx.x;    // 0..255
  const uint32_t* ap = actbits + (size_t)n*32;
  const uint32_t* wp = wb + (size_t)o*32;
  int acc=0;
  #pragma unroll
  for (int k=0;k<32;k++) acc = BMAC(ap[k], wp[k], acc);
  double h = (double)(1024 - 2*acc) + (double)bias2[o];
  double s=h, s2=h*h;
  __shared__ double sh[8];
  for(int off=32;off;off>>=1){s+=__shfl_down(s,off,64);s2+=__shfl_down(s2,off,64);}
  int wid=threadIdx.x>>6,lane=threadIdx.x&63;
  if(lane==0){sh[wid]=s;sh[4+wid]=s2;}
  __syncthreads();
  __shared__ double sm, sinv;
  if(threadIdx.x==0){
    double S=0,S2=0;
    #pragma unroll
    for(int i=0;i<4;i++){S+=sh[i];S2+=sh[4+i];}
    double m=S/256.0, v=S2/256.0-m*m;
    sm=m; sinv=1.0/sqrt(v+1e-5);
  }
  __syncthreads();
  double r = (h - sm)*sinv*(double)g[o] + (double)b[o];
  out[(size_t)n*10 + o] = (float)r;
}

extern "C" void kernel_launch(void* const* d_in, const int* in_sizes, int n_in,
                              void* d_out, int out_size, void* d_ws, size_t ws_size,
                              hipStream_t stream) {
  const float* x   = (const float*)d_in[0];
  const float* w1  = (const float*)d_in[1];
  const float* g1  = (const float*)d_in[2];
  const float* b1  = (const float*)d_in[3];
  const float* w2  = (const float*)d_in[4];
  const float* g2  = (const float*)d_in[5];
  const float* b2  = (const float*)d_in[6];
  const float* w3  = (const float*)d_in[7];
  const float* g3  = (const float*)d_in[8];
  const float* b3  = (const float*)d_in[9];
  const float* w4  = (const float*)d_in[10];
  const float* g4  = (const float*)d_in[11];
  const float* b4  = (const float*)d_in[12];
  const float* w5  = (const float*)d_in[13];
  const float* g5  = (const float*)d_in[14];
  const float* b5  = (const float*)d_in[15];
  const float* w6  = (const float*)d_in[16];
  const float* g6  = (const float*)d_in[17];
  const float* b6  = (const float*)d_in[18];
  const float* wf1 = (const float*)d_in[19];
  const float* gf1 = (const float*)d_in[20];
  const float* bf1 = (const float*)d_in[21];
  const float* wf2 = (const float*)d_in[22];
  const float* bias2=(const float*)d_in[23];
  const float* gf2 = (const float*)d_in[24];
  const float* bf2 = (const float*)d_in[25];
  float* out = (float*)d_out;

  char* ws = (char*)d_ws;
  size_t off = 0;
  auto alloc = [&](size_t bytes)->char*{ char* p = ws + off; off = (off + bytes + 255) & ~(size_t)255; return p; };

  uint32_t* wb2  = (uint32_t*)alloc(4608ull*4);
  uint32_t* wb3  = (uint32_t*)alloc(9216ull*4);
  uint32_t* wb4  = (uint32_t*)alloc(18432ull*4);
  uint32_t* wb5  = (uint32_t*)alloc(36864ull*4);
  uint32_t* wb6  = (uint32_t*)alloc(73728ull*4);
  uint32_t* wf1b = (uint32_t*)alloc(262144ull*4);
  uint32_t* wf2b = (uint32_t*)alloc(320ull*4);
  double*   part = (double*)  alloc(128ull*4096*2*8);
  long long* pll = (long long*)alloc(512ull*256*2*8);
  double*   Abuf = (double*)  alloc(1024ull*8);
  double*   Bbuf = (double*)  alloc(1024ull*8);
  uint32_t* bitsA= (uint32_t*)alloc(1048576ull*4);
  uint32_t* bitsB= (uint32_t*)alloc(262144ull*4);
  int16_t*  conv = (int16_t*) alloc(16777216ull*2);

  // pack weights (single launch for all conv layers)
  k_pack_conv_all<<<CDIV(142848,256),256,0,stream>>>(w2,w3,w4,w5,w6, wb2,wb3,wb4,wb5,wb6);
  k_pack_fc1_w<<<CDIV(262144,256),256,0,stream>>>(wf1, wf1b);
  k_pack_fc2_w<<<CDIV(320,256),256,0,stream>>>(wf2, wf2b);

  // ---- layer 1 ----
  k_conv1_stats4<<<2048,256,0,stream>>>(x, w1, part);
  k_finalize_partials_p<<<128,256,0,stream>>>(part, g1, b1, Abuf, Bbuf, 4096, 1.0/(256.0*1024.0));
  k_conv1_binarize5<<<2048,256,0,stream>>>(x, w1, Abuf, Bbuf, bitsA);

  // ---- layer 2: conv+pool -> [256,128,16,16] ----
  k_xconv_pool2<4,32,32,128,8,8><<<256*16,256,0,stream>>>(bitsA, wb2, conv, pll);
  k_chstats_fin_p<<<128,256,0,stream>>>(pll, g2, b2, Abuf, Bbuf, 1.0/(256.0*256.0));
  k_binarize_pack<<<CDIV(256ull*4*256,256),256,0,stream>>>(conv, Abuf, Bbuf, bitsB, 128, 256);

  // ---- layer 3: conv -> [256,256,16,16] ----
  k_xconv<4,16,16,256,16,8><<<256*16,256,0,stream>>>(bitsB, wb3, conv, pll);
  k_chstats_fin_p<<<256,256,0,stream>>>(pll, g3, b3, Abuf, Bbuf, 1.0/(256.0*256.0));
  k_binarize_pack<<<CDIV(256ull*8*256,256),256,0,stream>>>(conv, Abuf, Bbuf, bitsA, 256, 256);

  // ---- layer 4: conv+pool -> [256,256,8,8] ----
  k_xconv_pool2<8,16,16,256,32,8><<<256*8,256,0,stream>>>(bitsA, wb4, conv, pll);
  k_chstats_fin_p<<<256,256,0,stream>>>(pll, g4, b4, Abuf, Bbuf, 1.0/(256.0*64.0));
  k_binarize_pack<<<CDIV(256ull*8*64,256),256,0,stream>>>(conv, Abuf, Bbuf, bitsB, 256, 64);

  // ---- layer 5: conv -> [256,512,8,8] ----
  k_xconv<8,8,8,512,64,8><<<256*8,256,0,stream>>>(bitsB, wb5, conv, pll);
  k_chstats_fin_p<<<512,256,0,stream>>>(pll, g5, b5, Abuf, Bbuf, 1.0/(256.0*64.0));
  k_binarize_pack<<<CDIV(256ull*16*64,256),256,0,stream>>>(conv, Abuf, Bbuf, bitsA, 512, 64);

  // ---- layer 6: conv+pool -> [256,512,4,4] ----
  k_xconv_pool<16,8,8,512,64,8><<<256*8,256,0,stream>>>(bitsA, wb6, conv, pll);
  k_chstats_fin_p<<<512,256,0,stream>>>(pll, g6, b6, Abuf, Bbuf, 1.0/(256.0*16.0));
  k_binarize_pack<<<CDIV(256ull*16*16,256),256,0,stream>>>(conv, Abuf, Bbuf, bitsB, 512, 16);

  // ---- FC1 ----
  k_fc1<<<256*4,256,0,stream>>>(bitsB, wf1b, conv);
  k_fc_stats<<<1024,256,0,stream>>>(conv, gf1, bf1, Abuf, Bbuf);
  k_binpack_fc<<<CDIV(256*32,256),256,0,stream>>>(conv, Abuf, Bbuf, bitsA);

  // ---- FC2 + final BN ----
  k_fc2_out<<<10,256,0,stream>>>(bitsA, wf2b, bias2, gf2, bf2, out);

  (void)in_sizes; (void)n_in; (void)out_size; (void)ws_size;
}